// Round 1
// baseline (520.469 us; speedup 1.0000x reference)
//
#include <hip/hip_runtime.h>
#include <hip/hip_bf16.h>
#include <stdint.h>

// Problem constants
#define S_LEN   2048
#define BATCH   2
#define HID     2048
#define NHEADS  16
#define HDIM    128
#define ROWS    (BATCH * S_LEN)          // 4096
#define ATT_SCALE 0.08838834764831843f   // 1/sqrt(128)

typedef __attribute__((ext_vector_type(8))) short s16x8;
typedef __attribute__((ext_vector_type(4))) float f32x4;

#define GLL16(gp, lp)                                                          \
  __builtin_amdgcn_global_load_lds(                                            \
      (__attribute__((address_space(1))) void*)(gp),                           \
      (__attribute__((address_space(3))) void*)(lp), 16, 0, 0)

__device__ __forceinline__ float bf2f(unsigned short u) {
  union { unsigned int i; float f; } v; v.i = ((unsigned int)u) << 16; return v.f;
}
__device__ __forceinline__ unsigned short f2bf(float f) {
  union { float f; unsigned int i; } v; v.f = f;
  unsigned int i = v.i;
  return (unsigned short)((i + 0x7FFFu + ((i >> 16) & 1u)) >> 16);
}
__device__ __forceinline__ void store_out(unsigned short* p, float v) { *p = f2bf(v); }
__device__ __forceinline__ void store_out(float* p, float v) { *p = v; }

// ---------------- weight cast fp32 -> bf16 (4 elems/thread) ----------------
__global__ __launch_bounds__(256) void cast_w_kernel(const float* __restrict__ in,
                                                     unsigned short* __restrict__ out, int n4) {
  int i = blockIdx.x * 256 + threadIdx.x;
  if (i >= n4) return;
  float4 v = ((const float4*)in)[i];
  ushort4 o;
  o.x = f2bf(v.x); o.y = f2bf(v.y); o.z = f2bf(v.z); o.w = f2bf(v.w);
  ((ushort4*)out)[i] = o;
}

// ---------------- RMSNorm (fp32 in, bf16 out), one row per block ----------------
__global__ __launch_bounds__(256) void rmsnorm_kernel(const float* __restrict__ x,
                                                      const float* __restrict__ w,
                                                      unsigned short* __restrict__ h) {
  int row = blockIdx.x;
  int t = threadIdx.x;
  const float4* xr4 = (const float4*)(x + (size_t)row * HID);
  float4 a = xr4[t], b = xr4[t + 256];
  float ss = a.x*a.x + a.y*a.y + a.z*a.z + a.w*a.w
           + b.x*b.x + b.y*b.y + b.z*b.z + b.w*b.w;
#pragma unroll
  for (int off = 32; off >= 1; off >>= 1) ss += __shfl_xor(ss, off, 64);
  __shared__ float red[4];
  if ((t & 63) == 0) red[t >> 6] = ss;
  __syncthreads();
  float tot = red[0] + red[1] + red[2] + red[3];
  float rs = rsqrtf(tot * (1.0f / (float)HID) + 1e-6f);
  const float4* w4 = (const float4*)w;
  float4 wa = w4[t], wb = w4[t + 256];
  ushort4 oa, ob;
  oa.x = f2bf(a.x * wa.x * rs); oa.y = f2bf(a.y * wa.y * rs);
  oa.z = f2bf(a.z * wa.z * rs); oa.w = f2bf(a.w * wa.w * rs);
  ob.x = f2bf(b.x * wb.x * rs); ob.y = f2bf(b.y * wb.y * rs);
  ob.z = f2bf(b.z * wb.z * rs); ob.w = f2bf(b.w * wb.w * rs);
  ushort4* hr = (ushort4*)(h + (size_t)row * HID);
  hr[t] = oa; hr[t + 256] = ob;
}

// ---------------- RoPE tables: cos/sin [S][64] fp32 ----------------
__global__ void rope_tab_kernel(float* __restrict__ cost, float* __restrict__ sint) {
  int s = blockIdx.x, j = threadIdx.x;  // 64 threads
  float inv = powf(10000.0f, -((float)j) / 64.0f);
  float ang = (float)s * inv;
  cost[s * 64 + j] = cosf(ang);
  sint[s * 64 + j] = sinf(ang);
}

// ---------------- RoPE apply in-place on q and k (bf16) ----------------
__global__ __launch_bounds__(256) void rope_kernel(const int* __restrict__ pos_ids,
                                                   const float* __restrict__ cost,
                                                   const float* __restrict__ sint,
                                                   unsigned short* __restrict__ q,
                                                   unsigned short* __restrict__ k) {
  int row = blockIdx.x;            // b*S + s
  int p = pos_ids[row];
  int t = threadIdx.x;
  int head = t >> 4;
  int j0 = (t & 15) * 4;
  size_t base = (size_t)row * HID + head * HDIM;
  float4 c = *(const float4*)(cost + p * 64 + j0);
  float4 s = *(const float4*)(sint + p * 64 + j0);
#pragma unroll
  for (int which = 0; which < 2; which++) {
    unsigned short* ptr = which ? k : q;
    ushort4 v1 = *(ushort4*)(ptr + base + j0);
    ushort4 v2 = *(ushort4*)(ptr + base + 64 + j0);
    ushort4 o1, o2;
    o1.x = f2bf(bf2f(v1.x) * c.x - bf2f(v2.x) * s.x);
    o1.y = f2bf(bf2f(v1.y) * c.y - bf2f(v2.y) * s.y);
    o1.z = f2bf(bf2f(v1.z) * c.z - bf2f(v2.z) * s.z);
    o1.w = f2bf(bf2f(v1.w) * c.w - bf2f(v2.w) * s.w);
    o2.x = f2bf(bf2f(v2.x) * c.x + bf2f(v1.x) * s.x);
    o2.y = f2bf(bf2f(v2.y) * c.y + bf2f(v1.y) * s.y);
    o2.z = f2bf(bf2f(v2.z) * c.z + bf2f(v1.z) * s.z);
    o2.w = f2bf(bf2f(v2.w) * c.w + bf2f(v1.w) * s.w);
    *(ushort4*)(ptr + base + j0) = o1;
    *(ushort4*)(ptr + base + 64 + j0) = o2;
  }
}

// ---------------- GEMM: C[m,n] = sum_k A[m,k]*B[n,k], bf16 in, fp32 acc ----------------
// m97 structure: 128x128 tile, BK=32, 4 waves 2x2, global_load_lds w16.
template <typename OutT>
__global__ __launch_bounds__(256) void gemm_bt_kernel(const unsigned short* __restrict__ A,
                                                      const unsigned short* __restrict__ B,
                                                      OutT* __restrict__ C, int K, int N) {
  __shared__ __align__(16) unsigned short As[128 * 32];
  __shared__ __align__(16) unsigned short Bs[128 * 32];
  const int m0 = blockIdx.y * 128, n0 = blockIdx.x * 128;
  const int tid = threadIdx.x;
  const int w = tid >> 6, l = tid & 63, g = l >> 4, r = l & 15;
  const int wm = (w >> 1) * 64, wn = (w & 1) * 64;

  f32x4 zero = {0.f, 0.f, 0.f, 0.f};
  f32x4 acc[4][4];
#pragma unroll
  for (int mi = 0; mi < 4; mi++)
#pragma unroll
    for (int ni = 0; ni < 4; ni++) acc[mi][ni] = zero;

  const int rowA0 = tid >> 2, koff = (tid & 3) * 8;
  const unsigned short* ag0 = A + (size_t)(m0 + rowA0) * K + koff;
  const unsigned short* ag1 = A + (size_t)(m0 + rowA0 + 64) * K + koff;
  const unsigned short* bg0 = B + (size_t)(n0 + rowA0) * K + koff;
  const unsigned short* bg1 = B + (size_t)(n0 + rowA0 + 64) * K + koff;
  unsigned short* al0 = As + tid * 8;
  unsigned short* al1 = As + (tid + 256) * 8;
  unsigned short* bl0 = Bs + tid * 8;
  unsigned short* bl1 = Bs + (tid + 256) * 8;

  for (int k0 = 0; k0 < K; k0 += 32) {
    GLL16(ag0 + k0, al0);
    GLL16(ag1 + k0, al1);
    GLL16(bg0 + k0, bl0);
    GLL16(bg1 + k0, bl1);
    __syncthreads();
    s16x8 af[4], bfr[4];
#pragma unroll
    for (int mi = 0; mi < 4; mi++)
      af[mi] = *(const s16x8*)(As + (wm + mi * 16 + r) * 32 + g * 8);
#pragma unroll
    for (int ni = 0; ni < 4; ni++)
      bfr[ni] = *(const s16x8*)(Bs + (wn + ni * 16 + r) * 32 + g * 8);
#pragma unroll
    for (int mi = 0; mi < 4; mi++)
#pragma unroll
      for (int ni = 0; ni < 4; ni++)
        acc[mi][ni] = __builtin_amdgcn_mfma_f32_16x16x32_bf16(af[mi], bfr[ni], acc[mi][ni], 0, 0, 0);
    __syncthreads();
  }
#pragma unroll
  for (int mi = 0; mi < 4; mi++) {
#pragma unroll
    for (int ni = 0; ni < 4; ni++) {
      const int crow = m0 + wm + mi * 16 + g * 4;
      const int ccol = n0 + wn + ni * 16 + r;
#pragma unroll
      for (int j = 0; j < 4; j++)
        store_out(&C[(size_t)(crow + j) * N + ccol], acc[mi][ni][j]);
    }
  }
}

// ---------------- Flash attention, causal. grid (S/64, B*NHEADS), 256 thr ----------------
__global__ __launch_bounds__(256) void attn_kernel(const unsigned short* __restrict__ Q,
                                                   const unsigned short* __restrict__ Kb,
                                                   const unsigned short* __restrict__ Vb,
                                                   unsigned short* __restrict__ O) {
  __shared__ __align__(16) unsigned short Ksm[64 * 128];  // swizzled
  __shared__ __align__(16) unsigned short Vsm[64 * 128];  // linear
  __shared__ __align__(16) unsigned short Psm[4 * 16 * 64];  // per-wave, swizzled
  const int qt = blockIdx.x;
  const int bh = blockIdx.y;
  const int b = bh >> 4, hd = bh & 15;
  const int tid = threadIdx.x, w = tid >> 6, l = tid & 63, g = l >> 4, r = l & 15;
  const size_t hbase = ((size_t)b * S_LEN) * HID + hd * HDIM;

  // Q fragments (A-layout): row = r, d = ks*32 + g*8 + j
  const int qrow = qt * 64 + w * 16 + r;
  const unsigned short* qp = Q + hbase + (size_t)qrow * HID;
  s16x8 qf[4];
#pragma unroll
  for (int ks = 0; ks < 4; ks++) qf[ks] = *(const s16x8*)(qp + ks * 32 + g * 8);

  float mreg[4], lreg[4];
  f32x4 zero = {0.f, 0.f, 0.f, 0.f};
  f32x4 oacc[8];
#pragma unroll
  for (int j = 0; j < 4; j++) { mreg[j] = -1e30f; lreg[j] = 0.f; }
#pragma unroll
  for (int di = 0; di < 8; di++) oacc[di] = zero;

  // staging geometry: chunk c = tid + 256*i -> krow = c>>4, d-off = (c&15)*8
  const int stg_d = (tid & 15) * 8;
  const int stg_row = tid >> 4;  // + 16*i
  const unsigned short* kgp = Kb + hbase + stg_d;
  const unsigned short* vgp = Vb + hbase + stg_d;
  char* const ksm_c = (char*)Ksm;
  char* const psm_w = (char*)Psm + w * 2048;

  for (int kt2 = 0; kt2 <= qt; kt2++) {
    const size_t kvoff = (size_t)(kt2 * 64) * HID;
#pragma unroll
    for (int i = 0; i < 4; i++) {
      const int row = stg_row + 16 * i;
      s16x8 tmp = *(const s16x8*)(kgp + kvoff + (size_t)row * HID);
      int byte = row * 256 + stg_d * 2;
      byte ^= (row & 7) << 4;
      *(s16x8*)(ksm_c + byte) = tmp;
      GLL16(vgp + kvoff + (size_t)row * HID, (char*)Vsm + (tid + 256 * i) * 16);
    }
    __syncthreads();

    // S = (Q K^T) tiles: sacc[ni], C-layout row=g*4+j (q), col=r (k)
    f32x4 sacc[4];
#pragma unroll
    for (int ni = 0; ni < 4; ni++) sacc[ni] = zero;
#pragma unroll
    for (int ni = 0; ni < 4; ni++) {
      const int krow = ni * 16 + r;
      const int swz = (krow & 7) << 4;
      const char* kb2 = ksm_c + krow * 256;
#pragma unroll
      for (int ks = 0; ks < 4; ks++) {
        s16x8 kf = *(const s16x8*)(kb2 + (((ks * 32 + g * 8) * 2) ^ swz));
        sacc[ni] = __builtin_amdgcn_mfma_f32_16x16x32_bf16(qf[ks], kf, sacc[ni], 0, 0, 0);
      }
    }

    // online softmax (rows = g*4+j, 16 lanes per row-group share reduction)
    float pv[4][4];
    float mrow[4];
#pragma unroll
    for (int j = 0; j < 4; j++) mrow[j] = -1e30f;
#pragma unroll
    for (int ni = 0; ni < 4; ni++)
#pragma unroll
      for (int j = 0; j < 4; j++) {
        float sval = sacc[ni][j] * ATT_SCALE;
        if (kt2 == qt) {
          int kg = kt2 * 64 + ni * 16 + r;
          int qg = qt * 64 + w * 16 + g * 4 + j;
          if (kg > qg) sval = -1e30f;
        }
        pv[ni][j] = sval;
        mrow[j] = fmaxf(mrow[j], sval);
      }
#pragma unroll
    for (int j = 0; j < 4; j++) {
#pragma unroll
      for (int off = 8; off >= 1; off >>= 1)
        mrow[j] = fmaxf(mrow[j], __shfl_xor(mrow[j], off, 64));
    }
    float corr[4];
#pragma unroll
    for (int j = 0; j < 4; j++) {
      float mn = fmaxf(mreg[j], mrow[j]);
      corr[j] = __expf(mreg[j] - mn);
      mreg[j] = mn;
      float s = 0.f;
#pragma unroll
      for (int ni = 0; ni < 4; ni++) { pv[ni][j] = __expf(pv[ni][j] - mn); s += pv[ni][j]; }
#pragma unroll
      for (int off = 8; off >= 1; off >>= 1) s += __shfl_xor(s, off, 64);
      lreg[j] = lreg[j] * corr[j] + s;
    }
#pragma unroll
    for (int di = 0; di < 8; di++)
#pragma unroll
      for (int j = 0; j < 4; j++) oacc[di][j] *= corr[j];

    // P -> LDS (wave-private, swizzled), C-layout -> A-layout round trip
#pragma unroll
    for (int ni = 0; ni < 4; ni++)
#pragma unroll
      for (int j = 0; j < 4; j++) {
        int prow = g * 4 + j;
        int byte = prow * 128 + (ni * 16 + r) * 2;
        byte ^= (prow & 7) << 4;
        *(unsigned short*)(psm_w + byte) = f2bf(pv[ni][j]);
      }

    // PV: oacc[di] += P[16x64] * V[64x(di*16..)]
#pragma unroll
    for (int ksl = 0; ksl < 2; ksl++) {
      s16x8 pa = *(const s16x8*)(psm_w + ((r * 128 + (ksl * 32 + g * 8) * 2) ^ ((r & 7) << 4)));
      const int kb2 = ksl * 32 + g * 8;
#pragma unroll
      for (int di = 0; di < 8; di++) {
        s16x8 vf;
#pragma unroll
        for (int jj = 0; jj < 8; jj++)
          vf[jj] = (short)Vsm[(kb2 + jj) * 128 + di * 16 + r];
        oacc[di] = __builtin_amdgcn_mfma_f32_16x16x32_bf16(pa, vf, oacc[di], 0, 0, 0);
      }
    }
    __syncthreads();
  }

  // epilogue: O = oacc / l
#pragma unroll
  for (int di = 0; di < 8; di++)
#pragma unroll
    for (int j = 0; j < 4; j++) {
      int orow = qt * 64 + w * 16 + g * 4 + j;
      O[hbase + (size_t)orow * HID + di * 16 + r] = f2bf(oacc[di][j] / lreg[j]);
    }
}

extern "C" void kernel_launch(void* const* d_in, const int* in_sizes, int n_in,
                              void* d_out, int out_size, void* d_ws, size_t ws_size,
                              hipStream_t stream) {
  const float* x      = (const float*)d_in[0];
  const float* norm_w = (const float*)d_in[1];
  const float* wq     = (const float*)d_in[2];
  const float* wk     = (const float*)d_in[3];
  const float* wv     = (const float*)d_in[4];
  const float* wo     = (const float*)d_in[5];
  const int*   pos    = (const int*)d_in[6];
  float* out = (float*)d_out;

  char* ws = (char*)d_ws;
  const size_t WBYTES = (size_t)HID * HID * 2;        // 8 MB
  const size_t ABYTES = (size_t)ROWS * HID * 2;       // 16 MB
  unsigned short* wqb = (unsigned short*)(ws);
  unsigned short* wkb = (unsigned short*)(ws + WBYTES);
  unsigned short* wvb = (unsigned short*)(ws + 2 * WBYTES);
  unsigned short* wob = (unsigned short*)(ws + 3 * WBYTES);
  unsigned short* h   = (unsigned short*)(ws + 4 * WBYTES);            // also ctx
  unsigned short* qb  = (unsigned short*)(ws + 4 * WBYTES + ABYTES);
  unsigned short* kb  = (unsigned short*)(ws + 4 * WBYTES + 2 * ABYTES);
  unsigned short* vb  = (unsigned short*)(ws + 4 * WBYTES + 3 * ABYTES);
  float* cost = (float*)(ws + 4 * WBYTES + 4 * ABYTES);
  float* sint = cost + (size_t)S_LEN * 64;

  const int n4 = HID * HID / 4;  // 1M float4 per weight
  cast_w_kernel<<<n4 / 256, 256, 0, stream>>>(wq, wqb, n4);
  cast_w_kernel<<<n4 / 256, 256, 0, stream>>>(wk, wkb, n4);
  cast_w_kernel<<<n4 / 256, 256, 0, stream>>>(wv, wvb, n4);
  cast_w_kernel<<<n4 / 256, 256, 0, stream>>>(wo, wob, n4);
  rope_tab_kernel<<<S_LEN, 64, 0, stream>>>(cost, sint);
  rmsnorm_kernel<<<ROWS, 256, 0, stream>>>(x, norm_w, h);

  dim3 ggrid(HID / 128, ROWS / 128);
  gemm_bt_kernel<unsigned short><<<ggrid, 256, 0, stream>>>(h, wqb, qb, HID, HID);
  gemm_bt_kernel<unsigned short><<<ggrid, 256, 0, stream>>>(h, wkb, kb, HID, HID);
  gemm_bt_kernel<unsigned short><<<ggrid, 256, 0, stream>>>(h, wvb, vb, HID, HID);

  rope_kernel<<<ROWS, 256, 0, stream>>>(pos, cost, sint, qb, kb);

  dim3 agrid(S_LEN / 64, BATCH * NHEADS);
  attn_kernel<<<agrid, 256, 0, stream>>>(qb, kb, vb, h /* ctx reuses h */);

  gemm_bt_kernel<float><<<ggrid, 256, 0, stream>>>(h, wob, out, HID, HID);
}

// Round 2
// 466.217 us; speedup vs baseline: 1.1164x; 1.1164x over previous
//
#include <hip/hip_runtime.h>
#include <hip/hip_bf16.h>
#include <stdint.h>

#define S_LEN   2048
#define BATCH   2
#define HID     2048
#define NHEADS  16
#define HDIM    128
#define ROWS    (BATCH * S_LEN)          // 4096
#define QS      6144                     // qkv row stride (3*HID)
#define ATT_SCALE 0.08838834764831843f   // 1/sqrt(128)

typedef __attribute__((ext_vector_type(8))) short s16x8;
typedef __attribute__((ext_vector_type(4))) float f32x4;

#define GLL16(gp, lp)                                                          \
  __builtin_amdgcn_global_load_lds(                                            \
      (__attribute__((address_space(1))) void*)(gp),                           \
      (__attribute__((address_space(3))) void*)(lp), 16, 0, 0)

__device__ __forceinline__ float bf2f(unsigned short u) {
  union { unsigned int i; float f; } v; v.i = ((unsigned int)u) << 16; return v.f;
}
__device__ __forceinline__ unsigned short f2bf(float f) {
  union { float f; unsigned int i; } v; v.f = f;
  unsigned int i = v.i;
  return (unsigned short)((i + 0x7FFFu + ((i >> 16) & 1u)) >> 16);
}
__device__ __forceinline__ void store_out(unsigned short* p, float v) { *p = f2bf(v); }
__device__ __forceinline__ void store_out(float* p, float v) { *p = v; }

// ---------------- weight cast fp32 -> bf16 ----------------
__global__ __launch_bounds__(256) void cast_w_kernel(const float* __restrict__ in,
                                                     unsigned short* __restrict__ out, int n4) {
  int i = blockIdx.x * 256 + threadIdx.x;
  if (i >= n4) return;
  float4 v = ((const float4*)in)[i];
  ushort4 o;
  o.x = f2bf(v.x); o.y = f2bf(v.y); o.z = f2bf(v.z); o.w = f2bf(v.w);
  ((ushort4*)out)[i] = o;
}

// ---------------- RMSNorm (fp32 in, bf16 out) ----------------
__global__ __launch_bounds__(256) void rmsnorm_kernel(const float* __restrict__ x,
                                                      const float* __restrict__ w,
                                                      unsigned short* __restrict__ h) {
  int row = blockIdx.x;
  int t = threadIdx.x;
  const float4* xr4 = (const float4*)(x + (size_t)row * HID);
  float4 a = xr4[t], b = xr4[t + 256];
  float ss = a.x*a.x + a.y*a.y + a.z*a.z + a.w*a.w
           + b.x*b.x + b.y*b.y + b.z*b.z + b.w*b.w;
#pragma unroll
  for (int off = 32; off >= 1; off >>= 1) ss += __shfl_xor(ss, off, 64);
  __shared__ float red[4];
  if ((t & 63) == 0) red[t >> 6] = ss;
  __syncthreads();
  float tot = red[0] + red[1] + red[2] + red[3];
  float rs = rsqrtf(tot * (1.0f / (float)HID) + 1e-6f);
  const float4* w4 = (const float4*)w;
  float4 wa = w4[t], wb = w4[t + 256];
  ushort4 oa, ob;
  oa.x = f2bf(a.x * wa.x * rs); oa.y = f2bf(a.y * wa.y * rs);
  oa.z = f2bf(a.z * wa.z * rs); oa.w = f2bf(a.w * wa.w * rs);
  ob.x = f2bf(b.x * wb.x * rs); ob.y = f2bf(b.y * wb.y * rs);
  ob.z = f2bf(b.z * wb.z * rs); ob.w = f2bf(b.w * wb.w * rs);
  ushort4* hr = (ushort4*)(h + (size_t)row * HID);
  hr[t] = oa; hr[t + 256] = ob;
}

// ---------------- RoPE tables ----------------
__global__ void rope_tab_kernel(float* __restrict__ cost, float* __restrict__ sint) {
  int s = blockIdx.x, j = threadIdx.x;  // 64 threads
  float inv = powf(10000.0f, -((float)j) / 64.0f);
  float ang = (float)s * inv;
  cost[s * 64 + j] = cosf(ang);
  sint[s * 64 + j] = sinf(ang);
}

// ---------------- RoPE apply in-place on q,k inside fused qkv ----------------
__global__ __launch_bounds__(256) void rope_kernel(const int* __restrict__ pos_ids,
                                                   const float* __restrict__ cost,
                                                   const float* __restrict__ sint,
                                                   unsigned short* __restrict__ qkv) {
  int row = blockIdx.x;            // b*S + s
  int p = pos_ids[row];
  int t = threadIdx.x;
  int head = t >> 4;
  int j0 = (t & 15) * 4;
  size_t base = (size_t)row * QS + head * HDIM;
  float4 c = *(const float4*)(cost + p * 64 + j0);
  float4 s = *(const float4*)(sint + p * 64 + j0);
#pragma unroll
  for (int which = 0; which < 2; which++) {
    unsigned short* ptr = qkv + base + which * HID;  // q then k
    ushort4 v1 = *(ushort4*)(ptr + j0);
    ushort4 v2 = *(ushort4*)(ptr + 64 + j0);
    ushort4 o1, o2;
    o1.x = f2bf(bf2f(v1.x) * c.x - bf2f(v2.x) * s.x);
    o1.y = f2bf(bf2f(v1.y) * c.y - bf2f(v2.y) * s.y);
    o1.z = f2bf(bf2f(v1.z) * c.z - bf2f(v2.z) * s.z);
    o1.w = f2bf(bf2f(v1.w) * c.w - bf2f(v2.w) * s.w);
    o2.x = f2bf(bf2f(v2.x) * c.x + bf2f(v1.x) * s.x);
    o2.y = f2bf(bf2f(v2.y) * c.y + bf2f(v1.y) * s.y);
    o2.z = f2bf(bf2f(v2.z) * c.z + bf2f(v1.z) * s.z);
    o2.w = f2bf(bf2f(v2.w) * c.w + bf2f(v1.w) * s.w);
    *(ushort4*)(ptr + j0) = o1;
    *(ushort4*)(ptr + 64 + j0) = o2;
  }
}

// ---------------- V transpose: qkv v-block [tok][d] -> vt [bh*128+d][S] ----------------
__global__ __launch_bounds__(256) void transpose_v_kernel(const unsigned short* __restrict__ qkv,
                                                          unsigned short* __restrict__ vt) {
  __shared__ unsigned short tile[64][72];
  const int stile = blockIdx.x, dt = blockIdx.y, bh = blockIdx.z;
  const int t = threadIdx.x;
  const int b = bh >> 4, h = bh & 15;
  const int s0 = stile * 64;
  const unsigned short* src = qkv + (size_t)(b * S_LEN + s0) * QS + 2 * HID + h * HDIM + dt * 64;
#pragma unroll
  for (int it = 0; it < 2; it++) {
    int sl = (t >> 3) + 32 * it;
    int dl = (t & 7) * 8;
    *(s16x8*)&tile[sl][dl] = *(const s16x8*)(src + (size_t)sl * QS + dl);
  }
  __syncthreads();
#pragma unroll
  for (int it = 0; it < 2; it++) {
    int dl = (t >> 3) + 32 * it;
    int sl8 = (t & 7) * 8;
    s16x8 o;
#pragma unroll
    for (int jj = 0; jj < 8; jj++) o[jj] = (short)tile[sl8 + jj][dl];
    *(s16x8*)(vt + (size_t)(bh * 128 + dt * 64 + dl) * S_LEN + s0 + sl8) = o;
  }
}

// ---------------- GEMM: C[m,n] = sum_k A[m,k]*B[n,k] ----------------
template <typename OutT>
__global__ __launch_bounds__(256) void gemm_bt_kernel(const unsigned short* __restrict__ A,
                                                      const unsigned short* __restrict__ B,
                                                      OutT* __restrict__ C, int K, int N) {
  __shared__ __align__(16) unsigned short As[128 * 32];
  __shared__ __align__(16) unsigned short Bs[128 * 32];
  const int m0 = blockIdx.y * 128, n0 = blockIdx.x * 128;
  const int tid = threadIdx.x;
  const int w = tid >> 6, l = tid & 63, g = l >> 4, r = l & 15;
  const int wm = (w >> 1) * 64, wn = (w & 1) * 64;

  f32x4 zero = {0.f, 0.f, 0.f, 0.f};
  f32x4 acc[4][4];
#pragma unroll
  for (int mi = 0; mi < 4; mi++)
#pragma unroll
    for (int ni = 0; ni < 4; ni++) acc[mi][ni] = zero;

  const int rowA0 = tid >> 2, koff = (tid & 3) * 8;
  const unsigned short* ag0 = A + (size_t)(m0 + rowA0) * K + koff;
  const unsigned short* ag1 = A + (size_t)(m0 + rowA0 + 64) * K + koff;
  const unsigned short* bg0 = B + (size_t)(n0 + rowA0) * K + koff;
  const unsigned short* bg1 = B + (size_t)(n0 + rowA0 + 64) * K + koff;
  unsigned short* al0 = As + tid * 8;
  unsigned short* al1 = As + (tid + 256) * 8;
  unsigned short* bl0 = Bs + tid * 8;
  unsigned short* bl1 = Bs + (tid + 256) * 8;

  for (int k0 = 0; k0 < K; k0 += 32) {
    GLL16(ag0 + k0, al0);
    GLL16(ag1 + k0, al1);
    GLL16(bg0 + k0, bl0);
    GLL16(bg1 + k0, bl1);
    __syncthreads();
    s16x8 af[4], bfr[4];
#pragma unroll
    for (int mi = 0; mi < 4; mi++)
      af[mi] = *(const s16x8*)(As + (wm + mi * 16 + r) * 32 + g * 8);
#pragma unroll
    for (int ni = 0; ni < 4; ni++)
      bfr[ni] = *(const s16x8*)(Bs + (wn + ni * 16 + r) * 32 + g * 8);
#pragma unroll
    for (int mi = 0; mi < 4; mi++)
#pragma unroll
      for (int ni = 0; ni < 4; ni++)
        acc[mi][ni] = __builtin_amdgcn_mfma_f32_16x16x32_bf16(af[mi], bfr[ni], acc[mi][ni], 0, 0, 0);
    __syncthreads();
  }
#pragma unroll
  for (int mi = 0; mi < 4; mi++) {
#pragma unroll
    for (int ni = 0; ni < 4; ni++) {
      const int crow = m0 + wm + mi * 16 + g * 4;
      const int ccol = n0 + wn + ni * 16 + r;
#pragma unroll
      for (int j = 0; j < 4; j++)
        store_out(&C[(size_t)(crow + j) * N + ccol], acc[mi][ni][j]);
    }
  }
}

// ---------------- Flash attention, causal. grid (S/128, B*NHEADS), 256 thr ----------------
// 4 waves x 32 q-rows; KV tile 64; K & V^T staged via global_load_lds with
// pre-swizzled source (granule ^= row&7); all fragment reads ds_read_b128.
__global__ __launch_bounds__(256) void attn_kernel(const unsigned short* __restrict__ QKV,
                                                   const unsigned short* __restrict__ VT,
                                                   unsigned short* __restrict__ O) {
  __shared__ __align__(16) unsigned short Ksm[64 * 128];    // 16 KB, swizzled granules
  __shared__ __align__(16) unsigned short VTsm[128 * 64];   // 16 KB, swizzled granules
  __shared__ __align__(16) unsigned short Psm[4 * 32 * 64]; // 16 KB, per-wave
  const int qt = (int)gridDim.x - 1 - (int)blockIdx.x;  // heavy blocks first
  const int bh = blockIdx.y;
  const int b = bh >> 4, hd = bh & 15;
  const int tid = threadIdx.x, w = tid >> 6, l = tid & 63, g = l >> 4, r = l & 15;
  const int qbs = qt * 128 + w * 32;   // wave's q-row base (global within sequence)

  // Q fragments: [s][ks], row = qbs + s*16 + r, d = ks*32 + g*8..+7
  s16x8 qf[2][4];
#pragma unroll
  for (int s = 0; s < 2; s++) {
    const unsigned short* qp = QKV + (size_t)(b * S_LEN + qbs + s * 16 + r) * QS + hd * HDIM;
#pragma unroll
    for (int ks = 0; ks < 4; ks++) qf[s][ks] = *(const s16x8*)(qp + ks * 32 + g * 8);
  }

  float mreg[2][4], lreg[2][4];
  f32x4 zero = {0.f, 0.f, 0.f, 0.f};
  f32x4 oacc[2][8];
#pragma unroll
  for (int s = 0; s < 2; s++)
#pragma unroll
    for (int j = 0; j < 4; j++) { mreg[s][j] = -1e30f; lreg[s][j] = 0.f; }
#pragma unroll
  for (int s = 0; s < 2; s++)
#pragma unroll
    for (int di = 0; di < 8; di++) oacc[s][di] = zero;

  // staging bases (i-step offsets are compile-time: (row&7) invariant under +16/+32)
  const int cK = tid & 15, rowK0 = tid >> 4;
  const unsigned short* kp0 = QKV + (size_t)(b * S_LEN + rowK0) * QS + HID + hd * HDIM
                              + ((cK ^ (rowK0 & 7)) << 3);
  const int cV = tid & 7, dV0 = tid >> 3;
  const unsigned short* vp0 = VT + (size_t)(bh * 128 + dV0) * S_LEN + ((cV ^ (dV0 & 7)) << 3);
  char* const ksm_c = (char*)Ksm;
  char* const vtsm_c = (char*)VTsm;
  char* const psm_w = (char*)Psm + w * 4096;

  const int nt = 2 * qt + 2;
  for (int kt2 = 0; kt2 < nt; kt2++) {
#pragma unroll
    for (int i = 0; i < 4; i++) {
      GLL16(kp0 + (size_t)(16 * i) * QS, ksm_c + (tid + 256 * i) * 16);
      GLL16(vp0 + 32 * i * S_LEN, vtsm_c + (tid + 256 * i) * 16);
    }
    kp0 += (size_t)64 * QS;
    vp0 += 64;
    __syncthreads();

    const bool active = (kt2 * 64) <= (qbs + 31);
    if (active) {
      // S = Q K^T
      f32x4 sacc[2][4];
#pragma unroll
      for (int s = 0; s < 2; s++)
#pragma unroll
        for (int ni = 0; ni < 4; ni++) sacc[s][ni] = zero;
#pragma unroll
      for (int ni = 0; ni < 4; ni++) {
        const int krow = ni * 16 + r;
        const int swz = (krow & 7) << 4;
        const char* kb2 = ksm_c + krow * 256;
#pragma unroll
        for (int ks = 0; ks < 4; ks++) {
          s16x8 kf = *(const s16x8*)(kb2 + ((ks * 64 + g * 16) ^ swz));
#pragma unroll
          for (int s = 0; s < 2; s++)
            sacc[s][ni] = __builtin_amdgcn_mfma_f32_16x16x32_bf16(qf[s][ks], kf, sacc[s][ni], 0, 0, 0);
        }
      }

      // online softmax per subtile
#pragma unroll
      for (int s = 0; s < 2; s++) {
        const int qb_s = qbs + s * 16;
        const bool domask = (kt2 * 64 + 63) > qb_s;
        float mrow[4];
#pragma unroll
        for (int j = 0; j < 4; j++) mrow[j] = -1e30f;
#pragma unroll
        for (int ni = 0; ni < 4; ni++)
#pragma unroll
          for (int j = 0; j < 4; j++) {
            float sval = sacc[s][ni][j] * ATT_SCALE;
            if (domask && (kt2 * 64 + ni * 16 + r) > (qb_s + g * 4 + j)) sval = -1e30f;
            sacc[s][ni][j] = sval;
            mrow[j] = fmaxf(mrow[j], sval);
          }
#pragma unroll
        for (int j = 0; j < 4; j++) {
#pragma unroll
          for (int off = 8; off >= 1; off >>= 1)
            mrow[j] = fmaxf(mrow[j], __shfl_xor(mrow[j], off, 64));
        }
        float corr[4];
#pragma unroll
        for (int j = 0; j < 4; j++) {
          float mn = fmaxf(mreg[s][j], mrow[j]);
          corr[j] = __expf(mreg[s][j] - mn);
          mreg[s][j] = mn;
          float sm = 0.f;
#pragma unroll
          for (int ni = 0; ni < 4; ni++) {
            float p = __expf(sacc[s][ni][j] - mn);
            sacc[s][ni][j] = p;
            sm += p;
          }
#pragma unroll
          for (int off = 8; off >= 1; off >>= 1) sm += __shfl_xor(sm, off, 64);
          lreg[s][j] = lreg[s][j] * corr[j] + sm;
        }
#pragma unroll
        for (int di = 0; di < 8; di++)
#pragma unroll
          for (int j = 0; j < 4; j++) oacc[s][di][j] *= corr[j];

        // P -> wave-private LDS (swizzled)
#pragma unroll
        for (int ni = 0; ni < 4; ni++)
#pragma unroll
          for (int j = 0; j < 4; j++) {
            int prow = s * 16 + g * 4 + j;
            int byte = (prow * 128 + ((ni * 16 + r) << 1)) ^ ((prow & 7) << 4);
            *(unsigned short*)(psm_w + byte) = f2bf(sacc[s][ni][j]);
          }
      }

      // PV
#pragma unroll
      for (int ksl = 0; ksl < 2; ksl++) {
        s16x8 pa[2];
#pragma unroll
        for (int s = 0; s < 2; s++)
          pa[s] = *(const s16x8*)(psm_w + (((s * 16 + r) * 128 + ((ksl * 32 + g * 8) << 1)) ^ ((r & 7) << 4)));
        const int kgran = ksl * 4 + g;
#pragma unroll
        for (int di = 0; di < 8; di++) {
          const int d = di * 16 + r;
          s16x8 vf = *(const s16x8*)(vtsm_c + d * 128 + ((kgran ^ (d & 7)) << 4));
#pragma unroll
          for (int s = 0; s < 2; s++)
            oacc[s][di] = __builtin_amdgcn_mfma_f32_16x16x32_bf16(pa[s], vf, oacc[s][di], 0, 0, 0);
        }
      }
    }
    __syncthreads();
  }

  // epilogue
#pragma unroll
  for (int s = 0; s < 2; s++)
#pragma unroll
    for (int di = 0; di < 8; di++)
#pragma unroll
      for (int j = 0; j < 4; j++) {
        int orow = qbs + s * 16 + g * 4 + j;
        O[(size_t)(b * S_LEN + orow) * HID + hd * HDIM + di * 16 + r] =
            f2bf(oacc[s][di][j] / lreg[s][j]);
      }
}

extern "C" void kernel_launch(void* const* d_in, const int* in_sizes, int n_in,
                              void* d_out, int out_size, void* d_ws, size_t ws_size,
                              hipStream_t stream) {
  const float* x      = (const float*)d_in[0];
  const float* norm_w = (const float*)d_in[1];
  const float* wq     = (const float*)d_in[2];
  const float* wk     = (const float*)d_in[3];
  const float* wv     = (const float*)d_in[4];
  const float* wo     = (const float*)d_in[5];
  const int*   pos    = (const int*)d_in[6];
  float* out = (float*)d_out;

  char* ws = (char*)d_ws;
  const size_t WQKV_B = (size_t)3 * HID * HID * 2;   // 24 MB (region A)
  const size_t VT_B   = (size_t)ROWS * HID * 2;      // 16 MB (aliases region A after qkv gemm)
  const size_t H_B    = (size_t)ROWS * HID * 2;      // 16 MB
  const size_t QKV_B  = (size_t)ROWS * QS * 2;       // 48 MB

  unsigned short* wqkvb = (unsigned short*)(ws);            // region A
  unsigned short* vt    = (unsigned short*)(ws);            // reuses region A
  unsigned short* wob   = (unsigned short*)(ws + VT_B);     // region A + 16MB
  unsigned short* h     = (unsigned short*)(ws + WQKV_B);   // also ctx
  unsigned short* qkv   = (unsigned short*)(ws + WQKV_B + H_B);
  float* cost = (float*)(ws + WQKV_B + H_B + QKV_B);
  float* sint = cost + (size_t)S_LEN * 64;

  const int n4 = HID * HID / 4;
  cast_w_kernel<<<n4 / 256, 256, 0, stream>>>(wq, wqkvb, n4);
  cast_w_kernel<<<n4 / 256, 256, 0, stream>>>(wk, wqkvb + (size_t)HID * HID, n4);
  cast_w_kernel<<<n4 / 256, 256, 0, stream>>>(wv, wqkvb + (size_t)2 * HID * HID, n4);
  rope_tab_kernel<<<S_LEN, 64, 0, stream>>>(cost, sint);
  rmsnorm_kernel<<<ROWS, 256, 0, stream>>>(x, norm_w, h);

  dim3 qkvgrid(QS / 128, ROWS / 128);   // 48 x 32
  gemm_bt_kernel<unsigned short><<<qkvgrid, 256, 0, stream>>>(h, wqkvb, qkv, HID, QS);

  // region A is dead now: cast wo into it, build V^T in it
  cast_w_kernel<<<n4 / 256, 256, 0, stream>>>(wo, wob, n4);
  dim3 tgrid(S_LEN / 64, 2, BATCH * NHEADS);
  transpose_v_kernel<<<tgrid, 256, 0, stream>>>(qkv, vt);

  rope_kernel<<<ROWS, 256, 0, stream>>>(pos, cost, sint, qkv);

  dim3 agrid(S_LEN / 128, BATCH * NHEADS);   // 16 x 32
  attn_kernel<<<agrid, 256, 0, stream>>>(qkv, vt, h /* ctx */);

  dim3 ogrid(HID / 128, ROWS / 128);
  gemm_bt_kernel<float><<<ogrid, 256, 0, stream>>>(h, wob, out, HID, HID);
}

// Round 3
// 349.793 us; speedup vs baseline: 1.4879x; 1.3328x over previous
//
#include <hip/hip_runtime.h>
#include <hip/hip_bf16.h>
#include <stdint.h>

#define S_LEN   2048
#define BATCH   2
#define HID     2048
#define NHEADS  16
#define HDIM    128
#define ROWS    (BATCH * S_LEN)          // 4096
#define QS      6144                     // qkv row stride (3*HID)
#define ATT_SCALE 0.08838834764831843f   // 1/sqrt(128)

typedef __attribute__((ext_vector_type(8))) short s16x8;
typedef __attribute__((ext_vector_type(4))) float f32x4;

#define GLL16(gp, lp)                                                          \
  __builtin_amdgcn_global_load_lds(                                            \
      (__attribute__((address_space(1))) void*)(gp),                           \
      (__attribute__((address_space(3))) void*)(lp), 16, 0, 0)

__device__ __forceinline__ float bf2f(unsigned short u) {
  union { unsigned int i; float f; } v; v.i = ((unsigned int)u) << 16; return v.f;
}
__device__ __forceinline__ unsigned short f2bf(float f) {
  union { float f; unsigned int i; } v; v.f = f;
  unsigned int i = v.i;
  return (unsigned short)((i + 0x7FFFu + ((i >> 16) & 1u)) >> 16);
}
__device__ __forceinline__ void store_out(unsigned short* p, float v) { *p = f2bf(v); }
__device__ __forceinline__ void store_out(float* p, float v) { *p = v; }

// ---------------- weight cast fp32 -> bf16 ----------------
__global__ __launch_bounds__(256) void cast_w_kernel(const float* __restrict__ in,
                                                     unsigned short* __restrict__ out, int n4) {
  int i = blockIdx.x * 256 + threadIdx.x;
  if (i >= n4) return;
  float4 v = ((const float4*)in)[i];
  ushort4 o;
  o.x = f2bf(v.x); o.y = f2bf(v.y); o.z = f2bf(v.z); o.w = f2bf(v.w);
  ((ushort4*)out)[i] = o;
}

// ---------------- RMSNorm (fp32 in, bf16 out) ----------------
__global__ __launch_bounds__(256) void rmsnorm_kernel(const float* __restrict__ x,
                                                      const float* __restrict__ w,
                                                      unsigned short* __restrict__ h) {
  int row = blockIdx.x;
  int t = threadIdx.x;
  const float4* xr4 = (const float4*)(x + (size_t)row * HID);
  float4 a = xr4[t], b = xr4[t + 256];
  float ss = a.x*a.x + a.y*a.y + a.z*a.z + a.w*a.w
           + b.x*b.x + b.y*b.y + b.z*b.z + b.w*b.w;
#pragma unroll
  for (int off = 32; off >= 1; off >>= 1) ss += __shfl_xor(ss, off, 64);
  __shared__ float red[4];
  if ((t & 63) == 0) red[t >> 6] = ss;
  __syncthreads();
  float tot = red[0] + red[1] + red[2] + red[3];
  float rs = rsqrtf(tot * (1.0f / (float)HID) + 1e-6f);
  const float4* w4 = (const float4*)w;
  float4 wa = w4[t], wb = w4[t + 256];
  ushort4 oa, ob;
  oa.x = f2bf(a.x * wa.x * rs); oa.y = f2bf(a.y * wa.y * rs);
  oa.z = f2bf(a.z * wa.z * rs); oa.w = f2bf(a.w * wa.w * rs);
  ob.x = f2bf(b.x * wb.x * rs); ob.y = f2bf(b.y * wb.y * rs);
  ob.z = f2bf(b.z * wb.z * rs); ob.w = f2bf(b.w * wb.w * rs);
  ushort4* hr = (ushort4*)(h + (size_t)row * HID);
  hr[t] = oa; hr[t + 256] = ob;
}

// ---------------- RoPE tables ----------------
__global__ void rope_tab_kernel(float* __restrict__ cost, float* __restrict__ sint) {
  int s = blockIdx.x, j = threadIdx.x;  // 64 threads
  float inv = powf(10000.0f, -((float)j) / 64.0f);
  float ang = (float)s * inv;
  cost[s * 64 + j] = cosf(ang);
  sint[s * 64 + j] = sinf(ang);
}

// ---------------- RoPE apply in-place on q,k inside fused qkv ----------------
// q additionally scaled by 1/sqrt(HDIM) so attention skips the multiply.
__global__ __launch_bounds__(256) void rope_kernel(const int* __restrict__ pos_ids,
                                                   const float* __restrict__ cost,
                                                   const float* __restrict__ sint,
                                                   unsigned short* __restrict__ qkv) {
  int row = blockIdx.x;            // b*S + s
  int p = pos_ids[row];
  int t = threadIdx.x;
  int head = t >> 4;
  int j0 = (t & 15) * 4;
  size_t base = (size_t)row * QS + head * HDIM;
  float4 c = *(const float4*)(cost + p * 64 + j0);
  float4 s = *(const float4*)(sint + p * 64 + j0);
#pragma unroll
  for (int which = 0; which < 2; which++) {
    unsigned short* ptr = qkv + base + which * HID;  // q then k
    float sc = which ? 1.0f : ATT_SCALE;
    ushort4 v1 = *(ushort4*)(ptr + j0);
    ushort4 v2 = *(ushort4*)(ptr + 64 + j0);
    ushort4 o1, o2;
    o1.x = f2bf((bf2f(v1.x) * c.x - bf2f(v2.x) * s.x) * sc);
    o1.y = f2bf((bf2f(v1.y) * c.y - bf2f(v2.y) * s.y) * sc);
    o1.z = f2bf((bf2f(v1.z) * c.z - bf2f(v2.z) * s.z) * sc);
    o1.w = f2bf((bf2f(v1.w) * c.w - bf2f(v2.w) * s.w) * sc);
    o2.x = f2bf((bf2f(v2.x) * c.x + bf2f(v1.x) * s.x) * sc);
    o2.y = f2bf((bf2f(v2.y) * c.y + bf2f(v1.y) * s.y) * sc);
    o2.z = f2bf((bf2f(v2.z) * c.z + bf2f(v1.z) * s.z) * sc);
    o2.w = f2bf((bf2f(v2.w) * c.w + bf2f(v1.w) * s.w) * sc);
    *(ushort4*)(ptr + j0) = o1;
    *(ushort4*)(ptr + 64 + j0) = o2;
  }
}

// ---------------- V transpose: qkv v-block [tok][d] -> vt [bh*128+d][S] ----------------
__global__ __launch_bounds__(256) void transpose_v_kernel(const unsigned short* __restrict__ qkv,
                                                          unsigned short* __restrict__ vt) {
  __shared__ unsigned short tile[64][72];
  const int stile = blockIdx.x, dt = blockIdx.y, bh = blockIdx.z;
  const int t = threadIdx.x;
  const int b = bh >> 4, h = bh & 15;
  const int s0 = stile * 64;
  const unsigned short* src = qkv + (size_t)(b * S_LEN + s0) * QS + 2 * HID + h * HDIM + dt * 64;
#pragma unroll
  for (int it = 0; it < 2; it++) {
    int sl = (t >> 3) + 32 * it;
    int dl = (t & 7) * 8;
    *(s16x8*)&tile[sl][dl] = *(const s16x8*)(src + (size_t)sl * QS + dl);
  }
  __syncthreads();
#pragma unroll
  for (int it = 0; it < 2; it++) {
    int dl = (t >> 3) + 32 * it;
    int sl8 = (t & 7) * 8;
    s16x8 o;
#pragma unroll
    for (int jj = 0; jj < 8; jj++) o[jj] = (short)tile[sl8 + jj][dl];
    *(s16x8*)(vt + (size_t)(bh * 128 + dt * 64 + dl) * S_LEN + s0 + sl8) = o;
  }
}

// ---------------- GEMM: C[m,n] = sum_k A[m,k]*B[n,k] ----------------
template <typename OutT>
__global__ __launch_bounds__(256) void gemm_bt_kernel(const unsigned short* __restrict__ A,
                                                      const unsigned short* __restrict__ B,
                                                      OutT* __restrict__ C, int K, int N) {
  __shared__ __align__(16) unsigned short As[128 * 32];
  __shared__ __align__(16) unsigned short Bs[128 * 32];
  const int m0 = blockIdx.y * 128, n0 = blockIdx.x * 128;
  const int tid = threadIdx.x;
  const int w = tid >> 6, l = tid & 63, g = l >> 4, r = l & 15;
  const int wm = (w >> 1) * 64, wn = (w & 1) * 64;

  f32x4 zero = {0.f, 0.f, 0.f, 0.f};
  f32x4 acc[4][4];
#pragma unroll
  for (int mi = 0; mi < 4; mi++)
#pragma unroll
    for (int ni = 0; ni < 4; ni++) acc[mi][ni] = zero;

  const int rowA0 = tid >> 2, koff = (tid & 3) * 8;
  const unsigned short* ag0 = A + (size_t)(m0 + rowA0) * K + koff;
  const unsigned short* ag1 = A + (size_t)(m0 + rowA0 + 64) * K + koff;
  const unsigned short* bg0 = B + (size_t)(n0 + rowA0) * K + koff;
  const unsigned short* bg1 = B + (size_t)(n0 + rowA0 + 64) * K + koff;
  unsigned short* al0 = As + tid * 8;
  unsigned short* al1 = As + (tid + 256) * 8;
  unsigned short* bl0 = Bs + tid * 8;
  unsigned short* bl1 = Bs + (tid + 256) * 8;

  for (int k0 = 0; k0 < K; k0 += 32) {
    GLL16(ag0 + k0, al0);
    GLL16(ag1 + k0, al1);
    GLL16(bg0 + k0, bl0);
    GLL16(bg1 + k0, bl1);
    __syncthreads();
    s16x8 af[4], bfr[4];
#pragma unroll
    for (int mi = 0; mi < 4; mi++)
      af[mi] = *(const s16x8*)(As + (wm + mi * 16 + r) * 32 + g * 8);
#pragma unroll
    for (int ni = 0; ni < 4; ni++)
      bfr[ni] = *(const s16x8*)(Bs + (wn + ni * 16 + r) * 32 + g * 8);
#pragma unroll
    for (int mi = 0; mi < 4; mi++)
#pragma unroll
      for (int ni = 0; ni < 4; ni++)
        acc[mi][ni] = __builtin_amdgcn_mfma_f32_16x16x32_bf16(af[mi], bfr[ni], acc[mi][ni], 0, 0, 0);
    __syncthreads();
  }
#pragma unroll
  for (int mi = 0; mi < 4; mi++) {
#pragma unroll
    for (int ni = 0; ni < 4; ni++) {
      const int crow = m0 + wm + mi * 16 + g * 4;
      const int ccol = n0 + wn + ni * 16 + r;
#pragma unroll
      for (int j = 0; j < 4; j++)
        store_out(&C[(size_t)(crow + j) * N + ccol], acc[mi][ni][j]);
    }
  }
}

// ---------------- Flash attention, causal, paired q-tiles ----------------
// 256 blocks x 512 threads. Block p-pair: waves 0-3 -> q-tile qtA=8+p,
// waves 4-7 -> q-tile qtB=7-p (shared KV stream, uniform total work).
// bh chunked by blockIdx%8 -> same-XCD L2 reuse of K/V (4MB working set).
// KV staged via global_load_lds, double-buffered, 2-phase overlap.
__global__ __launch_bounds__(512) void attn_kernel(const unsigned short* __restrict__ QKV,
                                                   const unsigned short* __restrict__ VT,
                                                   unsigned short* __restrict__ O) {
  __shared__ __align__(16) unsigned short Ksm[2][64 * 128];    // 2x16KB swizzled
  __shared__ __align__(16) unsigned short VTsm[2][128 * 64];   // 2x16KB swizzled
  __shared__ __align__(16) unsigned short Psm[8 * 32 * 64];    // 32KB per-wave
  const int bid = blockIdx.x;
  const int grp = bid & 7, j = bid >> 3;
  const int bh = (grp << 2) | (j & 3);
  const int pr = j >> 2;                 // 0..7
  const int qtA = 8 + pr, qtB = 7 - pr;
  const int b = bh >> 4, hd = bh & 15;
  const int tid = threadIdx.x, w = tid >> 6, l = tid & 63, g = l >> 4, r = l & 15;
  const int qbs = (w < 4 ? qtA : qtB) * 128 + (w & 3) * 32;  // wave's q-row base

  // Q fragments (already pre-scaled by 1/sqrt(D) in rope)
  s16x8 qf[2][4];
#pragma unroll
  for (int s = 0; s < 2; s++) {
    const unsigned short* qp = QKV + (size_t)(b * S_LEN + qbs + s * 16 + r) * QS + hd * HDIM;
#pragma unroll
    for (int ks = 0; ks < 4; ks++) qf[s][ks] = *(const s16x8*)(qp + ks * 32 + g * 8);
  }

  float mreg[2][4], lreg[2][4];
  f32x4 zero = {0.f, 0.f, 0.f, 0.f};
  f32x4 oacc[2][8];
#pragma unroll
  for (int s = 0; s < 2; s++)
#pragma unroll
    for (int jj = 0; jj < 4; jj++) { mreg[s][jj] = -1e30f; lreg[s][jj] = 0.f; }
#pragma unroll
  for (int s = 0; s < 2; s++)
#pragma unroll
    for (int di = 0; di < 8; di++) oacc[s][di] = zero;

  // staging bases: K rows tid>>4 (+32), V^T rows tid>>3 (+64); granule swizzle ^(row&7)
  const int cK = tid & 15, rowK = tid >> 4;            // 0..31
  const unsigned short* kp_base = QKV + (size_t)(b * S_LEN + rowK) * QS + HID + hd * HDIM
                                  + ((cK ^ (rowK & 7)) << 3);
  const int cV = tid & 7, dV = tid >> 3;               // 0..63
  const unsigned short* vp_base = VT + (size_t)(bh * 128 + dV) * S_LEN + ((cV ^ (dV & 7)) << 3);
  char* const ksm0 = (char*)Ksm;
  char* const vtsm0 = (char*)VTsm;
  char* const psm_w = (char*)Psm + w * 4096;

#define STAGE(kt, bufi)                                                        \
  {                                                                            \
    const unsigned short* kp_ = kp_base + (size_t)((kt) * 64) * QS;            \
    const unsigned short* vp_ = vp_base + (kt) * 64;                           \
    char* kd_ = ksm0 + (bufi) * 16384;                                         \
    char* vd_ = vtsm0 + (bufi) * 16384;                                        \
    GLL16(kp_, kd_ + tid * 16);                                                \
    GLL16(kp_ + (size_t)32 * QS, kd_ + (tid + 512) * 16);                      \
    GLL16(vp_, vd_ + tid * 16);                                                \
    GLL16(vp_ + (size_t)64 * S_LEN, vd_ + (tid + 512) * 16);                   \
  }

  const int nt = 2 * qtA + 2;
  STAGE(0, 0);
  asm volatile("s_waitcnt vmcnt(0)" ::: "memory");
  __builtin_amdgcn_s_barrier();
  __builtin_amdgcn_sched_barrier(0);

  for (int kt2 = 0; kt2 < nt; kt2++) {
    const int buf = kt2 & 1;
    if (kt2 + 1 < nt) STAGE(kt2 + 1, buf ^ 1);

    const bool active = (kt2 * 64) <= (qbs + 31);
    if (active) {
      const char* ksm_c = ksm0 + buf * 16384;
      const char* vtsm_c = vtsm0 + buf * 16384;
      // S = Q K^T
      f32x4 sacc[2][4];
#pragma unroll
      for (int s = 0; s < 2; s++)
#pragma unroll
        for (int ni = 0; ni < 4; ni++) sacc[s][ni] = zero;
#pragma unroll
      for (int ni = 0; ni < 4; ni++) {
        const int krow = ni * 16 + r;
        const int swz = (krow & 7) << 4;
        const char* kb2 = ksm_c + krow * 256;
#pragma unroll
        for (int ks = 0; ks < 4; ks++) {
          s16x8 kf = *(const s16x8*)(kb2 + ((ks * 64 + g * 16) ^ swz));
#pragma unroll
          for (int s = 0; s < 2; s++)
            sacc[s][ni] = __builtin_amdgcn_mfma_f32_16x16x32_bf16(qf[s][ks], kf, sacc[s][ni], 0, 0, 0);
        }
      }

      // online softmax per subtile
#pragma unroll
      for (int s = 0; s < 2; s++) {
        const int qb_s = qbs + s * 16;
        const bool domask = (kt2 * 64 + 63) > qb_s;
        float mrow[4];
#pragma unroll
        for (int jj = 0; jj < 4; jj++) mrow[jj] = -1e30f;
#pragma unroll
        for (int ni = 0; ni < 4; ni++)
#pragma unroll
          for (int jj = 0; jj < 4; jj++) {
            float sval = sacc[s][ni][jj];
            if (domask && (kt2 * 64 + ni * 16 + r) > (qb_s + g * 4 + jj)) sval = -1e30f;
            sacc[s][ni][jj] = sval;
            mrow[jj] = fmaxf(mrow[jj], sval);
          }
#pragma unroll
        for (int jj = 0; jj < 4; jj++) {
#pragma unroll
          for (int off = 8; off >= 1; off >>= 1)
            mrow[jj] = fmaxf(mrow[jj], __shfl_xor(mrow[jj], off, 64));
        }
        float corr[4];
#pragma unroll
        for (int jj = 0; jj < 4; jj++) {
          float mn = fmaxf(mreg[s][jj], mrow[jj]);
          corr[jj] = __expf(mreg[s][jj] - mn);
          mreg[s][jj] = mn;
          float sm = 0.f;
#pragma unroll
          for (int ni = 0; ni < 4; ni++) {
            float p = __expf(sacc[s][ni][jj] - mn);
            sacc[s][ni][jj] = p;
            sm += p;
          }
#pragma unroll
          for (int off = 8; off >= 1; off >>= 1) sm += __shfl_xor(sm, off, 64);
          lreg[s][jj] = lreg[s][jj] * corr[jj] + sm;
        }
#pragma unroll
        for (int di = 0; di < 8; di++)
#pragma unroll
          for (int jj = 0; jj < 4; jj++) oacc[s][di][jj] *= corr[jj];

        // P -> wave-private LDS (swizzled)
#pragma unroll
        for (int ni = 0; ni < 4; ni++)
#pragma unroll
          for (int jj = 0; jj < 4; jj++) {
            int prow = s * 16 + g * 4 + jj;
            int byte = (prow * 128 + ((ni * 16 + r) << 1)) ^ ((prow & 7) << 4);
            *(unsigned short*)(psm_w + byte) = f2bf(sacc[s][ni][jj]);
          }
      }

      // PV
#pragma unroll
      for (int ksl = 0; ksl < 2; ksl++) {
        s16x8 pa[2];
#pragma unroll
        for (int s = 0; s < 2; s++)
          pa[s] = *(const s16x8*)(psm_w + (((s * 16 + r) * 128 + ((ksl * 32 + g * 8) << 1)) ^ ((r & 7) << 4)));
        const int kgran = ksl * 4 + g;
#pragma unroll
        for (int di = 0; di < 8; di++) {
          const int d = di * 16 + r;
          s16x8 vf = *(const s16x8*)(vtsm_c + d * 128 + ((kgran ^ (d & 7)) << 4));
#pragma unroll
          for (int s = 0; s < 2; s++)
            oacc[s][di] = __builtin_amdgcn_mfma_f32_16x16x32_bf16(pa[s], vf, oacc[s][di], 0, 0, 0);
        }
      }
    }
    asm volatile("s_waitcnt vmcnt(0)" ::: "memory");
    __builtin_amdgcn_s_barrier();
    __builtin_amdgcn_sched_barrier(0);
  }
#undef STAGE

  // epilogue
#pragma unroll
  for (int s = 0; s < 2; s++)
#pragma unroll
    for (int di = 0; di < 8; di++)
#pragma unroll
      for (int jj = 0; jj < 4; jj++) {
        int orow = qbs + s * 16 + g * 4 + jj;
        O[(size_t)(b * S_LEN + orow) * HID + hd * HDIM + di * 16 + r] =
            f2bf(oacc[s][di][jj] / lreg[s][jj]);
      }
}

extern "C" void kernel_launch(void* const* d_in, const int* in_sizes, int n_in,
                              void* d_out, int out_size, void* d_ws, size_t ws_size,
                              hipStream_t stream) {
  const float* x      = (const float*)d_in[0];
  const float* norm_w = (const float*)d_in[1];
  const float* wq     = (const float*)d_in[2];
  const float* wk     = (const float*)d_in[3];
  const float* wv     = (const float*)d_in[4];
  const float* wo     = (const float*)d_in[5];
  const int*   pos    = (const int*)d_in[6];
  float* out = (float*)d_out;

  char* ws = (char*)d_ws;
  const size_t WQKV_B = (size_t)3 * HID * HID * 2;   // 24 MB (region A)
  const size_t VT_B   = (size_t)ROWS * HID * 2;      // 16 MB (aliases region A after qkv gemm)
  const size_t H_B    = (size_t)ROWS * HID * 2;      // 16 MB
  const size_t QKV_B  = (size_t)ROWS * QS * 2;       // 48 MB

  unsigned short* wqkvb = (unsigned short*)(ws);            // region A
  unsigned short* vt    = (unsigned short*)(ws);            // reuses region A
  unsigned short* wob   = (unsigned short*)(ws + VT_B);     // region A + 16MB
  unsigned short* h     = (unsigned short*)(ws + WQKV_B);   // also ctx
  unsigned short* qkv   = (unsigned short*)(ws + WQKV_B + H_B);
  float* cost = (float*)(ws + WQKV_B + H_B + QKV_B);
  float* sint = cost + (size_t)S_LEN * 64;

  const int n4 = HID * HID / 4;
  cast_w_kernel<<<n4 / 256, 256, 0, stream>>>(wq, wqkvb, n4);
  cast_w_kernel<<<n4 / 256, 256, 0, stream>>>(wk, wqkvb + (size_t)HID * HID, n4);
  cast_w_kernel<<<n4 / 256, 256, 0, stream>>>(wv, wqkvb + (size_t)2 * HID * HID, n4);
  rope_tab_kernel<<<S_LEN, 64, 0, stream>>>(cost, sint);
  rmsnorm_kernel<<<ROWS, 256, 0, stream>>>(x, norm_w, h);

  dim3 qkvgrid(QS / 128, ROWS / 128);   // 48 x 32
  gemm_bt_kernel<unsigned short><<<qkvgrid, 256, 0, stream>>>(h, wqkvb, qkv, HID, QS);

  // region A is dead now: cast wo into it, build V^T in it
  cast_w_kernel<<<n4 / 256, 256, 0, stream>>>(wo, wob, n4);
  dim3 tgrid(S_LEN / 64, 2, BATCH * NHEADS);
  transpose_v_kernel<<<tgrid, 256, 0, stream>>>(qkv, vt);

  rope_kernel<<<ROWS, 256, 0, stream>>>(pos, cost, sint, qkv);

  attn_kernel<<<256, 512, 0, stream>>>(qkv, vt, h /* ctx */);

  dim3 ogrid(HID / 128, ROWS / 128);
  gemm_bt_kernel<float><<<ogrid, 256, 0, stream>>>(h, wob, out, HID, HID);
}

// Round 4
// 340.869 us; speedup vs baseline: 1.5269x; 1.0262x over previous
//
#include <hip/hip_runtime.h>
#include <hip/hip_bf16.h>
#include <stdint.h>

#define S_LEN   2048
#define BATCH   2
#define HID     2048
#define NHEADS  16
#define HDIM    128
#define ROWS    (BATCH * S_LEN)          // 4096
#define QS      6144                     // qkv row stride (3*HID)
#define ATT_SCALE 0.08838834764831843f   // 1/sqrt(128)

typedef __attribute__((ext_vector_type(8))) short s16x8;
typedef __attribute__((ext_vector_type(4))) float f32x4;

#define GLL16(gp, lp)                                                          \
  __builtin_amdgcn_global_load_lds(                                            \
      (__attribute__((address_space(1))) void*)(gp),                           \
      (__attribute__((address_space(3))) void*)(lp), 16, 0, 0)

__device__ __forceinline__ float bf2f(unsigned short u) {
  union { unsigned int i; float f; } v; v.i = ((unsigned int)u) << 16; return v.f;
}
__device__ __forceinline__ unsigned short f2bf(float f) {
  union { float f; unsigned int i; } v; v.f = f;
  unsigned int i = v.i;
  return (unsigned short)((i + 0x7FFFu + ((i >> 16) & 1u)) >> 16);
}
__device__ __forceinline__ void store_out(unsigned short* p, float v) { *p = f2bf(v); }
__device__ __forceinline__ void store_out(float* p, float v) { *p = v; }

// ---------------- weight cast fp32 -> bf16 ----------------
__global__ __launch_bounds__(256) void cast_w_kernel(const float* __restrict__ in,
                                                     unsigned short* __restrict__ out, int n4) {
  int i = blockIdx.x * 256 + threadIdx.x;
  if (i >= n4) return;
  float4 v = ((const float4*)in)[i];
  ushort4 o;
  o.x = f2bf(v.x); o.y = f2bf(v.y); o.z = f2bf(v.z); o.w = f2bf(v.w);
  ((ushort4*)out)[i] = o;
}

// ---------------- RMSNorm (fp32 in, bf16 out) ----------------
__global__ __launch_bounds__(256) void rmsnorm_kernel(const float* __restrict__ x,
                                                      const float* __restrict__ w,
                                                      unsigned short* __restrict__ h) {
  int row = blockIdx.x;
  int t = threadIdx.x;
  const float4* xr4 = (const float4*)(x + (size_t)row * HID);
  float4 a = xr4[t], b = xr4[t + 256];
  float ss = a.x*a.x + a.y*a.y + a.z*a.z + a.w*a.w
           + b.x*b.x + b.y*b.y + b.z*b.z + b.w*b.w;
#pragma unroll
  for (int off = 32; off >= 1; off >>= 1) ss += __shfl_xor(ss, off, 64);
  __shared__ float red[4];
  if ((t & 63) == 0) red[t >> 6] = ss;
  __syncthreads();
  float tot = red[0] + red[1] + red[2] + red[3];
  float rs = rsqrtf(tot * (1.0f / (float)HID) + 1e-6f);
  const float4* w4 = (const float4*)w;
  float4 wa = w4[t], wb = w4[t + 256];
  ushort4 oa, ob;
  oa.x = f2bf(a.x * wa.x * rs); oa.y = f2bf(a.y * wa.y * rs);
  oa.z = f2bf(a.z * wa.z * rs); oa.w = f2bf(a.w * wa.w * rs);
  ob.x = f2bf(b.x * wb.x * rs); ob.y = f2bf(b.y * wb.y * rs);
  ob.z = f2bf(b.z * wb.z * rs); ob.w = f2bf(b.w * wb.w * rs);
  ushort4* hr = (ushort4*)(h + (size_t)row * HID);
  hr[t] = oa; hr[t + 256] = ob;
}

// ---------------- RoPE tables ----------------
__global__ void rope_tab_kernel(float* __restrict__ cost, float* __restrict__ sint) {
  int s = blockIdx.x, j = threadIdx.x;  // 64 threads
  float inv = powf(10000.0f, -((float)j) / 64.0f);
  float ang = (float)s * inv;
  cost[s * 64 + j] = cosf(ang);
  sint[s * 64 + j] = sinf(ang);
}

// ---------------- RoPE apply in-place on q,k inside fused qkv ----------------
// q additionally scaled by 1/sqrt(HDIM) so attention skips the multiply.
__global__ __launch_bounds__(256) void rope_kernel(const int* __restrict__ pos_ids,
                                                   const float* __restrict__ cost,
                                                   const float* __restrict__ sint,
                                                   unsigned short* __restrict__ qkv) {
  int row = blockIdx.x;            // b*S + s
  int p = pos_ids[row];
  int t = threadIdx.x;
  int head = t >> 4;
  int j0 = (t & 15) * 4;
  size_t base = (size_t)row * QS + head * HDIM;
  float4 c = *(const float4*)(cost + p * 64 + j0);
  float4 s = *(const float4*)(sint + p * 64 + j0);
#pragma unroll
  for (int which = 0; which < 2; which++) {
    unsigned short* ptr = qkv + base + which * HID;  // q then k
    float sc = which ? 1.0f : ATT_SCALE;
    ushort4 v1 = *(ushort4*)(ptr + j0);
    ushort4 v2 = *(ushort4*)(ptr + 64 + j0);
    ushort4 o1, o2;
    o1.x = f2bf((bf2f(v1.x) * c.x - bf2f(v2.x) * s.x) * sc);
    o1.y = f2bf((bf2f(v1.y) * c.y - bf2f(v2.y) * s.y) * sc);
    o1.z = f2bf((bf2f(v1.z) * c.z - bf2f(v2.z) * s.z) * sc);
    o1.w = f2bf((bf2f(v1.w) * c.w - bf2f(v2.w) * s.w) * sc);
    o2.x = f2bf((bf2f(v2.x) * c.x + bf2f(v1.x) * s.x) * sc);
    o2.y = f2bf((bf2f(v2.y) * c.y + bf2f(v1.y) * s.y) * sc);
    o2.z = f2bf((bf2f(v2.z) * c.z + bf2f(v1.z) * s.z) * sc);
    o2.w = f2bf((bf2f(v2.w) * c.w + bf2f(v1.w) * s.w) * sc);
    *(ushort4*)(ptr + j0) = o1;
    *(ushort4*)(ptr + 64 + j0) = o2;
  }
}

// ---------------- V transpose: qkv v-block [tok][d] -> vt [bh*128+d][S] ----------------
__global__ __launch_bounds__(256) void transpose_v_kernel(const unsigned short* __restrict__ qkv,
                                                          unsigned short* __restrict__ vt) {
  __shared__ unsigned short tile[64][72];
  const int stile = blockIdx.x, dt = blockIdx.y, bh = blockIdx.z;
  const int t = threadIdx.x;
  const int b = bh >> 4, h = bh & 15;
  const int s0 = stile * 64;
  const unsigned short* src = qkv + (size_t)(b * S_LEN + s0) * QS + 2 * HID + h * HDIM + dt * 64;
#pragma unroll
  for (int it = 0; it < 2; it++) {
    int sl = (t >> 3) + 32 * it;
    int dl = (t & 7) * 8;
    *(s16x8*)&tile[sl][dl] = *(const s16x8*)(src + (size_t)sl * QS + dl);
  }
  __syncthreads();
#pragma unroll
  for (int it = 0; it < 2; it++) {
    int dl = (t >> 3) + 32 * it;
    int sl8 = (t & 7) * 8;
    s16x8 o;
#pragma unroll
    for (int jj = 0; jj < 8; jj++) o[jj] = (short)tile[sl8 + jj][dl];
    *(s16x8*)(vt + (size_t)(bh * 128 + dt * 64 + dl) * S_LEN + s0 + sl8) = o;
  }
}

// ---------------- Pipelined GEMM: C[m,n] = sum_k A[m,k]*B[n,k] ----------------
// 128(M)x256(N) tile, BK=64, 512 thr / 8 waves (2M x 4N), 96KB LDS double-buffer.
// Counted vmcnt(4) (never 0 mid-loop), granule XOR-swizzle on stage-src + ds_read,
// 2 barriers per K-tile, setprio around MFMA quadrants.
#define STG_A(ktile, bufi) {                                                   \
    const unsigned short* s_ = aSrc + (size_t)(ktile) * 64;                    \
    char* d_ = la0 + (bufi) * 16384 + tid * 16;                                \
    GLL16(s_, d_);                                                             \
    GLL16(s_ + (size_t)64 * K, d_ + 8192);                                     \
  }
#define STG_B0(ktile, bufi) {                                                  \
    const unsigned short* s_ = bSrc + (size_t)(ktile) * 64;                    \
    char* d_ = lb0 + (bufi) * 32768 + tid * 16;                                \
    GLL16(s_, d_);                                                             \
    GLL16(s_ + (size_t)64 * K, d_ + 8192);                                     \
  }
#define STG_B1(ktile, bufi) {                                                  \
    const unsigned short* s_ = bSrc + (size_t)128 * K + (size_t)(ktile) * 64;  \
    char* d_ = lb0 + (bufi) * 32768 + 16384 + tid * 16;                        \
    GLL16(s_, d_);                                                             \
    GLL16(s_ + (size_t)64 * K, d_ + 8192);                                     \
  }

template <typename OutT>
__global__ __launch_bounds__(512, 2) void gemm256_kernel(const unsigned short* __restrict__ A,
                                                         const unsigned short* __restrict__ B,
                                                         OutT* __restrict__ C, int K, int N) {
  __shared__ __align__(16) unsigned short LA[2][128][64];      // 32 KB [buf][row][k]
  __shared__ __align__(16) unsigned short LB[2][2][128][64];   // 64 KB [buf][half][row][k]
  const int NBM = gridDim.y, NBN = gridDim.x;
  int lin = blockIdx.y * NBN + blockIdx.x;
  const int cpx = (NBM * NBN) >> 3;            // nwg % 8 == 0 guaranteed by host
  lin = (lin & 7) * cpx + (lin >> 3);          // XCD-chunked swizzle
  const int bm = lin % NBM, bn = lin / NBM;    // bm-fast: chunk shares B panels
  const int tid = threadIdx.x;
  const int w = tid >> 6, wr = w >> 2, wc = w & 3;
  const int l = tid & 63, g = l >> 4, r = l & 15;
  const int KT = K >> 6;

  // staging source (granule-swizzled so linear LDS dest ends up XOR-swizzled)
  const int srow = tid >> 3;                   // 0..63
  const int sg = (tid & 7) ^ (srow & 7);
  const unsigned short* aSrc = A + (size_t)(bm * 128 + srow) * K + sg * 8;
  const unsigned short* bSrc = B + (size_t)(bn * 256 + srow) * K + sg * 8;
  char* const la0 = (char*)LA;
  char* const lb0 = (char*)LB;

  f32x4 zero = {0.f, 0.f, 0.f, 0.f};
  f32x4 acc[4][4];
#pragma unroll
  for (int mi = 0; mi < 4; mi++)
#pragma unroll
    for (int ni = 0; ni < 4; ni++) acc[mi][ni] = zero;

  const int kc0 = (g << 4);          // kk=0 granule byte (pre-XOR)
  const int kc1 = ((4 | g) << 4);    // kk=1
  const int swx = (r & 7) << 4;
  const int rA = wr * 64 + r;
  const int rB = (wc & 1) * 64 + r;

  // prologue: tile0 fully + tile1 B halves
  STG_A(0, 0);
  STG_B0(0, 0); STG_B1(0, 0);
  if (KT > 1) { STG_B0(1, 1); STG_B1(1, 1); }

  for (int kt = 0; kt < KT; ++kt) {
    const int buf = kt & 1;
    // needed now: A(kt) (issued last tile) + B(kt) (issued 2 tiles ago).
    // allowed in flight: B halves of kt+1 (4 loads) when they exist.
    if (kt + 1 < KT) { asm volatile("s_waitcnt vmcnt(4)" ::: "memory"); }
    else             { asm volatile("s_waitcnt vmcnt(0)" ::: "memory"); }
    __builtin_amdgcn_s_barrier();
    const char* lA = la0 + buf * 16384;
    const char* lB = lb0 + buf * 32768 + (wc >> 1) * 16384;

    s16x8 bfr[4][2];
#pragma unroll
    for (int ni = 0; ni < 4; ni++) {
      const char* p = lB + (rB + ni * 16) * 128;
      bfr[ni][0] = *(const s16x8*)(p + (kc0 ^ swx));
      bfr[ni][1] = *(const s16x8*)(p + (kc1 ^ swx));
    }
    s16x8 a0[2][2];
#pragma unroll
    for (int i = 0; i < 2; i++) {
      const char* p = lA + (rA + i * 16) * 128;
      a0[i][0] = *(const s16x8*)(p + (kc0 ^ swx));
      a0[i][1] = *(const s16x8*)(p + (kc1 ^ swx));
    }
    if (kt + 1 < KT) STG_A(kt + 1, buf ^ 1);   // A region of buf^1 free since prev tile
    asm volatile("s_waitcnt lgkmcnt(0)" ::: "memory");
    __builtin_amdgcn_s_barrier();              // all waves' reads of buf B/A-q0 done
    __builtin_amdgcn_sched_barrier(0);

    __builtin_amdgcn_s_setprio(1);
#pragma unroll
    for (int kk = 0; kk < 2; kk++)
#pragma unroll
      for (int ni = 0; ni < 4; ni++)
#pragma unroll
        for (int i = 0; i < 2; i++)
          acc[i][ni] = __builtin_amdgcn_mfma_f32_16x16x32_bf16(a0[i][kk], bfr[ni][kk], acc[i][ni], 0, 0, 0);
    __builtin_amdgcn_s_setprio(0);

    if (kt + 2 < KT) STG_B0(kt + 2, buf);      // B0 of buf freed by this tile's reads

    s16x8 a1[2][2];
#pragma unroll
    for (int i = 0; i < 2; i++) {
      const char* p = lA + (rA + 32 + i * 16) * 128;
      a1[i][0] = *(const s16x8*)(p + (kc0 ^ swx));
      a1[i][1] = *(const s16x8*)(p + (kc1 ^ swx));
    }
    if (kt + 2 < KT) STG_B1(kt + 2, buf);

    __builtin_amdgcn_s_setprio(1);
#pragma unroll
    for (int kk = 0; kk < 2; kk++)
#pragma unroll
      for (int ni = 0; ni < 4; ni++)
#pragma unroll
        for (int i = 0; i < 2; i++)
          acc[2 + i][ni] = __builtin_amdgcn_mfma_f32_16x16x32_bf16(a1[i][kk], bfr[ni][kk], acc[2 + i][ni], 0, 0, 0);
    __builtin_amdgcn_s_setprio(0);
  }

  // epilogue
#pragma unroll
  for (int mi = 0; mi < 4; mi++)
#pragma unroll
    for (int ni = 0; ni < 4; ni++) {
      const int crow = bm * 128 + wr * 64 + mi * 16 + g * 4;
      const int ccol = bn * 256 + wc * 64 + ni * 16 + r;
#pragma unroll
      for (int j = 0; j < 4; j++)
        store_out(&C[(size_t)(crow + j) * N + ccol], acc[mi][ni][j]);
    }
}

// ---------------- Flash attention, causal, paired q-tiles ----------------
__global__ __launch_bounds__(512) void attn_kernel(const unsigned short* __restrict__ QKV,
                                                   const unsigned short* __restrict__ VT,
                                                   unsigned short* __restrict__ O) {
  __shared__ __align__(16) unsigned short Ksm[2][64 * 128];    // 2x16KB swizzled
  __shared__ __align__(16) unsigned short VTsm[2][128 * 64];   // 2x16KB swizzled
  __shared__ __align__(16) unsigned short Psm[8 * 32 * 64];    // 32KB per-wave
  const int bid = blockIdx.x;
  const int grp = bid & 7, j = bid >> 3;
  const int bh = (grp << 2) | (j & 3);
  const int pr = j >> 2;                 // 0..7
  const int qtA = 8 + pr, qtB = 7 - pr;
  const int b = bh >> 4, hd = bh & 15;
  const int tid = threadIdx.x, w = tid >> 6, l = tid & 63, g = l >> 4, r = l & 15;
  const int qbs = (w < 4 ? qtA : qtB) * 128 + (w & 3) * 32;  // wave's q-row base

  // Q fragments (already pre-scaled by 1/sqrt(D) in rope)
  s16x8 qf[2][4];
#pragma unroll
  for (int s = 0; s < 2; s++) {
    const unsigned short* qp = QKV + (size_t)(b * S_LEN + qbs + s * 16 + r) * QS + hd * HDIM;
#pragma unroll
    for (int ks = 0; ks < 4; ks++) qf[s][ks] = *(const s16x8*)(qp + ks * 32 + g * 8);
  }

  float mreg[2][4], lreg[2][4];
  f32x4 zero = {0.f, 0.f, 0.f, 0.f};
  f32x4 oacc[2][8];
#pragma unroll
  for (int s = 0; s < 2; s++)
#pragma unroll
    for (int jj = 0; jj < 4; jj++) { mreg[s][jj] = -1e30f; lreg[s][jj] = 0.f; }
#pragma unroll
  for (int s = 0; s < 2; s++)
#pragma unroll
    for (int di = 0; di < 8; di++) oacc[s][di] = zero;

  // staging bases: K rows tid>>4 (+32), V^T rows tid>>3 (+64); granule swizzle ^(row&7)
  const int cK = tid & 15, rowK = tid >> 4;            // 0..31
  const unsigned short* kp_base = QKV + (size_t)(b * S_LEN + rowK) * QS + HID + hd * HDIM
                                  + ((cK ^ (rowK & 7)) << 3);
  const int cV = tid & 7, dV = tid >> 3;               // 0..63
  const unsigned short* vp_base = VT + (size_t)(bh * 128 + dV) * S_LEN + ((cV ^ (dV & 7)) << 3);
  char* const ksm0 = (char*)Ksm;
  char* const vtsm0 = (char*)VTsm;
  char* const psm_w = (char*)Psm + w * 4096;

#define STAGE(kt, bufi)                                                        \
  {                                                                            \
    const unsigned short* kp_ = kp_base + (size_t)((kt) * 64) * QS;            \
    const unsigned short* vp_ = vp_base + (kt) * 64;                           \
    char* kd_ = ksm0 + (bufi) * 16384;                                         \
    char* vd_ = vtsm0 + (bufi) * 16384;                                        \
    GLL16(kp_, kd_ + tid * 16);                                                \
    GLL16(kp_ + (size_t)32 * QS, kd_ + (tid + 512) * 16);                      \
    GLL16(vp_, vd_ + tid * 16);                                                \
    GLL16(vp_ + (size_t)64 * S_LEN, vd_ + (tid + 512) * 16);                   \
  }

  const int nt = 2 * qtA + 2;
  STAGE(0, 0);
  asm volatile("s_waitcnt vmcnt(0)" ::: "memory");
  __builtin_amdgcn_s_barrier();
  __builtin_amdgcn_sched_barrier(0);

  for (int kt2 = 0; kt2 < nt; kt2++) {
    const int buf = kt2 & 1;
    if (kt2 + 1 < nt) STAGE(kt2 + 1, buf ^ 1);

    const bool active = (kt2 * 64) <= (qbs + 31);
    if (active) {
      const char* ksm_c = ksm0 + buf * 16384;
      const char* vtsm_c = vtsm0 + buf * 16384;
      // S = Q K^T
      f32x4 sacc[2][4];
#pragma unroll
      for (int s = 0; s < 2; s++)
#pragma unroll
        for (int ni = 0; ni < 4; ni++) sacc[s][ni] = zero;
#pragma unroll
      for (int ni = 0; ni < 4; ni++) {
        const int krow = ni * 16 + r;
        const int swz = (krow & 7) << 4;
        const char* kb2 = ksm_c + krow * 256;
#pragma unroll
        for (int ks = 0; ks < 4; ks++) {
          s16x8 kf = *(const s16x8*)(kb2 + ((ks * 64 + g * 16) ^ swz));
#pragma unroll
          for (int s = 0; s < 2; s++)
            sacc[s][ni] = __builtin_amdgcn_mfma_f32_16x16x32_bf16(qf[s][ks], kf, sacc[s][ni], 0, 0, 0);
        }
      }

      // online softmax per subtile
#pragma unroll
      for (int s = 0; s < 2; s++) {
        const int qb_s = qbs + s * 16;
        const bool domask = (kt2 * 64 + 63) > qb_s;
        float mrow[4];
#pragma unroll
        for (int jj = 0; jj < 4; jj++) mrow[jj] = -1e30f;
#pragma unroll
        for (int ni = 0; ni < 4; ni++)
#pragma unroll
          for (int jj = 0; jj < 4; jj++) {
            float sval = sacc[s][ni][jj];
            if (domask && (kt2 * 64 + ni * 16 + r) > (qb_s + g * 4 + jj)) sval = -1e30f;
            sacc[s][ni][jj] = sval;
            mrow[jj] = fmaxf(mrow[jj], sval);
          }
#pragma unroll
        for (int jj = 0; jj < 4; jj++) {
#pragma unroll
          for (int off = 8; off >= 1; off >>= 1)
            mrow[jj] = fmaxf(mrow[jj], __shfl_xor(mrow[jj], off, 64));
        }
        float corr[4];
#pragma unroll
        for (int jj = 0; jj < 4; jj++) {
          float mn = fmaxf(mreg[s][jj], mrow[jj]);
          corr[jj] = __expf(mreg[s][jj] - mn);
          mreg[s][jj] = mn;
          float sm = 0.f;
#pragma unroll
          for (int ni = 0; ni < 4; ni++) {
            float p = __expf(sacc[s][ni][jj] - mn);
            sacc[s][ni][jj] = p;
            sm += p;
          }
#pragma unroll
          for (int off = 8; off >= 1; off >>= 1) sm += __shfl_xor(sm, off, 64);
          lreg[s][jj] = lreg[s][jj] * corr[jj] + sm;
        }
#pragma unroll
        for (int di = 0; di < 8; di++)
#pragma unroll
          for (int jj = 0; jj < 4; jj++) oacc[s][di][jj] *= corr[jj];

        // P -> wave-private LDS (swizzled)
#pragma unroll
        for (int ni = 0; ni < 4; ni++)
#pragma unroll
          for (int jj = 0; jj < 4; jj++) {
            int prow = s * 16 + g * 4 + jj;
            int byte = (prow * 128 + ((ni * 16 + r) << 1)) ^ ((prow & 7) << 4);
            *(unsigned short*)(psm_w + byte) = f2bf(sacc[s][ni][jj]);
          }
      }

      // PV
#pragma unroll
      for (int ksl = 0; ksl < 2; ksl++) {
        s16x8 pa[2];
#pragma unroll
        for (int s = 0; s < 2; s++)
          pa[s] = *(const s16x8*)(psm_w + (((s * 16 + r) * 128 + ((ksl * 32 + g * 8) << 1)) ^ ((r & 7) << 4)));
        const int kgran = ksl * 4 + g;
#pragma unroll
        for (int di = 0; di < 8; di++) {
          const int d = di * 16 + r;
          s16x8 vf = *(const s16x8*)(vtsm_c + d * 128 + ((kgran ^ (d & 7)) << 4));
#pragma unroll
          for (int s = 0; s < 2; s++)
            oacc[s][di] = __builtin_amdgcn_mfma_f32_16x16x32_bf16(pa[s], vf, oacc[s][di], 0, 0, 0);
        }
      }
    }
    asm volatile("s_waitcnt vmcnt(0)" ::: "memory");
    __builtin_amdgcn_s_barrier();
    __builtin_amdgcn_sched_barrier(0);
  }
#undef STAGE

  // epilogue
#pragma unroll
  for (int s = 0; s < 2; s++)
#pragma unroll
    for (int di = 0; di < 8; di++)
#pragma unroll
      for (int jj = 0; jj < 4; jj++) {
        int orow = qbs + s * 16 + g * 4 + jj;
        O[(size_t)(b * S_LEN + orow) * HID + hd * HDIM + di * 16 + r] =
            f2bf(oacc[s][di][jj] / lreg[s][jj]);
      }
}

extern "C" void kernel_launch(void* const* d_in, const int* in_sizes, int n_in,
                              void* d_out, int out_size, void* d_ws, size_t ws_size,
                              hipStream_t stream) {
  const float* x      = (const float*)d_in[0];
  const float* norm_w = (const float*)d_in[1];
  const float* wq     = (const float*)d_in[2];
  const float* wk     = (const float*)d_in[3];
  const float* wv     = (const float*)d_in[4];
  const float* wo     = (const float*)d_in[5];
  const int*   pos    = (const int*)d_in[6];
  float* out = (float*)d_out;

  char* ws = (char*)d_ws;
  const size_t WQKV_B = (size_t)3 * HID * HID * 2;   // 24 MB (region A)
  const size_t VT_B   = (size_t)ROWS * HID * 2;      // 16 MB (aliases region A after qkv gemm)
  const size_t H_B    = (size_t)ROWS * HID * 2;      // 16 MB
  const size_t QKV_B  = (size_t)ROWS * QS * 2;       // 48 MB

  unsigned short* wqkvb = (unsigned short*)(ws);            // region A
  unsigned short* vt    = (unsigned short*)(ws);            // reuses region A
  unsigned short* wob   = (unsigned short*)(ws + VT_B);     // region A + 16MB
  unsigned short* h     = (unsigned short*)(ws + WQKV_B);   // also ctx
  unsigned short* qkv   = (unsigned short*)(ws + WQKV_B + H_B);
  float* cost = (float*)(ws + WQKV_B + H_B + QKV_B);
  float* sint = cost + (size_t)S_LEN * 64;

  const int n4 = HID * HID / 4;
  cast_w_kernel<<<n4 / 256, 256, 0, stream>>>(wq, wqkvb, n4);
  cast_w_kernel<<<n4 / 256, 256, 0, stream>>>(wk, wqkvb + (size_t)HID * HID, n4);
  cast_w_kernel<<<n4 / 256, 256, 0, stream>>>(wv, wqkvb + (size_t)2 * HID * HID, n4);
  rope_tab_kernel<<<S_LEN, 64, 0, stream>>>(cost, sint);
  rmsnorm_kernel<<<ROWS, 256, 0, stream>>>(x, norm_w, h);

  dim3 qkvgrid(QS / 256, ROWS / 128);   // 24 x 32 = 768 blocks (%8==0)
  gemm256_kernel<unsigned short><<<qkvgrid, 512, 0, stream>>>(h, wqkvb, qkv, HID, QS);

  // region A is dead now: cast wo into it, build V^T in it
  cast_w_kernel<<<n4 / 256, 256, 0, stream>>>(wo, wob, n4);
  dim3 tgrid(S_LEN / 64, 2, BATCH * NHEADS);
  transpose_v_kernel<<<tgrid, 256, 0, stream>>>(qkv, vt);

  rope_kernel<<<ROWS, 256, 0, stream>>>(pos, cost, sint, qkv);

  attn_kernel<<<256, 512, 0, stream>>>(qkv, vt, h /* ctx */);

  dim3 ogrid(HID / 256, ROWS / 128);    // 8 x 32 = 256 blocks (%8==0)
  gemm256_kernel<float><<<ogrid, 512, 0, stream>>>(h, wob, out, HID, HID);
}

// Round 5
// 334.873 us; speedup vs baseline: 1.5542x; 1.0179x over previous
//
#include <hip/hip_runtime.h>
#include <hip/hip_bf16.h>
#include <stdint.h>

#define S_LEN   2048
#define BATCH   2
#define HID     2048
#define NHEADS  16
#define HDIM    128
#define ROWS    (BATCH * S_LEN)          // 4096
#define QS      6144                     // qkv row stride (3*HID)
#define ATT_SCALE 0.08838834764831843f   // 1/sqrt(128)

typedef __attribute__((ext_vector_type(8))) short s16x8;
typedef __attribute__((ext_vector_type(4))) float f32x4;

#define GLL16(gp, lp)                                                          \
  __builtin_amdgcn_global_load_lds(                                            \
      (__attribute__((address_space(1))) void*)(gp),                           \
      (__attribute__((address_space(3))) void*)(lp), 16, 0, 0)

__device__ __forceinline__ float bf2f(unsigned short u) {
  union { unsigned int i; float f; } v; v.i = ((unsigned int)u) << 16; return v.f;
}
__device__ __forceinline__ unsigned short f2bf(float f) {
  union { float f; unsigned int i; } v; v.f = f;
  unsigned int i = v.i;
  return (unsigned short)((i + 0x7FFFu + ((i >> 16) & 1u)) >> 16);
}
__device__ __forceinline__ void store_out(unsigned short* p, float v) { *p = f2bf(v); }
__device__ __forceinline__ void store_out(float* p, float v) { *p = v; }

// ---------------- weight cast fp32 -> bf16 ----------------
__global__ __launch_bounds__(256) void cast_w_kernel(const float* __restrict__ in,
                                                     unsigned short* __restrict__ out, int n4) {
  int i = blockIdx.x * 256 + threadIdx.x;
  if (i >= n4) return;
  float4 v = ((const float4*)in)[i];
  ushort4 o;
  o.x = f2bf(v.x); o.y = f2bf(v.y); o.z = f2bf(v.z); o.w = f2bf(v.w);
  ((ushort4*)out)[i] = o;
}

// ---------------- RMSNorm (fp32 in, bf16 out) ----------------
__global__ __launch_bounds__(256) void rmsnorm_kernel(const float* __restrict__ x,
                                                      const float* __restrict__ w,
                                                      unsigned short* __restrict__ h) {
  int row = blockIdx.x;
  int t = threadIdx.x;
  const float4* xr4 = (const float4*)(x + (size_t)row * HID);
  float4 a = xr4[t], b = xr4[t + 256];
  float ss = a.x*a.x + a.y*a.y + a.z*a.z + a.w*a.w
           + b.x*b.x + b.y*b.y + b.z*b.z + b.w*b.w;
#pragma unroll
  for (int off = 32; off >= 1; off >>= 1) ss += __shfl_xor(ss, off, 64);
  __shared__ float red[4];
  if ((t & 63) == 0) red[t >> 6] = ss;
  __syncthreads();
  float tot = red[0] + red[1] + red[2] + red[3];
  float rs = rsqrtf(tot * (1.0f / (float)HID) + 1e-6f);
  const float4* w4 = (const float4*)w;
  float4 wa = w4[t], wb = w4[t + 256];
  ushort4 oa, ob;
  oa.x = f2bf(a.x * wa.x * rs); oa.y = f2bf(a.y * wa.y * rs);
  oa.z = f2bf(a.z * wa.z * rs); oa.w = f2bf(a.w * wa.w * rs);
  ob.x = f2bf(b.x * wb.x * rs); ob.y = f2bf(b.y * wb.y * rs);
  ob.z = f2bf(b.z * wb.z * rs); ob.w = f2bf(b.w * wb.w * rs);
  ushort4* hr = (ushort4*)(h + (size_t)row * HID);
  hr[t] = oa; hr[t + 256] = ob;
}

// ---------------- RoPE tables ----------------
__global__ void rope_tab_kernel(float* __restrict__ cost, float* __restrict__ sint) {
  int s = blockIdx.x, j = threadIdx.x;  // 64 threads
  float inv = powf(10000.0f, -((float)j) / 64.0f);
  float ang = (float)s * inv;
  cost[s * 64 + j] = cosf(ang);
  sint[s * 64 + j] = sinf(ang);
}

// ---------------- RoPE apply in-place on q,k inside fused qkv ----------------
// q additionally scaled by 1/sqrt(HDIM) so attention skips the multiply.
__global__ __launch_bounds__(256) void rope_kernel(const int* __restrict__ pos_ids,
                                                   const float* __restrict__ cost,
                                                   const float* __restrict__ sint,
                                                   unsigned short* __restrict__ qkv) {
  int row = blockIdx.x;            // b*S + s
  int p = pos_ids[row];
  int t = threadIdx.x;
  int head = t >> 4;
  int j0 = (t & 15) * 4;
  size_t base = (size_t)row * QS + head * HDIM;
  float4 c = *(const float4*)(cost + p * 64 + j0);
  float4 s = *(const float4*)(sint + p * 64 + j0);
#pragma unroll
  for (int which = 0; which < 2; which++) {
    unsigned short* ptr = qkv + base + which * HID;  // q then k
    float sc = which ? 1.0f : ATT_SCALE;
    ushort4 v1 = *(ushort4*)(ptr + j0);
    ushort4 v2 = *(ushort4*)(ptr + 64 + j0);
    ushort4 o1, o2;
    o1.x = f2bf((bf2f(v1.x) * c.x - bf2f(v2.x) * s.x) * sc);
    o1.y = f2bf((bf2f(v1.y) * c.y - bf2f(v2.y) * s.y) * sc);
    o1.z = f2bf((bf2f(v1.z) * c.z - bf2f(v2.z) * s.z) * sc);
    o1.w = f2bf((bf2f(v1.w) * c.w - bf2f(v2.w) * s.w) * sc);
    o2.x = f2bf((bf2f(v2.x) * c.x + bf2f(v1.x) * s.x) * sc);
    o2.y = f2bf((bf2f(v2.y) * c.y + bf2f(v1.y) * s.y) * sc);
    o2.z = f2bf((bf2f(v2.z) * c.z + bf2f(v1.z) * s.z) * sc);
    o2.w = f2bf((bf2f(v2.w) * c.w + bf2f(v1.w) * s.w) * sc);
    *(ushort4*)(ptr + j0) = o1;
    *(ushort4*)(ptr + 64 + j0) = o2;
  }
}

// ---------------- V transpose: qkv v-block [tok][d] -> vt [bh*128+d][S] ----------------
__global__ __launch_bounds__(256) void transpose_v_kernel(const unsigned short* __restrict__ qkv,
                                                          unsigned short* __restrict__ vt) {
  __shared__ unsigned short tile[64][72];
  const int stile = blockIdx.x, dt = blockIdx.y, bh = blockIdx.z;
  const int t = threadIdx.x;
  const int b = bh >> 4, h = bh & 15;
  const int s0 = stile * 64;
  const unsigned short* src = qkv + (size_t)(b * S_LEN + s0) * QS + 2 * HID + h * HDIM + dt * 64;
#pragma unroll
  for (int it = 0; it < 2; it++) {
    int sl = (t >> 3) + 32 * it;
    int dl = (t & 7) * 8;
    *(s16x8*)&tile[sl][dl] = *(const s16x8*)(src + (size_t)sl * QS + dl);
  }
  __syncthreads();
#pragma unroll
  for (int it = 0; it < 2; it++) {
    int dl = (t >> 3) + 32 * it;
    int sl8 = (t & 7) * 8;
    s16x8 o;
#pragma unroll
    for (int jj = 0; jj < 8; jj++) o[jj] = (short)tile[sl8 + jj][dl];
    *(s16x8*)(vt + (size_t)(bh * 128 + dt * 64 + dl) * S_LEN + s0 + sl8) = o;
  }
}

// ---------------- 4-phase pipelined GEMM: C[m,n] = sum_k A[m,k]*B[n,k] ----------------
// BM=128, BN=256, BK=64 (2 k-halves of 32), 512 thr / 8 waves (2M x 4N).
// LDS [2buf][2kk]: A 128x32 (8KB, 1 load/thr), B 256x32 (16KB, 2 loads/thr) = 96KB.
// Per K-tile: 4 phases, each {barrier; ds_read; stage 1 unit of kt+1; lgkm0; 8 MFMA}.
// vmcnt(3) at P0/P2 only: every unit lands 3-4 phases after issue. Never vmcnt(0)
// mid-loop. Granule swizzle ^((row^(row>>2))&3) on stage-src and ds_read (involution).
#define STG_A(kt, kk2) {                                                       \
    GLL16(aS + (size_t)(kt) * 64 + (kk2) * 32,                                 \
          (char*)Akh[(kt) & 1][kk2] + tid * 16);                               \
  }
#define STG_B(kt, kk2) {                                                       \
    const unsigned short* s_ = bS + (size_t)(kt) * 64 + (kk2) * 32;            \
    char* d_ = (char*)Bkh[(kt) & 1][kk2] + tid * 16;                           \
    GLL16(s_, d_);                                                             \
    GLL16(s_ + (size_t)128 * K, d_ + 8192);                                    \
  }

template <typename OutT>
__global__ __launch_bounds__(512, 2) void gemm_pipe_kernel(const unsigned short* __restrict__ A,
                                                           const unsigned short* __restrict__ B,
                                                           OutT* __restrict__ C, int K, int N) {
  __shared__ __align__(16) unsigned short Akh[2][2][128 * 32];  // 32 KB
  __shared__ __align__(16) unsigned short Bkh[2][2][256 * 32];  // 64 KB
  const int NBM = gridDim.y, NBN = gridDim.x;
  // XCD map: each XCD owns contiguous bm-slice (A L2-resident), bn-fast within.
  int p = blockIdx.y * NBN + blockIdx.x;
  const int xcd = p & 7;
  const int idx = p >> 3;
  const int bm = xcd * (NBM >> 3) + idx / NBN;
  const int bn = idx % NBN;
  const int tid = threadIdx.x;
  const int w = tid >> 6, wr = w >> 2, wc = w & 3;
  const int l = tid & 63, g = l >> 4, r = l & 15;
  const int KT = K >> 6;

  // staging source (granule pre-swizzled; linear LDS dest)
  const int srow = tid >> 2;                       // 0..127
  const int sgr = (tid & 3) ^ ((srow ^ (srow >> 2)) & 3);
  const unsigned short* aS = A + (size_t)(bm * 128 + srow) * K + sgr * 8;
  const unsigned short* bS = B + (size_t)(bn * 256 + srow) * K + sgr * 8;

  f32x4 zero = {0.f, 0.f, 0.f, 0.f};
  f32x4 acc[4][4];
#pragma unroll
  for (int mi = 0; mi < 4; mi++)
#pragma unroll
    for (int ni = 0; ni < 4; ni++) acc[mi][ni] = zero;

  // ds_read offsets: row base + granule slot (involutive swizzle, r-dependent only)
  const int slot = ((g ^ ((r ^ (r >> 2)) & 3)) << 4);
  const int aoff = (wr * 64 + r) * 64 + slot;      // + mi*1024
  const int boff = (wc * 64 + r) * 64 + slot;      // + ni*1024

  // prologue: tile 0 fully (order: A00 B00 A01 B01 -> oldest 3 = k0 unit set)
  STG_A(0, 0); STG_B(0, 0);
  STG_A(0, 1); STG_B(0, 1);

  for (int kt = 0; kt < KT; ++kt) {
    const int buf = kt & 1;
    const char* lA0 = (const char*)Akh[buf][0];
    const char* lA1 = (const char*)Akh[buf][1];
    const char* lB0 = (const char*)Bkh[buf][0];
    const char* lB1 = (const char*)Bkh[buf][1];
    const bool more = (kt + 1 < KT);

    // ---- P0: needs (kt,k0); drains the 3 loads issued 4 phases ago ----
    asm volatile("s_waitcnt vmcnt(3)" ::: "memory");
    __builtin_amdgcn_s_barrier();
    __builtin_amdgcn_sched_barrier(0);
    s16x8 b0[4], a0[2];
#pragma unroll
    for (int ni = 0; ni < 4; ni++) b0[ni] = *(const s16x8*)(lB0 + boff + ni * 1024);
#pragma unroll
    for (int i = 0; i < 2; i++) a0[i] = *(const s16x8*)(lA0 + aoff + i * 1024);
    if (more) STG_A(kt + 1, 0);
    asm volatile("s_waitcnt lgkmcnt(0)" ::: "memory");
    __builtin_amdgcn_sched_barrier(0);
    __builtin_amdgcn_s_setprio(1);
#pragma unroll
    for (int ni = 0; ni < 4; ni++)
#pragma unroll
      for (int i = 0; i < 2; i++)
        acc[i][ni] = __builtin_amdgcn_mfma_f32_16x16x32_bf16(a0[i], b0[ni], acc[i][ni], 0, 0, 0);
    __builtin_amdgcn_s_setprio(0);

    // ---- P1 ----
    __builtin_amdgcn_s_barrier();
    __builtin_amdgcn_sched_barrier(0);
    s16x8 a1[2];
#pragma unroll
    for (int i = 0; i < 2; i++) a1[i] = *(const s16x8*)(lA0 + aoff + (2 + i) * 1024);
    if (more) STG_B(kt + 1, 0);
    asm volatile("s_waitcnt lgkmcnt(0)" ::: "memory");
    __builtin_amdgcn_sched_barrier(0);
    __builtin_amdgcn_s_setprio(1);
#pragma unroll
    for (int ni = 0; ni < 4; ni++)
#pragma unroll
      for (int i = 0; i < 2; i++)
        acc[2 + i][ni] = __builtin_amdgcn_mfma_f32_16x16x32_bf16(a1[i], b0[ni], acc[2 + i][ni], 0, 0, 0);
    __builtin_amdgcn_s_setprio(0);

    // ---- P2: needs (kt,k1) ----
    if (more) { asm volatile("s_waitcnt vmcnt(3)" ::: "memory"); }
    else      { asm volatile("s_waitcnt vmcnt(0)" ::: "memory"); }
    __builtin_amdgcn_s_barrier();
    __builtin_amdgcn_sched_barrier(0);
    s16x8 b1[4], a2[2];
#pragma unroll
    for (int ni = 0; ni < 4; ni++) b1[ni] = *(const s16x8*)(lB1 + boff + ni * 1024);
#pragma unroll
    for (int i = 0; i < 2; i++) a2[i] = *(const s16x8*)(lA1 + aoff + i * 1024);
    if (more) STG_A(kt + 1, 1);
    asm volatile("s_waitcnt lgkmcnt(0)" ::: "memory");
    __builtin_amdgcn_sched_barrier(0);
    __builtin_amdgcn_s_setprio(1);
#pragma unroll
    for (int ni = 0; ni < 4; ni++)
#pragma unroll
      for (int i = 0; i < 2; i++)
        acc[i][ni] = __builtin_amdgcn_mfma_f32_16x16x32_bf16(a2[i], b1[ni], acc[i][ni], 0, 0, 0);
    __builtin_amdgcn_s_setprio(0);

    // ---- P3 ----
    __builtin_amdgcn_s_barrier();
    __builtin_amdgcn_sched_barrier(0);
    s16x8 a3[2];
#pragma unroll
    for (int i = 0; i < 2; i++) a3[i] = *(const s16x8*)(lA1 + aoff + (2 + i) * 1024);
    if (more) STG_B(kt + 1, 1);
    asm volatile("s_waitcnt lgkmcnt(0)" ::: "memory");
    __builtin_amdgcn_sched_barrier(0);
    __builtin_amdgcn_s_setprio(1);
#pragma unroll
    for (int ni = 0; ni < 4; ni++)
#pragma unroll
      for (int i = 0; i < 2; i++)
        acc[2 + i][ni] = __builtin_amdgcn_mfma_f32_16x16x32_bf16(a3[i], b1[ni], acc[2 + i][ni], 0, 0, 0);
    __builtin_amdgcn_s_setprio(0);
  }

  // epilogue
#pragma unroll
  for (int mi = 0; mi < 4; mi++)
#pragma unroll
    for (int ni = 0; ni < 4; ni++) {
      const int crow = bm * 128 + wr * 64 + mi * 16 + g * 4;
      const int ccol = bn * 256 + wc * 64 + ni * 16 + r;
#pragma unroll
      for (int j = 0; j < 4; j++)
        store_out(&C[(size_t)(crow + j) * N + ccol], acc[mi][ni][j]);
    }
}

// ---------------- Flash attention, causal, paired q-tiles ----------------
__global__ __launch_bounds__(512) void attn_kernel(const unsigned short* __restrict__ QKV,
                                                   const unsigned short* __restrict__ VT,
                                                   unsigned short* __restrict__ O) {
  __shared__ __align__(16) unsigned short Ksm[2][64 * 128];    // 2x16KB swizzled
  __shared__ __align__(16) unsigned short VTsm[2][128 * 64];   // 2x16KB swizzled
  __shared__ __align__(16) unsigned short Psm[8 * 32 * 64];    // 32KB per-wave
  const int bid = blockIdx.x;
  const int grp = bid & 7, j = bid >> 3;
  const int bh = (grp << 2) | (j & 3);
  const int pr = j >> 2;                 // 0..7
  const int qtA = 8 + pr, qtB = 7 - pr;
  const int b = bh >> 4, hd = bh & 15;
  const int tid = threadIdx.x, w = tid >> 6, l = tid & 63, g = l >> 4, r = l & 15;
  const int qbs = (w < 4 ? qtA : qtB) * 128 + (w & 3) * 32;  // wave's q-row base

  // Q fragments (already pre-scaled by 1/sqrt(D) in rope)
  s16x8 qf[2][4];
#pragma unroll
  for (int s = 0; s < 2; s++) {
    const unsigned short* qp = QKV + (size_t)(b * S_LEN + qbs + s * 16 + r) * QS + hd * HDIM;
#pragma unroll
    for (int ks = 0; ks < 4; ks++) qf[s][ks] = *(const s16x8*)(qp + ks * 32 + g * 8);
  }

  float mreg[2][4], lreg[2][4];
  f32x4 zero = {0.f, 0.f, 0.f, 0.f};
  f32x4 oacc[2][8];
#pragma unroll
  for (int s = 0; s < 2; s++)
#pragma unroll
    for (int jj = 0; jj < 4; jj++) { mreg[s][jj] = -1e30f; lreg[s][jj] = 0.f; }
#pragma unroll
  for (int s = 0; s < 2; s++)
#pragma unroll
    for (int di = 0; di < 8; di++) oacc[s][di] = zero;

  // staging bases: K rows tid>>4 (+32), V^T rows tid>>3 (+64); granule swizzle ^(row&7)
  const int cK = tid & 15, rowK = tid >> 4;            // 0..31
  const unsigned short* kp_base = QKV + (size_t)(b * S_LEN + rowK) * QS + HID + hd * HDIM
                                  + ((cK ^ (rowK & 7)) << 3);
  const int cV = tid & 7, dV = tid >> 3;               // 0..63
  const unsigned short* vp_base = VT + (size_t)(bh * 128 + dV) * S_LEN + ((cV ^ (dV & 7)) << 3);
  char* const ksm0 = (char*)Ksm;
  char* const vtsm0 = (char*)VTsm;
  char* const psm_w = (char*)Psm + w * 4096;

#define STAGE(kt, bufi)                                                        \
  {                                                                            \
    const unsigned short* kp_ = kp_base + (size_t)((kt) * 64) * QS;            \
    const unsigned short* vp_ = vp_base + (kt) * 64;                           \
    char* kd_ = ksm0 + (bufi) * 16384;                                         \
    char* vd_ = vtsm0 + (bufi) * 16384;                                        \
    GLL16(kp_, kd_ + tid * 16);                                                \
    GLL16(kp_ + (size_t)32 * QS, kd_ + (tid + 512) * 16);                      \
    GLL16(vp_, vd_ + tid * 16);                                                \
    GLL16(vp_ + (size_t)64 * S_LEN, vd_ + (tid + 512) * 16);                   \
  }

  const int nt = 2 * qtA + 2;
  STAGE(0, 0);
  asm volatile("s_waitcnt vmcnt(0)" ::: "memory");
  __builtin_amdgcn_s_barrier();
  __builtin_amdgcn_sched_barrier(0);

  for (int kt2 = 0; kt2 < nt; kt2++) {
    const int buf = kt2 & 1;
    if (kt2 + 1 < nt) STAGE(kt2 + 1, buf ^ 1);

    const bool active = (kt2 * 64) <= (qbs + 31);
    if (active) {
      const char* ksm_c = ksm0 + buf * 16384;
      const char* vtsm_c = vtsm0 + buf * 16384;
      // S = Q K^T
      f32x4 sacc[2][4];
#pragma unroll
      for (int s = 0; s < 2; s++)
#pragma unroll
        for (int ni = 0; ni < 4; ni++) sacc[s][ni] = zero;
#pragma unroll
      for (int ni = 0; ni < 4; ni++) {
        const int krow = ni * 16 + r;
        const int swz = (krow & 7) << 4;
        const char* kb2 = ksm_c + krow * 256;
#pragma unroll
        for (int ks = 0; ks < 4; ks++) {
          s16x8 kf = *(const s16x8*)(kb2 + ((ks * 64 + g * 16) ^ swz));
#pragma unroll
          for (int s = 0; s < 2; s++)
            sacc[s][ni] = __builtin_amdgcn_mfma_f32_16x16x32_bf16(qf[s][ks], kf, sacc[s][ni], 0, 0, 0);
        }
      }

      // online softmax per subtile
#pragma unroll
      for (int s = 0; s < 2; s++) {
        const int qb_s = qbs + s * 16;
        const bool domask = (kt2 * 64 + 63) > qb_s;
        float mrow[4];
#pragma unroll
        for (int jj = 0; jj < 4; jj++) mrow[jj] = -1e30f;
#pragma unroll
        for (int ni = 0; ni < 4; ni++)
#pragma unroll
          for (int jj = 0; jj < 4; jj++) {
            float sval = sacc[s][ni][jj];
            if (domask && (kt2 * 64 + ni * 16 + r) > (qb_s + g * 4 + jj)) sval = -1e30f;
            sacc[s][ni][jj] = sval;
            mrow[jj] = fmaxf(mrow[jj], sval);
          }
#pragma unroll
        for (int jj = 0; jj < 4; jj++) {
#pragma unroll
          for (int off = 8; off >= 1; off >>= 1)
            mrow[jj] = fmaxf(mrow[jj], __shfl_xor(mrow[jj], off, 64));
        }
        float corr[4];
#pragma unroll
        for (int jj = 0; jj < 4; jj++) {
          float mn = fmaxf(mreg[s][jj], mrow[jj]);
          corr[jj] = __expf(mreg[s][jj] - mn);
          mreg[s][jj] = mn;
          float sm = 0.f;
#pragma unroll
          for (int ni = 0; ni < 4; ni++) {
            float p2 = __expf(sacc[s][ni][jj] - mn);
            sacc[s][ni][jj] = p2;
            sm += p2;
          }
#pragma unroll
          for (int off = 8; off >= 1; off >>= 1) sm += __shfl_xor(sm, off, 64);
          lreg[s][jj] = lreg[s][jj] * corr[jj] + sm;
        }
#pragma unroll
        for (int di = 0; di < 8; di++)
#pragma unroll
          for (int jj = 0; jj < 4; jj++) oacc[s][di][jj] *= corr[jj];

        // P -> wave-private LDS (swizzled)
#pragma unroll
        for (int ni = 0; ni < 4; ni++)
#pragma unroll
          for (int jj = 0; jj < 4; jj++) {
            int prow = s * 16 + g * 4 + jj;
            int byte = (prow * 128 + ((ni * 16 + r) << 1)) ^ ((prow & 7) << 4);
            *(unsigned short*)(psm_w + byte) = f2bf(sacc[s][ni][jj]);
          }
      }

      // PV
#pragma unroll
      for (int ksl = 0; ksl < 2; ksl++) {
        s16x8 pa[2];
#pragma unroll
        for (int s = 0; s < 2; s++)
          pa[s] = *(const s16x8*)(psm_w + (((s * 16 + r) * 128 + ((ksl * 32 + g * 8) << 1)) ^ ((r & 7) << 4)));
        const int kgran = ksl * 4 + g;
#pragma unroll
        for (int di = 0; di < 8; di++) {
          const int d = di * 16 + r;
          s16x8 vf = *(const s16x8*)(vtsm_c + d * 128 + ((kgran ^ (d & 7)) << 4));
#pragma unroll
          for (int s = 0; s < 2; s++)
            oacc[s][di] = __builtin_amdgcn_mfma_f32_16x16x32_bf16(pa[s], vf, oacc[s][di], 0, 0, 0);
        }
      }
    }
    asm volatile("s_waitcnt vmcnt(0)" ::: "memory");
    __builtin_amdgcn_s_barrier();
    __builtin_amdgcn_sched_barrier(0);
  }
#undef STAGE

  // epilogue
#pragma unroll
  for (int s = 0; s < 2; s++)
#pragma unroll
    for (int di = 0; di < 8; di++)
#pragma unroll
      for (int jj = 0; jj < 4; jj++) {
        int orow = qbs + s * 16 + g * 4 + jj;
        O[(size_t)(b * S_LEN + orow) * HID + hd * HDIM + di * 16 + r] =
            f2bf(oacc[s][di][jj] / lreg[s][jj]);
      }
}

extern "C" void kernel_launch(void* const* d_in, const int* in_sizes, int n_in,
                              void* d_out, int out_size, void* d_ws, size_t ws_size,
                              hipStream_t stream) {
  const float* x      = (const float*)d_in[0];
  const float* norm_w = (const float*)d_in[1];
  const float* wq     = (const float*)d_in[2];
  const float* wk     = (const float*)d_in[3];
  const float* wv     = (const float*)d_in[4];
  const float* wo     = (const float*)d_in[5];
  const int*   pos    = (const int*)d_in[6];
  float* out = (float*)d_out;

  char* ws = (char*)d_ws;
  const size_t WQKV_B = (size_t)3 * HID * HID * 2;   // 24 MB (region A)
  const size_t VT_B   = (size_t)ROWS * HID * 2;      // 16 MB (aliases region A after qkv gemm)
  const size_t H_B    = (size_t)ROWS * HID * 2;      // 16 MB
  const size_t QKV_B  = (size_t)ROWS * QS * 2;       // 48 MB

  unsigned short* wqkvb = (unsigned short*)(ws);            // region A
  unsigned short* vt    = (unsigned short*)(ws);            // reuses region A
  unsigned short* wob   = (unsigned short*)(ws + VT_B);     // region A + 16MB
  unsigned short* h     = (unsigned short*)(ws + WQKV_B);   // also ctx
  unsigned short* qkv   = (unsigned short*)(ws + WQKV_B + H_B);
  float* cost = (float*)(ws + WQKV_B + H_B + QKV_B);
  float* sint = cost + (size_t)S_LEN * 64;

  const int n4 = HID * HID / 4;
  cast_w_kernel<<<n4 / 256, 256, 0, stream>>>(wq, wqkvb, n4);
  cast_w_kernel<<<n4 / 256, 256, 0, stream>>>(wk, wqkvb + (size_t)HID * HID, n4);
  cast_w_kernel<<<n4 / 256, 256, 0, stream>>>(wv, wqkvb + (size_t)2 * HID * HID, n4);
  rope_tab_kernel<<<S_LEN, 64, 0, stream>>>(cost, sint);
  rmsnorm_kernel<<<ROWS, 256, 0, stream>>>(x, norm_w, h);

  dim3 qkvgrid(QS / 256, ROWS / 128);   // 24 x 32 = 768 blocks; NBM=32 %8==0
  gemm_pipe_kernel<unsigned short><<<qkvgrid, 512, 0, stream>>>(h, wqkvb, qkv, HID, QS);

  // region A is dead now: cast wo into it, build V^T in it
  cast_w_kernel<<<n4 / 256, 256, 0, stream>>>(wo, wob, n4);
  dim3 tgrid(S_LEN / 64, 2, BATCH * NHEADS);
  transpose_v_kernel<<<tgrid, 256, 0, stream>>>(qkv, vt);

  rope_kernel<<<ROWS, 256, 0, stream>>>(pos, cost, sint, qkv);

  attn_kernel<<<256, 512, 0, stream>>>(qkv, vt, h /* ctx */);

  dim3 ogrid(HID / 256, ROWS / 128);    // 8 x 32 = 256 blocks; NBM=32 %8==0
  gemm_pipe_kernel<float><<<ogrid, 512, 0, stream>>>(h, wob, out, HID, HID);
}

// Round 6
// 307.164 us; speedup vs baseline: 1.6944x; 1.0902x over previous
//
#include <hip/hip_runtime.h>
#include <hip/hip_bf16.h>
#include <stdint.h>

#define S_LEN   2048
#define BATCH   2
#define HID     2048
#define NHEADS  16
#define HDIM    128
#define ROWS    (BATCH * S_LEN)          // 4096
#define QS      6144                     // qkv row stride (3*HID)
#define ATT_SCALE 0.08838834764831843f   // 1/sqrt(128)

typedef __attribute__((ext_vector_type(8))) short s16x8;
typedef __attribute__((ext_vector_type(4))) float f32x4;

#define GLL16(gp, lp)                                                          \
  __builtin_amdgcn_global_load_lds(                                            \
      (__attribute__((address_space(1))) void*)(gp),                           \
      (__attribute__((address_space(3))) void*)(lp), 16, 0, 0)

__device__ __forceinline__ float bf2f(unsigned short u) {
  union { unsigned int i; float f; } v; v.i = ((unsigned int)u) << 16; return v.f;
}
__device__ __forceinline__ unsigned short f2bf(float f) {
  union { float f; unsigned int i; } v; v.f = f;
  unsigned int i = v.i;
  return (unsigned short)((i + 0x7FFFu + ((i >> 16) & 1u)) >> 16);
}
__device__ __forceinline__ void store_out(unsigned short* p, float v) { *p = f2bf(v); }
__device__ __forceinline__ void store_out(float* p, float v) { *p = v; }

// ---------------- weight cast fp32 -> bf16 ----------------
__global__ __launch_bounds__(256) void cast_w_kernel(const float* __restrict__ in,
                                                     unsigned short* __restrict__ out, int n4) {
  int i = blockIdx.x * 256 + threadIdx.x;
  if (i >= n4) return;
  float4 v = ((const float4*)in)[i];
  ushort4 o;
  o.x = f2bf(v.x); o.y = f2bf(v.y); o.z = f2bf(v.z); o.w = f2bf(v.w);
  ((ushort4*)out)[i] = o;
}

// ---------------- RMSNorm (fp32 in, bf16 out) ----------------
__global__ __launch_bounds__(256) void rmsnorm_kernel(const float* __restrict__ x,
                                                      const float* __restrict__ w,
                                                      unsigned short* __restrict__ h) {
  int row = blockIdx.x;
  int t = threadIdx.x;
  const float4* xr4 = (const float4*)(x + (size_t)row * HID);
  float4 a = xr4[t], b = xr4[t + 256];
  float ss = a.x*a.x + a.y*a.y + a.z*a.z + a.w*a.w
           + b.x*b.x + b.y*b.y + b.z*b.z + b.w*b.w;
#pragma unroll
  for (int off = 32; off >= 1; off >>= 1) ss += __shfl_xor(ss, off, 64);
  __shared__ float red[4];
  if ((t & 63) == 0) red[t >> 6] = ss;
  __syncthreads();
  float tot = red[0] + red[1] + red[2] + red[3];
  float rs = rsqrtf(tot * (1.0f / (float)HID) + 1e-6f);
  const float4* w4 = (const float4*)w;
  float4 wa = w4[t], wb = w4[t + 256];
  ushort4 oa, ob;
  oa.x = f2bf(a.x * wa.x * rs); oa.y = f2bf(a.y * wa.y * rs);
  oa.z = f2bf(a.z * wa.z * rs); oa.w = f2bf(a.w * wa.w * rs);
  ob.x = f2bf(b.x * wb.x * rs); ob.y = f2bf(b.y * wb.y * rs);
  ob.z = f2bf(b.z * wb.z * rs); ob.w = f2bf(b.w * wb.w * rs);
  ushort4* hr = (ushort4*)(h + (size_t)row * HID);
  hr[t] = oa; hr[t + 256] = ob;
}

// ---------------- RoPE tables ----------------
__global__ void rope_tab_kernel(float* __restrict__ cost, float* __restrict__ sint) {
  int s = blockIdx.x, j = threadIdx.x;  // 64 threads
  float inv = powf(10000.0f, -((float)j) / 64.0f);
  float ang = (float)s * inv;
  cost[s * 64 + j] = cosf(ang);
  sint[s * 64 + j] = sinf(ang);
}

// ---------------- RoPE apply in-place on q,k inside fused qkv ----------------
__global__ __launch_bounds__(256) void rope_kernel(const int* __restrict__ pos_ids,
                                                   const float* __restrict__ cost,
                                                   const float* __restrict__ sint,
                                                   unsigned short* __restrict__ qkv) {
  int row = blockIdx.x;            // b*S + s
  int p = pos_ids[row];
  int t = threadIdx.x;
  int head = t >> 4;
  int j0 = (t & 15) * 4;
  size_t base = (size_t)row * QS + head * HDIM;
  float4 c = *(const float4*)(cost + p * 64 + j0);
  float4 s = *(const float4*)(sint + p * 64 + j0);
#pragma unroll
  for (int which = 0; which < 2; which++) {
    unsigned short* ptr = qkv + base + which * HID;  // q then k
    float sc = which ? 1.0f : ATT_SCALE;
    ushort4 v1 = *(ushort4*)(ptr + j0);
    ushort4 v2 = *(ushort4*)(ptr + 64 + j0);
    ushort4 o1, o2;
    o1.x = f2bf((bf2f(v1.x) * c.x - bf2f(v2.x) * s.x) * sc);
    o1.y = f2bf((bf2f(v1.y) * c.y - bf2f(v2.y) * s.y) * sc);
    o1.z = f2bf((bf2f(v1.z) * c.z - bf2f(v2.z) * s.z) * sc);
    o1.w = f2bf((bf2f(v1.w) * c.w - bf2f(v2.w) * s.w) * sc);
    o2.x = f2bf((bf2f(v2.x) * c.x + bf2f(v1.x) * s.x) * sc);
    o2.y = f2bf((bf2f(v2.y) * c.y + bf2f(v1.y) * s.y) * sc);
    o2.z = f2bf((bf2f(v2.z) * c.z + bf2f(v1.z) * s.z) * sc);
    o2.w = f2bf((bf2f(v2.w) * c.w + bf2f(v1.w) * s.w) * sc);
    *(ushort4*)(ptr + j0) = o1;
    *(ushort4*)(ptr + 64 + j0) = o2;
  }
}

// ---------------- V transpose: qkv v-block [tok][d] -> vt [bh*128+d][S] ----------------
__global__ __launch_bounds__(256) void transpose_v_kernel(const unsigned short* __restrict__ qkv,
                                                          unsigned short* __restrict__ vt) {
  __shared__ unsigned short tile[64][72];
  const int stile = blockIdx.x, dt = blockIdx.y, bh = blockIdx.z;
  const int t = threadIdx.x;
  const int b = bh >> 4, h = bh & 15;
  const int s0 = stile * 64;
  const unsigned short* src = qkv + (size_t)(b * S_LEN + s0) * QS + 2 * HID + h * HDIM + dt * 64;
#pragma unroll
  for (int it = 0; it < 2; it++) {
    int sl = (t >> 3) + 32 * it;
    int dl = (t & 7) * 8;
    *(s16x8*)&tile[sl][dl] = *(const s16x8*)(src + (size_t)sl * QS + dl);
  }
  __syncthreads();
#pragma unroll
  for (int it = 0; it < 2; it++) {
    int dl = (t >> 3) + 32 * it;
    int sl8 = (t & 7) * 8;
    s16x8 o;
#pragma unroll
    for (int jj = 0; jj < 8; jj++) o[jj] = (short)tile[sl8 + jj][dl];
    *(s16x8*)(vt + (size_t)(bh * 128 + dt * 64 + dl) * S_LEN + s0 + sl8) = o;
  }
}

// ---------------- Triple-buffered counted-vmcnt GEMM ----------------
// C[m,n] = sum_k A[m,k]*B[n,k]. BM=128, BN=NI*64 (NI=4 -> 256, NI=2 -> 128).
// 512 thr / 8 waves (2M x 4N). BK=64, LDS 3 bufs (A 16KB + B 16*NI KB each).
// During tile kt: stage tile kt+2 into buf (kt+2)%3 (6 or 4 loads).
// Gate per tile: vmcnt(6/4) + one s_barrier -- loads span 2 full tiles.
// LDS rows 128B, granule swizzle ^(row&7) on both sides (r4-verified: 0 conflicts).
#define SA(kt, bi) {                                                           \
    const unsigned short* s_ = aS + (size_t)(kt) * 64;                         \
    char* d_ = (char*)Ab[bi] + tid * 16;                                       \
    GLL16(s_, d_);                                                             \
    GLL16(s_ + (size_t)64 * K, d_ + 8192);                                     \
  }
#define SB(kt, bi, hf) {                                                       \
    const unsigned short* s_ = bS + (size_t)(hf) * 128 * K + (size_t)(kt) * 64;\
    char* d_ = (char*)Bb[bi] + (hf) * 16384 + tid * 16;                        \
    GLL16(s_, d_);                                                             \
    GLL16(s_ + (size_t)64 * K, d_ + 8192);                                     \
  }

template <typename OutT, int NI>
__global__ __launch_bounds__(512, 1) void gemm8_kernel(const unsigned short* __restrict__ A,
                                                       const unsigned short* __restrict__ B,
                                                       OutT* __restrict__ C, int K, int N) {
  __shared__ __align__(16) unsigned short Ab[3][128 * 64];       // 48 KB
  __shared__ __align__(16) unsigned short Bb[3][NI * 64 * 64];   // 96 or 48 KB
  const int bm = blockIdx.y, bn = blockIdx.x;                    // plain mapping
  const int tid = threadIdx.x;
  const int w = tid >> 6, wr = w >> 2, wc = w & 3;
  const int l = tid & 63, g = l >> 4, r = l & 15;
  const int KT = K >> 6;

  // staging source: row tid>>3 (+64), granule pre-swizzled ^(row&7)
  const int srow = tid >> 3;
  const int sgr = (tid & 7) ^ (srow & 7);
  const unsigned short* aS = A + (size_t)(bm * 128 + srow) * K + sgr * 8;
  const unsigned short* bS = B + (size_t)(bn * (NI * 64) + srow) * K + sgr * 8;

  f32x4 zero = {0.f, 0.f, 0.f, 0.f};
  f32x4 acc[4][NI];
#pragma unroll
  for (int mi = 0; mi < 4; mi++)
#pragma unroll
    for (int ni = 0; ni < NI; ni++) acc[mi][ni] = zero;

  const int swx = (r & 7) << 4;
  const int ks0 = (g << 4) ^ swx;          // kk=0 granule byte
  const int ks1 = ((4 | g) << 4) ^ swx;    // kk=1
  const int aOff = (wr * 64 + r) * 128;          // + mi*2048
  const int bOff = (wc * (NI * 16) + r) * 128;   // + ni*2048

  // prologue: tiles 0 and 1 fully staged
  SA(0, 0); SB(0, 0, 0); if (NI == 4) SB(0, 0, 1);
  SA(1, 1); SB(1, 1, 0); if (NI == 4) SB(1, 1, 1);

  int cur = 0;
  for (int kt = 0; kt < KT; ++kt) {
    const int b2 = (cur >= 1) ? cur - 1 : cur + 2;   // (cur+2)%3
    if (kt == KT - 1)      { asm volatile("s_waitcnt vmcnt(0)" ::: "memory"); }
    else if (NI == 4)      { asm volatile("s_waitcnt vmcnt(6)" ::: "memory"); }
    else                   { asm volatile("s_waitcnt vmcnt(4)" ::: "memory"); }
    __builtin_amdgcn_s_barrier();
    __builtin_amdgcn_sched_barrier(0);
    const char* lA = (const char*)Ab[cur];
    const char* lB = (const char*)Bb[cur];
    const bool more = (kt + 2 < KT);

    // ---- P0 reads: all A frags + first half of B frags ----
    s16x8 a[4][2], b[NI][2];
#pragma unroll
    for (int mi = 0; mi < 4; mi++) {
      a[mi][0] = *(const s16x8*)(lA + aOff + mi * 2048 + ks0);
      a[mi][1] = *(const s16x8*)(lA + aOff + mi * 2048 + ks1);
    }
#pragma unroll
    for (int ni = 0; ni < NI / 2; ni++) {
      b[ni][0] = *(const s16x8*)(lB + bOff + ni * 2048 + ks0);
      b[ni][1] = *(const s16x8*)(lB + bOff + ni * 2048 + ks1);
    }
    if (more) { SA(kt + 2, b2); if (NI == 4) SB(kt + 2, b2, 0); }
    __builtin_amdgcn_s_setprio(1);
#pragma unroll
    for (int kk = 0; kk < 2; kk++)
#pragma unroll
      for (int ni = 0; ni < NI / 2; ni++)
#pragma unroll
        for (int mi = 0; mi < 4; mi++)
          acc[mi][ni] = __builtin_amdgcn_mfma_f32_16x16x32_bf16(a[mi][kk], b[ni][kk], acc[mi][ni], 0, 0, 0);
    __builtin_amdgcn_s_setprio(0);
    __builtin_amdgcn_sched_barrier(0);

    // ---- P1 reads: second half of B frags ----
#pragma unroll
    for (int ni = NI / 2; ni < NI; ni++) {
      b[ni][0] = *(const s16x8*)(lB + bOff + ni * 2048 + ks0);
      b[ni][1] = *(const s16x8*)(lB + bOff + ni * 2048 + ks1);
    }
    if (more) { if (NI == 4) { SB(kt + 2, b2, 1); } else { SB(kt + 2, b2, 0); } }
    __builtin_amdgcn_s_setprio(1);
#pragma unroll
    for (int kk = 0; kk < 2; kk++)
#pragma unroll
      for (int ni = NI / 2; ni < NI; ni++)
#pragma unroll
        for (int mi = 0; mi < 4; mi++)
          acc[mi][ni] = __builtin_amdgcn_mfma_f32_16x16x32_bf16(a[mi][kk], b[ni][kk], acc[mi][ni], 0, 0, 0);
    __builtin_amdgcn_s_setprio(0);
    cur = (cur == 2) ? 0 : cur + 1;
  }

  // epilogue
#pragma unroll
  for (int mi = 0; mi < 4; mi++)
#pragma unroll
    for (int ni = 0; ni < NI; ni++) {
      const int crow = bm * 128 + wr * 64 + mi * 16 + g * 4;
      const int ccol = bn * (NI * 64) + wc * (NI * 16) + ni * 16 + r;
#pragma unroll
      for (int j = 0; j < 4; j++)
        store_out(&C[(size_t)(crow + j) * N + ccol], acc[mi][ni][j]);
    }
}

// ---------------- Flash attention, causal, paired q-tiles ----------------
__global__ __launch_bounds__(512) void attn_kernel(const unsigned short* __restrict__ QKV,
                                                   const unsigned short* __restrict__ VT,
                                                   unsigned short* __restrict__ O) {
  __shared__ __align__(16) unsigned short Ksm[2][64 * 128];    // 2x16KB swizzled
  __shared__ __align__(16) unsigned short VTsm[2][128 * 64];   // 2x16KB swizzled
  __shared__ __align__(16) unsigned short Psm[8 * 32 * 64];    // 32KB per-wave
  const int bid = blockIdx.x;
  const int grp = bid & 7, j = bid >> 3;
  const int bh = (grp << 2) | (j & 3);
  const int pr = j >> 2;                 // 0..7
  const int qtA = 8 + pr, qtB = 7 - pr;
  const int b = bh >> 4, hd = bh & 15;
  const int tid = threadIdx.x, w = tid >> 6, l = tid & 63, g = l >> 4, r = l & 15;
  const int qbs = (w < 4 ? qtA : qtB) * 128 + (w & 3) * 32;  // wave's q-row base

  // Q fragments (already pre-scaled by 1/sqrt(D) in rope)
  s16x8 qf[2][4];
#pragma unroll
  for (int s = 0; s < 2; s++) {
    const unsigned short* qp = QKV + (size_t)(b * S_LEN + qbs + s * 16 + r) * QS + hd * HDIM;
#pragma unroll
    for (int ks = 0; ks < 4; ks++) qf[s][ks] = *(const s16x8*)(qp + ks * 32 + g * 8);
  }

  float mreg[2][4], lreg[2][4];
  f32x4 zero = {0.f, 0.f, 0.f, 0.f};
  f32x4 oacc[2][8];
#pragma unroll
  for (int s = 0; s < 2; s++)
#pragma unroll
    for (int jj = 0; jj < 4; jj++) { mreg[s][jj] = -1e30f; lreg[s][jj] = 0.f; }
#pragma unroll
  for (int s = 0; s < 2; s++)
#pragma unroll
    for (int di = 0; di < 8; di++) oacc[s][di] = zero;

  // staging bases: K rows tid>>4 (+32), V^T rows tid>>3 (+64); granule swizzle ^(row&7)
  const int cK = tid & 15, rowK = tid >> 4;            // 0..31
  const unsigned short* kp_base = QKV + (size_t)(b * S_LEN + rowK) * QS + HID + hd * HDIM
                                  + ((cK ^ (rowK & 7)) << 3);
  const int cV = tid & 7, dV = tid >> 3;               // 0..63
  const unsigned short* vp_base = VT + (size_t)(bh * 128 + dV) * S_LEN + ((cV ^ (dV & 7)) << 3);
  char* const ksm0 = (char*)Ksm;
  char* const vtsm0 = (char*)VTsm;
  char* const psm_w = (char*)Psm + w * 4096;

#define STAGE(kt, bufi)                                                        \
  {                                                                            \
    const unsigned short* kp_ = kp_base + (size_t)((kt) * 64) * QS;            \
    const unsigned short* vp_ = vp_base + (kt) * 64;                           \
    char* kd_ = ksm0 + (bufi) * 16384;                                         \
    char* vd_ = vtsm0 + (bufi) * 16384;                                        \
    GLL16(kp_, kd_ + tid * 16);                                                \
    GLL16(kp_ + (size_t)32 * QS, kd_ + (tid + 512) * 16);                      \
    GLL16(vp_, vd_ + tid * 16);                                                \
    GLL16(vp_ + (size_t)64 * S_LEN, vd_ + (tid + 512) * 16);                   \
  }

  const int nt = 2 * qtA + 2;
  STAGE(0, 0);
  asm volatile("s_waitcnt vmcnt(0)" ::: "memory");
  __builtin_amdgcn_s_barrier();
  __builtin_amdgcn_sched_barrier(0);

  for (int kt2 = 0; kt2 < nt; kt2++) {
    const int buf = kt2 & 1;
    if (kt2 + 1 < nt) STAGE(kt2 + 1, buf ^ 1);

    const bool active = (kt2 * 64) <= (qbs + 31);
    if (active) {
      const char* ksm_c = ksm0 + buf * 16384;
      const char* vtsm_c = vtsm0 + buf * 16384;
      // S = Q K^T
      f32x4 sacc[2][4];
#pragma unroll
      for (int s = 0; s < 2; s++)
#pragma unroll
        for (int ni = 0; ni < 4; ni++) sacc[s][ni] = zero;
#pragma unroll
      for (int ni = 0; ni < 4; ni++) {
        const int krow = ni * 16 + r;
        const int swz = (krow & 7) << 4;
        const char* kb2 = ksm_c + krow * 256;
#pragma unroll
        for (int ks = 0; ks < 4; ks++) {
          s16x8 kf = *(const s16x8*)(kb2 + ((ks * 64 + g * 16) ^ swz));
#pragma unroll
          for (int s = 0; s < 2; s++)
            sacc[s][ni] = __builtin_amdgcn_mfma_f32_16x16x32_bf16(qf[s][ks], kf, sacc[s][ni], 0, 0, 0);
        }
      }

      // online softmax per subtile
#pragma unroll
      for (int s = 0; s < 2; s++) {
        const int qb_s = qbs + s * 16;
        const bool domask = (kt2 * 64 + 63) > qb_s;
        float mrow[4];
#pragma unroll
        for (int jj = 0; jj < 4; jj++) mrow[jj] = -1e30f;
#pragma unroll
        for (int ni = 0; ni < 4; ni++)
#pragma unroll
          for (int jj = 0; jj < 4; jj++) {
            float sval = sacc[s][ni][jj];
            if (domask && (kt2 * 64 + ni * 16 + r) > (qb_s + g * 4 + jj)) sval = -1e30f;
            sacc[s][ni][jj] = sval;
            mrow[jj] = fmaxf(mrow[jj], sval);
          }
#pragma unroll
        for (int jj = 0; jj < 4; jj++) {
#pragma unroll
          for (int off = 8; off >= 1; off >>= 1)
            mrow[jj] = fmaxf(mrow[jj], __shfl_xor(mrow[jj], off, 64));
        }
        float corr[4];
#pragma unroll
        for (int jj = 0; jj < 4; jj++) {
          float mn = fmaxf(mreg[s][jj], mrow[jj]);
          corr[jj] = __expf(mreg[s][jj] - mn);
          mreg[s][jj] = mn;
          float sm = 0.f;
#pragma unroll
          for (int ni = 0; ni < 4; ni++) {
            float p2 = __expf(sacc[s][ni][jj] - mn);
            sacc[s][ni][jj] = p2;
            sm += p2;
          }
#pragma unroll
          for (int off = 8; off >= 1; off >>= 1) sm += __shfl_xor(sm, off, 64);
          lreg[s][jj] = lreg[s][jj] * corr[jj] + sm;
        }
#pragma unroll
        for (int di = 0; di < 8; di++)
#pragma unroll
          for (int jj = 0; jj < 4; jj++) oacc[s][di][jj] *= corr[jj];

        // P -> wave-private LDS (swizzled)
#pragma unroll
        for (int ni = 0; ni < 4; ni++)
#pragma unroll
          for (int jj = 0; jj < 4; jj++) {
            int prow = s * 16 + g * 4 + jj;
            int byte = (prow * 128 + ((ni * 16 + r) << 1)) ^ ((prow & 7) << 4);
            *(unsigned short*)(psm_w + byte) = f2bf(sacc[s][ni][jj]);
          }
      }

      // PV
#pragma unroll
      for (int ksl = 0; ksl < 2; ksl++) {
        s16x8 pa[2];
#pragma unroll
        for (int s = 0; s < 2; s++)
          pa[s] = *(const s16x8*)(psm_w + (((s * 16 + r) * 128 + ((ksl * 32 + g * 8) << 1)) ^ ((r & 7) << 4)));
        const int kgran = ksl * 4 + g;
#pragma unroll
        for (int di = 0; di < 8; di++) {
          const int d = di * 16 + r;
          s16x8 vf = *(const s16x8*)(vtsm_c + d * 128 + ((kgran ^ (d & 7)) << 4));
#pragma unroll
          for (int s = 0; s < 2; s++)
            oacc[s][di] = __builtin_amdgcn_mfma_f32_16x16x32_bf16(pa[s], vf, oacc[s][di], 0, 0, 0);
        }
      }
    }
    asm volatile("s_waitcnt vmcnt(0)" ::: "memory");
    __builtin_amdgcn_s_barrier();
    __builtin_amdgcn_sched_barrier(0);
  }
#undef STAGE

  // epilogue
#pragma unroll
  for (int s = 0; s < 2; s++)
#pragma unroll
    for (int di = 0; di < 8; di++)
#pragma unroll
      for (int jj = 0; jj < 4; jj++) {
        int orow = qbs + s * 16 + g * 4 + jj;
        O[(size_t)(b * S_LEN + orow) * HID + hd * HDIM + di * 16 + r] =
            f2bf(oacc[s][di][jj] / lreg[s][jj]);
      }
}

extern "C" void kernel_launch(void* const* d_in, const int* in_sizes, int n_in,
                              void* d_out, int out_size, void* d_ws, size_t ws_size,
                              hipStream_t stream) {
  const float* x      = (const float*)d_in[0];
  const float* norm_w = (const float*)d_in[1];
  const float* wq     = (const float*)d_in[2];
  const float* wk     = (const float*)d_in[3];
  const float* wv     = (const float*)d_in[4];
  const float* wo     = (const float*)d_in[5];
  const int*   pos    = (const int*)d_in[6];
  float* out = (float*)d_out;

  char* ws = (char*)d_ws;
  const size_t WQKV_B = (size_t)3 * HID * HID * 2;   // 24 MB (region A)
  const size_t VT_B   = (size_t)ROWS * HID * 2;      // 16 MB (aliases region A after qkv gemm)
  const size_t H_B    = (size_t)ROWS * HID * 2;      // 16 MB
  const size_t QKV_B  = (size_t)ROWS * QS * 2;       // 48 MB

  unsigned short* wqkvb = (unsigned short*)(ws);            // region A
  unsigned short* vt    = (unsigned short*)(ws);            // reuses region A
  unsigned short* wob   = (unsigned short*)(ws + VT_B);     // region A + 16MB
  unsigned short* h     = (unsigned short*)(ws + WQKV_B);   // also ctx
  unsigned short* qkv   = (unsigned short*)(ws + WQKV_B + H_B);
  float* cost = (float*)(ws + WQKV_B + H_B + QKV_B);
  float* sint = cost + (size_t)S_LEN * 64;

  const int n4 = HID * HID / 4;
  cast_w_kernel<<<n4 / 256, 256, 0, stream>>>(wq, wqkvb, n4);
  cast_w_kernel<<<n4 / 256, 256, 0, stream>>>(wk, wqkvb + (size_t)HID * HID, n4);
  cast_w_kernel<<<n4 / 256, 256, 0, stream>>>(wv, wqkvb + (size_t)2 * HID * HID, n4);
  rope_tab_kernel<<<S_LEN, 64, 0, stream>>>(cost, sint);
  rmsnorm_kernel<<<ROWS, 256, 0, stream>>>(x, norm_w, h);

  dim3 qkvgrid(QS / 256, ROWS / 128);   // 24 x 32 = 768 blocks (3.0 waves/CU)
  gemm8_kernel<unsigned short, 4><<<qkvgrid, 512, 0, stream>>>(h, wqkvb, qkv, HID, QS);

  // region A is dead now: cast wo into it, build V^T in it
  cast_w_kernel<<<n4 / 256, 256, 0, stream>>>(wo, wob, n4);
  dim3 tgrid(S_LEN / 64, 2, BATCH * NHEADS);
  transpose_v_kernel<<<tgrid, 256, 0, stream>>>(qkv, vt);

  rope_kernel<<<ROWS, 256, 0, stream>>>(pos, cost, sint, qkv);

  attn_kernel<<<256, 512, 0, stream>>>(qkv, vt, h /* ctx */);

  dim3 ogrid(HID / 128, ROWS / 128);    // 16 x 32 = 512 blocks (2.0 waves/CU)
  gemm8_kernel<float, 2><<<ogrid, 512, 0, stream>>>(h, wob, out, HID, HID);
}

// Round 7
// 298.182 us; speedup vs baseline: 1.7455x; 1.0301x over previous
//
#include <hip/hip_runtime.h>
#include <hip/hip_bf16.h>
#include <stdint.h>

#define S_LEN   2048
#define BATCH   2
#define HID     2048
#define NHEADS  16
#define HDIM    128
#define ROWS    (BATCH * S_LEN)          // 4096
#define QS      6144                     // qkv row stride (3*HID)
#define ATT_SCALE 0.08838834764831843f   // 1/sqrt(128)

typedef __attribute__((ext_vector_type(8))) short s16x8;
typedef __attribute__((ext_vector_type(4))) float f32x4;

#define GLL16(gp, lp)                                                          \
  __builtin_amdgcn_global_load_lds(                                            \
      (__attribute__((address_space(1))) void*)(gp),                           \
      (__attribute__((address_space(3))) void*)(lp), 16, 0, 0)

__device__ __forceinline__ float bf2f(unsigned short u) {
  union { unsigned int i; float f; } v; v.i = ((unsigned int)u) << 16; return v.f;
}
__device__ __forceinline__ unsigned short f2bf(float f) {
  union { float f; unsigned int i; } v; v.f = f;
  unsigned int i = v.i;
  return (unsigned short)((i + 0x7FFFu + ((i >> 16) & 1u)) >> 16);
}
__device__ __forceinline__ void store_out(unsigned short* p, float v) { *p = f2bf(v); }
__device__ __forceinline__ void store_out(float* p, float v) { *p = v; }

// ---------------- weight cast fp32 -> bf16 ----------------
__global__ __launch_bounds__(256) void cast_w_kernel(const float* __restrict__ in,
                                                     unsigned short* __restrict__ out, int n4) {
  int i = blockIdx.x * 256 + threadIdx.x;
  if (i >= n4) return;
  float4 v = ((const float4*)in)[i];
  ushort4 o;
  o.x = f2bf(v.x); o.y = f2bf(v.y); o.z = f2bf(v.z); o.w = f2bf(v.w);
  ((ushort4*)out)[i] = o;
}

// ---------------- RMSNorm (fp32 in, bf16 out) ----------------
__global__ __launch_bounds__(256) void rmsnorm_kernel(const float* __restrict__ x,
                                                      const float* __restrict__ w,
                                                      unsigned short* __restrict__ h) {
  int row = blockIdx.x;
  int t = threadIdx.x;
  const float4* xr4 = (const float4*)(x + (size_t)row * HID);
  float4 a = xr4[t], b = xr4[t + 256];
  float ss = a.x*a.x + a.y*a.y + a.z*a.z + a.w*a.w
           + b.x*b.x + b.y*b.y + b.z*b.z + b.w*b.w;
#pragma unroll
  for (int off = 32; off >= 1; off >>= 1) ss += __shfl_xor(ss, off, 64);
  __shared__ float red[4];
  if ((t & 63) == 0) red[t >> 6] = ss;
  __syncthreads();
  float tot = red[0] + red[1] + red[2] + red[3];
  float rs = rsqrtf(tot * (1.0f / (float)HID) + 1e-6f);
  const float4* w4 = (const float4*)w;
  float4 wa = w4[t], wb = w4[t + 256];
  ushort4 oa, ob;
  oa.x = f2bf(a.x * wa.x * rs); oa.y = f2bf(a.y * wa.y * rs);
  oa.z = f2bf(a.z * wa.z * rs); oa.w = f2bf(a.w * wa.w * rs);
  ob.x = f2bf(b.x * wb.x * rs); ob.y = f2bf(b.y * wb.y * rs);
  ob.z = f2bf(b.z * wb.z * rs); ob.w = f2bf(b.w * wb.w * rs);
  ushort4* hr = (ushort4*)(h + (size_t)row * HID);
  hr[t] = oa; hr[t + 256] = ob;
}

// ---------------- RoPE tables ----------------
__global__ void rope_tab_kernel(float* __restrict__ cost, float* __restrict__ sint) {
  int s = blockIdx.x, j = threadIdx.x;  // 64 threads
  float inv = powf(10000.0f, -((float)j) / 64.0f);
  float ang = (float)s * inv;
  cost[s * 64 + j] = cosf(ang);
  sint[s * 64 + j] = sinf(ang);
}

// ---------------- RoPE apply in-place on q,k inside fused qkv ----------------
__global__ __launch_bounds__(256) void rope_kernel(const int* __restrict__ pos_ids,
                                                   const float* __restrict__ cost,
                                                   const float* __restrict__ sint,
                                                   unsigned short* __restrict__ qkv) {
  int row = blockIdx.x;            // b*S + s
  int p = pos_ids[row];
  int t = threadIdx.x;
  int head = t >> 4;
  int j0 = (t & 15) * 4;
  size_t base = (size_t)row * QS + head * HDIM;
  float4 c = *(const float4*)(cost + p * 64 + j0);
  float4 s = *(const float4*)(sint + p * 64 + j0);
#pragma unroll
  for (int which = 0; which < 2; which++) {
    unsigned short* ptr = qkv + base + which * HID;  // q then k
    float sc = which ? 1.0f : ATT_SCALE;
    ushort4 v1 = *(ushort4*)(ptr + j0);
    ushort4 v2 = *(ushort4*)(ptr + 64 + j0);
    ushort4 o1, o2;
    o1.x = f2bf((bf2f(v1.x) * c.x - bf2f(v2.x) * s.x) * sc);
    o1.y = f2bf((bf2f(v1.y) * c.y - bf2f(v2.y) * s.y) * sc);
    o1.z = f2bf((bf2f(v1.z) * c.z - bf2f(v2.z) * s.z) * sc);
    o1.w = f2bf((bf2f(v1.w) * c.w - bf2f(v2.w) * s.w) * sc);
    o2.x = f2bf((bf2f(v2.x) * c.x + bf2f(v1.x) * s.x) * sc);
    o2.y = f2bf((bf2f(v2.y) * c.y + bf2f(v1.y) * s.y) * sc);
    o2.z = f2bf((bf2f(v2.z) * c.z + bf2f(v1.z) * s.z) * sc);
    o2.w = f2bf((bf2f(v2.w) * c.w + bf2f(v1.w) * s.w) * sc);
    *(ushort4*)(ptr + j0) = o1;
    *(ushort4*)(ptr + 64 + j0) = o2;
  }
}

// ---------------- V transpose: qkv v-block [tok][d] -> vt [bh*128+d][S] ----------------
__global__ __launch_bounds__(256) void transpose_v_kernel(const unsigned short* __restrict__ qkv,
                                                          unsigned short* __restrict__ vt) {
  __shared__ unsigned short tile[64][72];
  const int stile = blockIdx.x, dt = blockIdx.y, bh = blockIdx.z;
  const int t = threadIdx.x;
  const int b = bh >> 4, h = bh & 15;
  const int s0 = stile * 64;
  const unsigned short* src = qkv + (size_t)(b * S_LEN + s0) * QS + 2 * HID + h * HDIM + dt * 64;
#pragma unroll
  for (int it = 0; it < 2; it++) {
    int sl = (t >> 3) + 32 * it;
    int dl = (t & 7) * 8;
    *(s16x8*)&tile[sl][dl] = *(const s16x8*)(src + (size_t)sl * QS + dl);
  }
  __syncthreads();
#pragma unroll
  for (int it = 0; it < 2; it++) {
    int dl = (t >> 3) + 32 * it;
    int sl8 = (t & 7) * 8;
    s16x8 o;
#pragma unroll
    for (int jj = 0; jj < 8; jj++) o[jj] = (short)tile[sl8 + jj][dl];
    *(s16x8*)(vt + (size_t)(bh * 128 + dt * 64 + dl) * S_LEN + s0 + sl8) = o;
  }
}

// ---------------- Triple-buffered counted-vmcnt GEMM ----------------
// (unchanged from round 6: dropped out of the top-5)
#define SA(kt, bi) {                                                           \
    const unsigned short* s_ = aS + (size_t)(kt) * 64;                         \
    char* d_ = (char*)Ab[bi] + tid * 16;                                       \
    GLL16(s_, d_);                                                             \
    GLL16(s_ + (size_t)64 * K, d_ + 8192);                                     \
  }
#define SB(kt, bi, hf) {                                                       \
    const unsigned short* s_ = bS + (size_t)(hf) * 128 * K + (size_t)(kt) * 64;\
    char* d_ = (char*)Bb[bi] + (hf) * 16384 + tid * 16;                        \
    GLL16(s_, d_);                                                             \
    GLL16(s_ + (size_t)64 * K, d_ + 8192);                                     \
  }

template <typename OutT, int NI>
__global__ __launch_bounds__(512, 1) void gemm8_kernel(const unsigned short* __restrict__ A,
                                                       const unsigned short* __restrict__ B,
                                                       OutT* __restrict__ C, int K, int N) {
  __shared__ __align__(16) unsigned short Ab[3][128 * 64];       // 48 KB
  __shared__ __align__(16) unsigned short Bb[3][NI * 64 * 64];   // 96 or 48 KB
  const int bm = blockIdx.y, bn = blockIdx.x;                    // plain mapping
  const int tid = threadIdx.x;
  const int w = tid >> 6, wr = w >> 2, wc = w & 3;
  const int l = tid & 63, g = l >> 4, r = l & 15;
  const int KT = K >> 6;

  const int srow = tid >> 3;
  const int sgr = (tid & 7) ^ (srow & 7);
  const unsigned short* aS = A + (size_t)(bm * 128 + srow) * K + sgr * 8;
  const unsigned short* bS = B + (size_t)(bn * (NI * 64) + srow) * K + sgr * 8;

  f32x4 zero = {0.f, 0.f, 0.f, 0.f};
  f32x4 acc[4][NI];
#pragma unroll
  for (int mi = 0; mi < 4; mi++)
#pragma unroll
    for (int ni = 0; ni < NI; ni++) acc[mi][ni] = zero;

  const int swx = (r & 7) << 4;
  const int ks0 = (g << 4) ^ swx;
  const int ks1 = ((4 | g) << 4) ^ swx;
  const int aOff = (wr * 64 + r) * 128;
  const int bOff = (wc * (NI * 16) + r) * 128;

  SA(0, 0); SB(0, 0, 0); if (NI == 4) SB(0, 0, 1);
  SA(1, 1); SB(1, 1, 0); if (NI == 4) SB(1, 1, 1);

  int cur = 0;
  for (int kt = 0; kt < KT; ++kt) {
    const int b2 = (cur >= 1) ? cur - 1 : cur + 2;   // (cur+2)%3
    if (kt == KT - 1)      { asm volatile("s_waitcnt vmcnt(0)" ::: "memory"); }
    else if (NI == 4)      { asm volatile("s_waitcnt vmcnt(6)" ::: "memory"); }
    else                   { asm volatile("s_waitcnt vmcnt(4)" ::: "memory"); }
    __builtin_amdgcn_s_barrier();
    __builtin_amdgcn_sched_barrier(0);
    const char* lA = (const char*)Ab[cur];
    const char* lB = (const char*)Bb[cur];
    const bool more = (kt + 2 < KT);

    s16x8 a[4][2], b[NI][2];
#pragma unroll
    for (int mi = 0; mi < 4; mi++) {
      a[mi][0] = *(const s16x8*)(lA + aOff + mi * 2048 + ks0);
      a[mi][1] = *(const s16x8*)(lA + aOff + mi * 2048 + ks1);
    }
#pragma unroll
    for (int ni = 0; ni < NI / 2; ni++) {
      b[ni][0] = *(const s16x8*)(lB + bOff + ni * 2048 + ks0);
      b[ni][1] = *(const s16x8*)(lB + bOff + ni * 2048 + ks1);
    }
    if (more) { SA(kt + 2, b2); if (NI == 4) SB(kt + 2, b2, 0); }
    __builtin_amdgcn_s_setprio(1);
#pragma unroll
    for (int kk = 0; kk < 2; kk++)
#pragma unroll
      for (int ni = 0; ni < NI / 2; ni++)
#pragma unroll
        for (int mi = 0; mi < 4; mi++)
          acc[mi][ni] = __builtin_amdgcn_mfma_f32_16x16x32_bf16(a[mi][kk], b[ni][kk], acc[mi][ni], 0, 0, 0);
    __builtin_amdgcn_s_setprio(0);
    __builtin_amdgcn_sched_barrier(0);

#pragma unroll
    for (int ni = NI / 2; ni < NI; ni++) {
      b[ni][0] = *(const s16x8*)(lB + bOff + ni * 2048 + ks0);
      b[ni][1] = *(const s16x8*)(lB + bOff + ni * 2048 + ks1);
    }
    if (more) { if (NI == 4) { SB(kt + 2, b2, 1); } else { SB(kt + 2, b2, 0); } }
    __builtin_amdgcn_s_setprio(1);
#pragma unroll
    for (int kk = 0; kk < 2; kk++)
#pragma unroll
      for (int ni = NI / 2; ni < NI; ni++)
#pragma unroll
        for (int mi = 0; mi < 4; mi++)
          acc[mi][ni] = __builtin_amdgcn_mfma_f32_16x16x32_bf16(a[mi][kk], b[ni][kk], acc[mi][ni], 0, 0, 0);
    __builtin_amdgcn_s_setprio(0);
    cur = (cur == 2) ? 0 : cur + 1;
  }

#pragma unroll
  for (int mi = 0; mi < 4; mi++)
#pragma unroll
    for (int ni = 0; ni < NI; ni++) {
      const int crow = bm * 128 + wr * 64 + mi * 16 + g * 4;
      const int ccol = bn * (NI * 64) + wc * (NI * 16) + ni * 16 + r;
#pragma unroll
      for (int j = 0; j < 4; j++)
        store_out(&C[(size_t)(crow + j) * N + ccol], acc[mi][ni][j]);
    }
}

// ---------------- Flash attention, causal ----------------
// 1024 blocks x 256 thr (4 waves). Block = one 64-row q-tile (wave = 16 rows).
// qt descending in dispatch order (LPT balance on 512 slots); bh XCD-chunked.
// LDS 40KB (K 16 + VT 16 + P 8), single-buffered KV -> 4 blocks/CU, 16 waves/CU.
__global__ __launch_bounds__(256, 4) void attn_kernel(const unsigned short* __restrict__ QKV,
                                                      const unsigned short* __restrict__ VT,
                                                      unsigned short* __restrict__ O) {
  __shared__ __align__(16) unsigned short Ksm[64 * 128];    // 16KB swizzled
  __shared__ __align__(16) unsigned short VTsm[128 * 64];   // 16KB swizzled
  __shared__ __align__(16) unsigned short Psm[4 * 16 * 64]; // 8KB per-wave
  const int bid = blockIdx.x;
  const int grp = bid & 7, idx = bid >> 3;     // idx 0..127
  const int qt = 31 - (idx >> 2);              // heavy-first (LPT)
  const int bh = (grp << 2) | (idx & 3);
  const int b = bh >> 4, hd = bh & 15;
  const int tid = threadIdx.x, w = tid >> 6, l = tid & 63, g = l >> 4, r = l & 15;
  const int qbs = qt * 64 + w * 16;            // wave's q-row base (16 rows)

  // Q fragments (pre-scaled by 1/sqrt(D) in rope): row qbs+r, d = ks*32+g*8..
  const unsigned short* qp = QKV + (size_t)(b * S_LEN + qbs + r) * QS + hd * HDIM;
  s16x8 qf[4];
#pragma unroll
  for (int ks = 0; ks < 4; ks++) qf[ks] = *(const s16x8*)(qp + ks * 32 + g * 8);

  float mreg[4], lreg[4];
  f32x4 zero = {0.f, 0.f, 0.f, 0.f};
  f32x4 oacc[8];
#pragma unroll
  for (int jj = 0; jj < 4; jj++) { mreg[jj] = -1e30f; lreg[jj] = 0.f; }
#pragma unroll
  for (int di = 0; di < 8; di++) oacc[di] = zero;

  // staging: K granule c=tid+256i -> row c>>4, col16 c&15; V: row c>>3, col8 c&7
  const int cK = tid & 15, rowK = tid >> 4;            // 0..15 (+16/i)
  const unsigned short* kp_base = QKV + (size_t)(b * S_LEN + rowK) * QS + HID + hd * HDIM
                                  + ((cK ^ (rowK & 7)) << 3);
  const int cV = tid & 7, dV = tid >> 3;               // 0..31 (+32/i)
  const unsigned short* vp_base = VT + (size_t)(bh * 128 + dV) * S_LEN + ((cV ^ (dV & 7)) << 3);
  char* const ksm_c = (char*)Ksm;
  char* const vtsm_c = (char*)VTsm;
  char* const psm_w = (char*)Psm + w * 2048;

#define STAGE(kt)                                                              \
  {                                                                            \
    const unsigned short* kp_ = kp_base + (size_t)((kt) * 64) * QS;            \
    const unsigned short* vp_ = vp_base + (kt) * 64;                           \
    GLL16(kp_,                      ksm_c + tid * 16);                         \
    GLL16(kp_ + (size_t)16 * QS,    ksm_c + (tid + 256) * 16);                 \
    GLL16(kp_ + (size_t)32 * QS,    ksm_c + (tid + 512) * 16);                 \
    GLL16(kp_ + (size_t)48 * QS,    ksm_c + (tid + 768) * 16);                 \
    GLL16(vp_,                      vtsm_c + tid * 16);                        \
    GLL16(vp_ + (size_t)32 * S_LEN, vtsm_c + (tid + 256) * 16);                \
    GLL16(vp_ + (size_t)64 * S_LEN, vtsm_c + (tid + 512) * 16);                \
    GLL16(vp_ + (size_t)96 * S_LEN, vtsm_c + (tid + 768) * 16);                \
  }

  const int nt = qt + 1;
  STAGE(0);

  for (int kt2 = 0; kt2 < nt; kt2++) {
    asm volatile("s_waitcnt vmcnt(0)" ::: "memory");
    __builtin_amdgcn_s_barrier();
    __builtin_amdgcn_sched_barrier(0);

    // S = Q K^T
    f32x4 sacc[4];
#pragma unroll
    for (int ni = 0; ni < 4; ni++) sacc[ni] = zero;
#pragma unroll
    for (int ni = 0; ni < 4; ni++) {
      const int krow = ni * 16 + r;
      const int swz = (krow & 7) << 4;
      const char* kb2 = ksm_c + krow * 256;
#pragma unroll
      for (int ks = 0; ks < 4; ks++) {
        s16x8 kf = *(const s16x8*)(kb2 + ((ks * 64 + g * 16) ^ swz));
        sacc[ni] = __builtin_amdgcn_mfma_f32_16x16x32_bf16(qf[ks], kf, sacc[ni], 0, 0, 0);
      }
    }

    // online softmax (rows g*4+jj)
    const bool domask = (kt2 == qt);
    float mrow[4];
#pragma unroll
    for (int jj = 0; jj < 4; jj++) mrow[jj] = -1e30f;
#pragma unroll
    for (int ni = 0; ni < 4; ni++)
#pragma unroll
      for (int jj = 0; jj < 4; jj++) {
        float sval = sacc[ni][jj];
        if (domask && (kt2 * 64 + ni * 16 + r) > (qbs + g * 4 + jj)) sval = -1e30f;
        sacc[ni][jj] = sval;
        mrow[jj] = fmaxf(mrow[jj], sval);
      }
#pragma unroll
    for (int jj = 0; jj < 4; jj++) {
#pragma unroll
      for (int off = 8; off >= 1; off >>= 1)
        mrow[jj] = fmaxf(mrow[jj], __shfl_xor(mrow[jj], off, 64));
    }
    float corr[4];
#pragma unroll
    for (int jj = 0; jj < 4; jj++) {
      float mn = fmaxf(mreg[jj], mrow[jj]);
      corr[jj] = __expf(mreg[jj] - mn);
      mreg[jj] = mn;
      float sm = 0.f;
#pragma unroll
      for (int ni = 0; ni < 4; ni++) {
        float p2 = __expf(sacc[ni][jj] - mn);
        sacc[ni][jj] = p2;
        sm += p2;
      }
#pragma unroll
      for (int off = 8; off >= 1; off >>= 1) sm += __shfl_xor(sm, off, 64);
      lreg[jj] = lreg[jj] * corr[jj] + sm;
    }
#pragma unroll
    for (int di = 0; di < 8; di++)
#pragma unroll
      for (int jj = 0; jj < 4; jj++) oacc[di][jj] *= corr[jj];

    // P -> wave-private LDS (swizzled)
#pragma unroll
    for (int ni = 0; ni < 4; ni++)
#pragma unroll
      for (int jj = 0; jj < 4; jj++) {
        int prow = g * 4 + jj;
        int byte = (prow * 128 + ((ni * 16 + r) << 1)) ^ ((prow & 7) << 4);
        *(unsigned short*)(psm_w + byte) = f2bf(sacc[ni][jj]);
      }

    // PV
#pragma unroll
    for (int ksl = 0; ksl < 2; ksl++) {
      s16x8 pa = *(const s16x8*)(psm_w + ((r * 128 + ((ksl * 32 + g * 8) << 1)) ^ ((r & 7) << 4)));
      const int kgran = ksl * 4 + g;
#pragma unroll
      for (int di = 0; di < 8; di++) {
        const int d = di * 16 + r;
        s16x8 vf = *(const s16x8*)(vtsm_c + d * 128 + ((kgran ^ (d & 7)) << 4));
        oacc[di] = __builtin_amdgcn_mfma_f32_16x16x32_bf16(pa, vf, oacc[di], 0, 0, 0);
      }
    }

    __builtin_amdgcn_s_barrier();           // all waves done reading Ksm/VTsm
    if (kt2 + 1 < nt) STAGE(kt2 + 1);
  }
#undef STAGE

  // epilogue
#pragma unroll
  for (int di = 0; di < 8; di++)
#pragma unroll
    for (int jj = 0; jj < 4; jj++) {
      int orow = qbs + g * 4 + jj;
      O[(size_t)(b * S_LEN + orow) * HID + hd * HDIM + di * 16 + r] =
          f2bf(oacc[di][jj] / lreg[jj]);
    }
}

extern "C" void kernel_launch(void* const* d_in, const int* in_sizes, int n_in,
                              void* d_out, int out_size, void* d_ws, size_t ws_size,
                              hipStream_t stream) {
  const float* x      = (const float*)d_in[0];
  const float* norm_w = (const float*)d_in[1];
  const float* wq     = (const float*)d_in[2];
  const float* wk     = (const float*)d_in[3];
  const float* wv     = (const float*)d_in[4];
  const float* wo     = (const float*)d_in[5];
  const int*   pos    = (const int*)d_in[6];
  float* out = (float*)d_out;

  char* ws = (char*)d_ws;
  const size_t WQKV_B = (size_t)3 * HID * HID * 2;   // 24 MB (region A)
  const size_t VT_B   = (size_t)ROWS * HID * 2;      // 16 MB (aliases region A after qkv gemm)
  const size_t H_B    = (size_t)ROWS * HID * 2;      // 16 MB
  const size_t QKV_B  = (size_t)ROWS * QS * 2;       // 48 MB

  unsigned short* wqkvb = (unsigned short*)(ws);            // region A
  unsigned short* vt    = (unsigned short*)(ws);            // reuses region A
  unsigned short* wob   = (unsigned short*)(ws + VT_B);     // region A + 16MB
  unsigned short* h     = (unsigned short*)(ws + WQKV_B);   // also ctx
  unsigned short* qkv   = (unsigned short*)(ws + WQKV_B + H_B);
  float* cost = (float*)(ws + WQKV_B + H_B + QKV_B);
  float* sint = cost + (size_t)S_LEN * 64;

  const int n4 = HID * HID / 4;
  cast_w_kernel<<<n4 / 256, 256, 0, stream>>>(wq, wqkvb, n4);
  cast_w_kernel<<<n4 / 256, 256, 0, stream>>>(wk, wqkvb + (size_t)HID * HID, n4);
  cast_w_kernel<<<n4 / 256, 256, 0, stream>>>(wv, wqkvb + (size_t)2 * HID * HID, n4);
  rope_tab_kernel<<<S_LEN, 64, 0, stream>>>(cost, sint);
  rmsnorm_kernel<<<ROWS, 256, 0, stream>>>(x, norm_w, h);

  dim3 qkvgrid(QS / 256, ROWS / 128);   // 24 x 32 = 768 blocks
  gemm8_kernel<unsigned short, 4><<<qkvgrid, 512, 0, stream>>>(h, wqkvb, qkv, HID, QS);

  // region A is dead now: cast wo into it, build V^T in it
  cast_w_kernel<<<n4 / 256, 256, 0, stream>>>(wo, wob, n4);
  dim3 tgrid(S_LEN / 64, 2, BATCH * NHEADS);
  transpose_v_kernel<<<tgrid, 256, 0, stream>>>(qkv, vt);

  rope_kernel<<<ROWS, 256, 0, stream>>>(pos, cost, sint, qkv);

  attn_kernel<<<1024, 256, 0, stream>>>(qkv, vt, h /* ctx */);

  dim3 ogrid(HID / 128, ROWS / 128);    // 16 x 32 = 512 blocks
  gemm8_kernel<float, 2><<<ogrid, 512, 0, stream>>>(h, wob, out, HID, HID);
}

// Round 8
// 295.136 us; speedup vs baseline: 1.7635x; 1.0103x over previous
//
#include <hip/hip_runtime.h>
#include <hip/hip_bf16.h>
#include <stdint.h>

#define S_LEN   2048
#define BATCH   2
#define HID     2048
#define NHEADS  16
#define HDIM    128
#define ROWS    (BATCH * S_LEN)          // 4096
#define QS      6144                     // qkv row stride (3*HID)
#define ATT_SCALE 0.08838834764831843f   // 1/sqrt(128)

typedef __attribute__((ext_vector_type(8))) short s16x8;
typedef __attribute__((ext_vector_type(4))) float f32x4;

#define GLL16(gp, lp)                                                          \
  __builtin_amdgcn_global_load_lds(                                            \
      (__attribute__((address_space(1))) void*)(gp),                           \
      (__attribute__((address_space(3))) void*)(lp), 16, 0, 0)

__device__ __forceinline__ float bf2f(unsigned short u) {
  union { unsigned int i; float f; } v; v.i = ((unsigned int)u) << 16; return v.f;
}
__device__ __forceinline__ unsigned short f2bf(float f) {
  union { float f; unsigned int i; } v; v.f = f;
  unsigned int i = v.i;
  return (unsigned short)((i + 0x7FFFu + ((i >> 16) & 1u)) >> 16);
}
__device__ __forceinline__ void store_out(unsigned short* p, float v) { *p = f2bf(v); }
__device__ __forceinline__ void store_out(float* p, float v) { *p = v; }

// ---------------- fused weight cast fp32 -> bf16 (4 weights, 1 launch) ----------------
__global__ __launch_bounds__(256) void cast4_kernel(const float* __restrict__ w0,
                                                    const float* __restrict__ w1,
                                                    const float* __restrict__ w2,
                                                    const float* __restrict__ w3,
                                                    unsigned short* __restrict__ dqkv,
                                                    unsigned short* __restrict__ dwo) {
  const int which = blockIdx.y;
  const float* src = (which == 0) ? w0 : (which == 1) ? w1 : (which == 2) ? w2 : w3;
  unsigned short* dst = (which < 3) ? dqkv + (size_t)which * HID * HID : dwo;
  int i = blockIdx.x * 256 + threadIdx.x;
  float4 v = ((const float4*)src)[i];
  ushort4 o;
  o.x = f2bf(v.x); o.y = f2bf(v.y); o.z = f2bf(v.z); o.w = f2bf(v.w);
  ((ushort4*)dst)[i] = o;
}

// ---------------- RMSNorm (fp32 in, bf16 out) ----------------
__global__ __launch_bounds__(256) void rmsnorm_kernel(const float* __restrict__ x,
                                                      const float* __restrict__ w,
                                                      unsigned short* __restrict__ h) {
  int row = blockIdx.x;
  int t = threadIdx.x;
  const float4* xr4 = (const float4*)(x + (size_t)row * HID);
  float4 a = xr4[t], b = xr4[t + 256];
  float ss = a.x*a.x + a.y*a.y + a.z*a.z + a.w*a.w
           + b.x*b.x + b.y*b.y + b.z*b.z + b.w*b.w;
#pragma unroll
  for (int off = 32; off >= 1; off >>= 1) ss += __shfl_xor(ss, off, 64);
  __shared__ float red[4];
  if ((t & 63) == 0) red[t >> 6] = ss;
  __syncthreads();
  float tot = red[0] + red[1] + red[2] + red[3];
  float rs = rsqrtf(tot * (1.0f / (float)HID) + 1e-6f);
  const float4* w4 = (const float4*)w;
  float4 wa = w4[t], wb = w4[t + 256];
  ushort4 oa, ob;
  oa.x = f2bf(a.x * wa.x * rs); oa.y = f2bf(a.y * wa.y * rs);
  oa.z = f2bf(a.z * wa.z * rs); oa.w = f2bf(a.w * wa.w * rs);
  ob.x = f2bf(b.x * wb.x * rs); ob.y = f2bf(b.y * wb.y * rs);
  ob.z = f2bf(b.z * wb.z * rs); ob.w = f2bf(b.w * wb.w * rs);
  ushort4* hr = (ushort4*)(h + (size_t)row * HID);
  hr[t] = oa; hr[t + 256] = ob;
}

// ---------------- RoPE tables ----------------
__global__ void rope_tab_kernel(float* __restrict__ cost, float* __restrict__ sint) {
  int s = blockIdx.x, j = threadIdx.x;  // 64 threads
  float inv = powf(10000.0f, -((float)j) / 64.0f);
  float ang = (float)s * inv;
  cost[s * 64 + j] = cosf(ang);
  sint[s * 64 + j] = sinf(ang);
}

// ---------------- RoPE apply in-place on q,k inside fused qkv ----------------
__global__ __launch_bounds__(256) void rope_kernel(const int* __restrict__ pos_ids,
                                                   const float* __restrict__ cost,
                                                   const float* __restrict__ sint,
                                                   unsigned short* __restrict__ qkv) {
  int row = blockIdx.x;            // b*S + s
  int p = pos_ids[row];
  int t = threadIdx.x;
  int head = t >> 4;
  int j0 = (t & 15) * 4;
  size_t base = (size_t)row * QS + head * HDIM;
  float4 c = *(const float4*)(cost + p * 64 + j0);
  float4 s = *(const float4*)(sint + p * 64 + j0);
#pragma unroll
  for (int which = 0; which < 2; which++) {
    unsigned short* ptr = qkv + base + which * HID;  // q then k
    float sc = which ? 1.0f : ATT_SCALE;
    ushort4 v1 = *(ushort4*)(ptr + j0);
    ushort4 v2 = *(ushort4*)(ptr + 64 + j0);
    ushort4 o1, o2;
    o1.x = f2bf((bf2f(v1.x) * c.x - bf2f(v2.x) * s.x) * sc);
    o1.y = f2bf((bf2f(v1.y) * c.y - bf2f(v2.y) * s.y) * sc);
    o1.z = f2bf((bf2f(v1.z) * c.z - bf2f(v2.z) * s.z) * sc);
    o1.w = f2bf((bf2f(v1.w) * c.w - bf2f(v2.w) * s.w) * sc);
    o2.x = f2bf((bf2f(v2.x) * c.x + bf2f(v1.x) * s.x) * sc);
    o2.y = f2bf((bf2f(v2.y) * c.y + bf2f(v1.y) * s.y) * sc);
    o2.z = f2bf((bf2f(v2.z) * c.z + bf2f(v1.z) * s.z) * sc);
    o2.w = f2bf((bf2f(v2.w) * c.w + bf2f(v1.w) * s.w) * sc);
    *(ushort4*)(ptr + j0) = o1;
    *(ushort4*)(ptr + 64 + j0) = o2;
  }
}

// ---------------- V transpose: qkv v-block [tok][d] -> vt [bh*128+d][S] ----------------
__global__ __launch_bounds__(256) void transpose_v_kernel(const unsigned short* __restrict__ qkv,
                                                          unsigned short* __restrict__ vt) {
  __shared__ unsigned short tile[64][72];
  const int stile = blockIdx.x, dt = blockIdx.y, bh = blockIdx.z;
  const int t = threadIdx.x;
  const int b = bh >> 4, h = bh & 15;
  const int s0 = stile * 64;
  const unsigned short* src = qkv + (size_t)(b * S_LEN + s0) * QS + 2 * HID + h * HDIM + dt * 64;
#pragma unroll
  for (int it = 0; it < 2; it++) {
    int sl = (t >> 3) + 32 * it;
    int dl = (t & 7) * 8;
    *(s16x8*)&tile[sl][dl] = *(const s16x8*)(src + (size_t)sl * QS + dl);
  }
  __syncthreads();
#pragma unroll
  for (int it = 0; it < 2; it++) {
    int dl = (t >> 3) + 32 * it;
    int sl8 = (t & 7) * 8;
    s16x8 o;
#pragma unroll
    for (int jj = 0; jj < 8; jj++) o[jj] = (short)tile[sl8 + jj][dl];
    *(s16x8*)(vt + (size_t)(bh * 128 + dt * 64 + dl) * S_LEN + s0 + sl8) = o;
  }
}

// ---------------- 256x256 kk-half-staggered GEMM (QK projection) ----------------
// BM=BN=256, BK=64, 8 waves (2M x 4N), wave = 128x64 out (0.375 ds_read/MFMA).
// LDS 128KB: [2buf][2kk]{A 256x32 + B 256x32}. Stage unit = kk-half (4 loads/thr):
// h0 at P0, h1 at P2 of previous tile -> vmcnt(4) gate twice per tile, never 0
// mid-loop. Unit rows are 64B; swizzle slot = g ^ (r&3) ^ ((r>>2)&3) (involutive,
// uniform 8 lanes per 16B slot = conflict-free).
#define SH(kt, bi, kk2) {                                                      \
    const unsigned short* sa_ = aQ + (size_t)(kt) * 64 + (kk2) * 32;           \
    const unsigned short* sb_ = bQ + (size_t)(kt) * 64 + (kk2) * 32;           \
    char* da_ = qsm + ((bi) * 2 + (kk2)) * 32768 + tid * 16;                   \
    GLL16(sa_, da_);                                                           \
    GLL16(sa_ + (size_t)128 * K, da_ + 8192);                                  \
    GLL16(sb_, da_ + 16384);                                                   \
    GLL16(sb_ + (size_t)128 * K, da_ + 16384 + 8192);                          \
  }

__global__ __launch_bounds__(512, 2) void gemm_qk_kernel(const unsigned short* __restrict__ A,
                                                         const unsigned short* __restrict__ B,
                                                         unsigned short* __restrict__ C,
                                                         int K, int N) {
  __shared__ __align__(16) unsigned short Qsm[2][2][2][256 * 32];  // 128 KB
  const int bm = blockIdx.y, bn = blockIdx.x;
  const int tid = threadIdx.x;
  const int w = tid >> 6, wr = w >> 2, wc = w & 3;
  const int l = tid & 63, g = l >> 4, r = l & 15;
  const int KT = K >> 6;

  // staging: granule idx = tid + 512*i -> row = idx>>2 (+128 for i=1), slot = idx&3
  const int srow = tid >> 2;
  const int sg = (tid & 3) ^ ((tid >> 2) & 3) ^ ((tid >> 4) & 3);
  const unsigned short* aQ = A + (size_t)(bm * 256 + srow) * K + sg * 8;
  const unsigned short* bQ = B + (size_t)(bn * 256 + srow) * K + sg * 8;
  char* const qsm = (char*)Qsm;

  f32x4 zero = {0.f, 0.f, 0.f, 0.f};
  f32x4 acc[8][4];
#pragma unroll
  for (int mi = 0; mi < 8; mi++)
#pragma unroll
    for (int ni = 0; ni < 4; ni++) acc[mi][ni] = zero;

  const int ro = ((g ^ (r & 3) ^ ((r >> 2) & 3)) << 4);
  const int aOff = (wr * 128 + r) * 64 + ro;           // + mi*1024
  const int bOff = 16384 + (wc * 64 + r) * 64 + ro;    // + ni*1024

  SH(0, 0, 0); SH(0, 0, 1);

  for (int kt = 0; kt < KT; ++kt) {
    const int buf = kt & 1;
    const bool more = (kt + 1 < KT);
    const char* l0 = qsm + (buf * 2 + 0) * 32768;
    const char* l1 = qsm + (buf * 2 + 1) * 32768;

    // ---- P0: gate h0(kt); read kk0 frags; stage h0(kt+1); MFMA mi0-3 ----
    asm volatile("s_waitcnt vmcnt(4)" ::: "memory");
    __builtin_amdgcn_s_barrier();
    __builtin_amdgcn_sched_barrier(0);
    s16x8 a[4], b[4];
#pragma unroll
    for (int ni = 0; ni < 4; ni++) b[ni] = *(const s16x8*)(l0 + bOff + ni * 1024);
#pragma unroll
    for (int i = 0; i < 4; i++) a[i] = *(const s16x8*)(l0 + aOff + i * 1024);
    if (more) SH(kt + 1, buf ^ 1, 0);
    __builtin_amdgcn_s_setprio(1);
#pragma unroll
    for (int ni = 0; ni < 4; ni++)
#pragma unroll
      for (int i = 0; i < 4; i++)
        acc[i][ni] = __builtin_amdgcn_mfma_f32_16x16x32_bf16(a[i], b[ni], acc[i][ni], 0, 0, 0);
    __builtin_amdgcn_s_setprio(0);

    // ---- P1: read A mi4-7 kk0; MFMA ----
    s16x8 a2[4];
#pragma unroll
    for (int i = 0; i < 4; i++) a2[i] = *(const s16x8*)(l0 + aOff + (4 + i) * 1024);
    __builtin_amdgcn_s_setprio(1);
#pragma unroll
    for (int ni = 0; ni < 4; ni++)
#pragma unroll
      for (int i = 0; i < 4; i++)
        acc[4 + i][ni] = __builtin_amdgcn_mfma_f32_16x16x32_bf16(a2[i], b[ni], acc[4 + i][ni], 0, 0, 0);
    __builtin_amdgcn_s_setprio(0);

    // ---- P2: gate h1(kt); read kk1 frags; stage h1(kt+1); MFMA mi0-3 ----
    if (more) { asm volatile("s_waitcnt vmcnt(4)" ::: "memory"); }
    else      { asm volatile("s_waitcnt vmcnt(0)" ::: "memory"); }
    __builtin_amdgcn_s_barrier();
    __builtin_amdgcn_sched_barrier(0);
#pragma unroll
    for (int ni = 0; ni < 4; ni++) b[ni] = *(const s16x8*)(l1 + bOff + ni * 1024);
#pragma unroll
    for (int i = 0; i < 4; i++) a[i] = *(const s16x8*)(l1 + aOff + i * 1024);
    if (more) SH(kt + 1, buf ^ 1, 1);
    __builtin_amdgcn_s_setprio(1);
#pragma unroll
    for (int ni = 0; ni < 4; ni++)
#pragma unroll
      for (int i = 0; i < 4; i++)
        acc[i][ni] = __builtin_amdgcn_mfma_f32_16x16x32_bf16(a[i], b[ni], acc[i][ni], 0, 0, 0);
    __builtin_amdgcn_s_setprio(0);

    // ---- P3: read A mi4-7 kk1; MFMA ----
#pragma unroll
    for (int i = 0; i < 4; i++) a2[i] = *(const s16x8*)(l1 + aOff + (4 + i) * 1024);
    __builtin_amdgcn_s_setprio(1);
#pragma unroll
    for (int ni = 0; ni < 4; ni++)
#pragma unroll
      for (int i = 0; i < 4; i++)
        acc[4 + i][ni] = __builtin_amdgcn_mfma_f32_16x16x32_bf16(a2[i], b[ni], acc[4 + i][ni], 0, 0, 0);
    __builtin_amdgcn_s_setprio(0);
  }

  // epilogue
#pragma unroll
  for (int mi = 0; mi < 8; mi++)
#pragma unroll
    for (int ni = 0; ni < 4; ni++) {
      const int crow = bm * 256 + wr * 128 + mi * 16 + g * 4;
      const int ccol = bn * 256 + wc * 64 + ni * 16 + r;
#pragma unroll
      for (int j = 0; j < 4; j++)
        store_out(&C[(size_t)(crow + j) * N + ccol], acc[mi][ni][j]);
    }
}
#undef SH

// ---------------- Triple-buffered counted-vmcnt GEMM (V proj + out-proj) ----------------
#define SA(kt, bi) {                                                           \
    const unsigned short* s_ = aS + (size_t)(kt) * 64;                         \
    char* d_ = (char*)Ab[bi] + tid * 16;                                       \
    GLL16(s_, d_);                                                             \
    GLL16(s_ + (size_t)64 * K, d_ + 8192);                                     \
  }
#define SB(kt, bi, hf) {                                                       \
    const unsigned short* s_ = bS + (size_t)(hf) * 128 * K + (size_t)(kt) * 64;\
    char* d_ = (char*)Bb[bi] + (hf) * 16384 + tid * 16;                        \
    GLL16(s_, d_);                                                             \
    GLL16(s_ + (size_t)64 * K, d_ + 8192);                                     \
  }

template <typename OutT, int NI>
__global__ __launch_bounds__(512, 1) void gemm8_kernel(const unsigned short* __restrict__ A,
                                                       const unsigned short* __restrict__ B,
                                                       OutT* __restrict__ C, int K, int N) {
  __shared__ __align__(16) unsigned short Ab[3][128 * 64];       // 48 KB
  __shared__ __align__(16) unsigned short Bb[3][NI * 64 * 64];   // 96 or 48 KB
  const int bm = blockIdx.y, bn = blockIdx.x;                    // plain mapping
  const int tid = threadIdx.x;
  const int w = tid >> 6, wr = w >> 2, wc = w & 3;
  const int l = tid & 63, g = l >> 4, r = l & 15;
  const int KT = K >> 6;

  const int srow = tid >> 3;
  const int sgr = (tid & 7) ^ (srow & 7);
  const unsigned short* aS = A + (size_t)(bm * 128 + srow) * K + sgr * 8;
  const unsigned short* bS = B + (size_t)(bn * (NI * 64) + srow) * K + sgr * 8;

  f32x4 zero = {0.f, 0.f, 0.f, 0.f};
  f32x4 acc[4][NI];
#pragma unroll
  for (int mi = 0; mi < 4; mi++)
#pragma unroll
    for (int ni = 0; ni < NI; ni++) acc[mi][ni] = zero;

  const int swx = (r & 7) << 4;
  const int ks0 = (g << 4) ^ swx;
  const int ks1 = ((4 | g) << 4) ^ swx;
  const int aOff = (wr * 64 + r) * 128;
  const int bOff = (wc * (NI * 16) + r) * 128;

  SA(0, 0); SB(0, 0, 0); if (NI == 4) SB(0, 0, 1);
  SA(1, 1); SB(1, 1, 0); if (NI == 4) SB(1, 1, 1);

  int cur = 0;
  for (int kt = 0; kt < KT; ++kt) {
    const int b2 = (cur >= 1) ? cur - 1 : cur + 2;   // (cur+2)%3
    if (kt == KT - 1)      { asm volatile("s_waitcnt vmcnt(0)" ::: "memory"); }
    else if (NI == 4)      { asm volatile("s_waitcnt vmcnt(6)" ::: "memory"); }
    else                   { asm volatile("s_waitcnt vmcnt(4)" ::: "memory"); }
    __builtin_amdgcn_s_barrier();
    __builtin_amdgcn_sched_barrier(0);
    const char* lA = (const char*)Ab[cur];
    const char* lB = (const char*)Bb[cur];
    const bool more = (kt + 2 < KT);

    s16x8 a[4][2], b[NI][2];
#pragma unroll
    for (int mi = 0; mi < 4; mi++) {
      a[mi][0] = *(const s16x8*)(lA + aOff + mi * 2048 + ks0);
      a[mi][1] = *(const s16x8*)(lA + aOff + mi * 2048 + ks1);
    }
#pragma unroll
    for (int ni = 0; ni < NI / 2; ni++) {
      b[ni][0] = *(const s16x8*)(lB + bOff + ni * 2048 + ks0);
      b[ni][1] = *(const s16x8*)(lB + bOff + ni * 2048 + ks1);
    }
    if (more) { SA(kt + 2, b2); if (NI == 4) SB(kt + 2, b2, 0); }
    __builtin_amdgcn_s_setprio(1);
#pragma unroll
    for (int kk = 0; kk < 2; kk++)
#pragma unroll
      for (int ni = 0; ni < NI / 2; ni++)
#pragma unroll
        for (int mi = 0; mi < 4; mi++)
          acc[mi][ni] = __builtin_amdgcn_mfma_f32_16x16x32_bf16(a[mi][kk], b[ni][kk], acc[mi][ni], 0, 0, 0);
    __builtin_amdgcn_s_setprio(0);
    __builtin_amdgcn_sched_barrier(0);

#pragma unroll
    for (int ni = NI / 2; ni < NI; ni++) {
      b[ni][0] = *(const s16x8*)(lB + bOff + ni * 2048 + ks0);
      b[ni][1] = *(const s16x8*)(lB + bOff + ni * 2048 + ks1);
    }
    if (more) { if (NI == 4) { SB(kt + 2, b2, 1); } else { SB(kt + 2, b2, 0); } }
    __builtin_amdgcn_s_setprio(1);
#pragma unroll
    for (int kk = 0; kk < 2; kk++)
#pragma unroll
      for (int ni = NI / 2; ni < NI; ni++)
#pragma unroll
        for (int mi = 0; mi < 4; mi++)
          acc[mi][ni] = __builtin_amdgcn_mfma_f32_16x16x32_bf16(a[mi][kk], b[ni][kk], acc[mi][ni], 0, 0, 0);
    __builtin_amdgcn_s_setprio(0);
    cur = (cur == 2) ? 0 : cur + 1;
  }

#pragma unroll
  for (int mi = 0; mi < 4; mi++)
#pragma unroll
    for (int ni = 0; ni < NI; ni++) {
      const int crow = bm * 128 + wr * 64 + mi * 16 + g * 4;
      const int ccol = bn * (NI * 64) + wc * (NI * 16) + ni * 16 + r;
#pragma unroll
      for (int j = 0; j < 4; j++)
        store_out(&C[(size_t)(crow + j) * N + ccol], acc[mi][ni][j]);
    }
}

// ---------------- Flash attention, causal (round-7 structure, unchanged) ----------------
__global__ __launch_bounds__(256, 4) void attn_kernel(const unsigned short* __restrict__ QKV,
                                                      const unsigned short* __restrict__ VT,
                                                      unsigned short* __restrict__ O) {
  __shared__ __align__(16) unsigned short Ksm[64 * 128];    // 16KB swizzled
  __shared__ __align__(16) unsigned short VTsm[128 * 64];   // 16KB swizzled
  __shared__ __align__(16) unsigned short Psm[4 * 16 * 64]; // 8KB per-wave
  const int bid = blockIdx.x;
  const int grp = bid & 7, idx = bid >> 3;     // idx 0..127
  const int qt = 31 - (idx >> 2);              // heavy-first (LPT)
  const int bh = (grp << 2) | (idx & 3);
  const int b = bh >> 4, hd = bh & 15;
  const int tid = threadIdx.x, w = tid >> 6, l = tid & 63, g = l >> 4, r = l & 15;
  const int qbs = qt * 64 + w * 16;            // wave's q-row base (16 rows)

  const unsigned short* qp = QKV + (size_t)(b * S_LEN + qbs + r) * QS + hd * HDIM;
  s16x8 qf[4];
#pragma unroll
  for (int ks = 0; ks < 4; ks++) qf[ks] = *(const s16x8*)(qp + ks * 32 + g * 8);

  float mreg[4], lreg[4];
  f32x4 zero = {0.f, 0.f, 0.f, 0.f};
  f32x4 oacc[8];
#pragma unroll
  for (int jj = 0; jj < 4; jj++) { mreg[jj] = -1e30f; lreg[jj] = 0.f; }
#pragma unroll
  for (int di = 0; di < 8; di++) oacc[di] = zero;

  const int cK = tid & 15, rowK = tid >> 4;            // 0..15 (+16/i)
  const unsigned short* kp_base = QKV + (size_t)(b * S_LEN + rowK) * QS + HID + hd * HDIM
                                  + ((cK ^ (rowK & 7)) << 3);
  const int cV = tid & 7, dV = tid >> 3;               // 0..31 (+32/i)
  const unsigned short* vp_base = VT + (size_t)(bh * 128 + dV) * S_LEN + ((cV ^ (dV & 7)) << 3);
  char* const ksm_c = (char*)Ksm;
  char* const vtsm_c = (char*)VTsm;
  char* const psm_w = (char*)Psm + w * 2048;

#define STAGE(kt)                                                              \
  {                                                                            \
    const unsigned short* kp_ = kp_base + (size_t)((kt) * 64) * QS;            \
    const unsigned short* vp_ = vp_base + (kt) * 64;                           \
    GLL16(kp_,                      ksm_c + tid * 16);                         \
    GLL16(kp_ + (size_t)16 * QS,    ksm_c + (tid + 256) * 16);                 \
    GLL16(kp_ + (size_t)32 * QS,    ksm_c + (tid + 512) * 16);                 \
    GLL16(kp_ + (size_t)48 * QS,    ksm_c + (tid + 768) * 16);                 \
    GLL16(vp_,                      vtsm_c + tid * 16);                        \
    GLL16(vp_ + (size_t)32 * S_LEN, vtsm_c + (tid + 256) * 16);                \
    GLL16(vp_ + (size_t)64 * S_LEN, vtsm_c + (tid + 512) * 16);                \
    GLL16(vp_ + (size_t)96 * S_LEN, vtsm_c + (tid + 768) * 16);                \
  }

  const int nt = qt + 1;
  STAGE(0);

  for (int kt2 = 0; kt2 < nt; kt2++) {
    asm volatile("s_waitcnt vmcnt(0)" ::: "memory");
    __builtin_amdgcn_s_barrier();
    __builtin_amdgcn_sched_barrier(0);

    f32x4 sacc[4];
#pragma unroll
    for (int ni = 0; ni < 4; ni++) sacc[ni] = zero;
#pragma unroll
    for (int ni = 0; ni < 4; ni++) {
      const int krow = ni * 16 + r;
      const int swz = (krow & 7) << 4;
      const char* kb2 = ksm_c + krow * 256;
#pragma unroll
      for (int ks = 0; ks < 4; ks++) {
        s16x8 kf = *(const s16x8*)(kb2 + ((ks * 64 + g * 16) ^ swz));
        sacc[ni] = __builtin_amdgcn_mfma_f32_16x16x32_bf16(qf[ks], kf, sacc[ni], 0, 0, 0);
      }
    }

    const bool domask = (kt2 == qt);
    float mrow[4];
#pragma unroll
    for (int jj = 0; jj < 4; jj++) mrow[jj] = -1e30f;
#pragma unroll
    for (int ni = 0; ni < 4; ni++)
#pragma unroll
      for (int jj = 0; jj < 4; jj++) {
        float sval = sacc[ni][jj];
        if (domask && (kt2 * 64 + ni * 16 + r) > (qbs + g * 4 + jj)) sval = -1e30f;
        sacc[ni][jj] = sval;
        mrow[jj] = fmaxf(mrow[jj], sval);
      }
#pragma unroll
    for (int jj = 0; jj < 4; jj++) {
#pragma unroll
      for (int off = 8; off >= 1; off >>= 1)
        mrow[jj] = fmaxf(mrow[jj], __shfl_xor(mrow[jj], off, 64));
    }
    float corr[4];
#pragma unroll
    for (int jj = 0; jj < 4; jj++) {
      float mn = fmaxf(mreg[jj], mrow[jj]);
      corr[jj] = __expf(mreg[jj] - mn);
      mreg[jj] = mn;
      float sm = 0.f;
#pragma unroll
      for (int ni = 0; ni < 4; ni++) {
        float p2 = __expf(sacc[ni][jj] - mn);
        sacc[ni][jj] = p2;
        sm += p2;
      }
#pragma unroll
      for (int off = 8; off >= 1; off >>= 1) sm += __shfl_xor(sm, off, 64);
      lreg[jj] = lreg[jj] * corr[jj] + sm;
    }
#pragma unroll
    for (int di = 0; di < 8; di++)
#pragma unroll
      for (int jj = 0; jj < 4; jj++) oacc[di][jj] *= corr[jj];

#pragma unroll
    for (int ni = 0; ni < 4; ni++)
#pragma unroll
      for (int jj = 0; jj < 4; jj++) {
        int prow = g * 4 + jj;
        int byte = (prow * 128 + ((ni * 16 + r) << 1)) ^ ((prow & 7) << 4);
        *(unsigned short*)(psm_w + byte) = f2bf(sacc[ni][jj]);
      }

#pragma unroll
    for (int ksl = 0; ksl < 2; ksl++) {
      s16x8 pa = *(const s16x8*)(psm_w + ((r * 128 + ((ksl * 32 + g * 8) << 1)) ^ ((r & 7) << 4)));
      const int kgran = ksl * 4 + g;
#pragma unroll
      for (int di = 0; di < 8; di++) {
        const int d = di * 16 + r;
        s16x8 vf = *(const s16x8*)(vtsm_c + d * 128 + ((kgran ^ (d & 7)) << 4));
        oacc[di] = __builtin_amdgcn_mfma_f32_16x16x32_bf16(pa, vf, oacc[di], 0, 0, 0);
      }
    }

    __builtin_amdgcn_s_barrier();           // all waves done reading Ksm/VTsm
    if (kt2 + 1 < nt) STAGE(kt2 + 1);
  }
#undef STAGE

#pragma unroll
  for (int di = 0; di < 8; di++)
#pragma unroll
    for (int jj = 0; jj < 4; jj++) {
      int orow = qbs + g * 4 + jj;
      O[(size_t)(b * S_LEN + orow) * HID + hd * HDIM + di * 16 + r] =
          f2bf(oacc[di][jj] / lreg[jj]);
    }
}

extern "C" void kernel_launch(void* const* d_in, const int* in_sizes, int n_in,
                              void* d_out, int out_size, void* d_ws, size_t ws_size,
                              hipStream_t stream) {
  const float* x      = (const float*)d_in[0];
  const float* norm_w = (const float*)d_in[1];
  const float* wq     = (const float*)d_in[2];
  const float* wk     = (const float*)d_in[3];
  const float* wv     = (const float*)d_in[4];
  const float* wo     = (const float*)d_in[5];
  const int*   pos    = (const int*)d_in[6];
  float* out = (float*)d_out;

  char* ws = (char*)d_ws;
  const size_t WQKV_B = (size_t)3 * HID * HID * 2;   // 24 MB
  const size_t WO_B   = (size_t)HID * HID * 2;       // 8 MB
  const size_t H_B    = (size_t)ROWS * HID * 2;      // 16 MB
  const size_t QKV_B  = (size_t)ROWS * QS * 2;       // 48 MB

  unsigned short* wqkvb = (unsigned short*)(ws);                     // [0,24)
  unsigned short* vt    = (unsigned short*)(ws);                     // aliases [0,16) after gemms
  unsigned short* wob   = (unsigned short*)(ws + WQKV_B);            // [24,32)
  unsigned short* h     = (unsigned short*)(ws + WQKV_B + WO_B);     // [32,48) also ctx
  unsigned short* qkv   = (unsigned short*)(ws + WQKV_B + WO_B + H_B);           // [48,96)
  float* cost = (float*)(ws + WQKV_B + WO_B + H_B + QKV_B);
  float* sint = cost + (size_t)S_LEN * 64;

  dim3 cgrid(HID * HID / 4 / 256, 4);
  cast4_kernel<<<cgrid, 256, 0, stream>>>(wq, wk, wv, wo, wqkvb, wob);
  rope_tab_kernel<<<S_LEN, 64, 0, stream>>>(cost, sint);
  rmsnorm_kernel<<<ROWS, 256, 0, stream>>>(x, norm_w, h);

  // Q,K projection: 256x256-tile kernel, 16x16 = 256 blocks (1/CU, no tail)
  dim3 qkgrid(2 * HID / 256, ROWS / 256);
  gemm_qk_kernel<<<qkgrid, 512, 0, stream>>>(h, wqkvb, qkv, HID, QS);

  // V projection: proven gemm8, 8x32 = 256 blocks
  dim3 vgrid(HID / 256, ROWS / 128);
  gemm8_kernel<unsigned short, 4><<<vgrid, 512, 0, stream>>>(
      h, wqkvb + (size_t)2 * HID * HID, qkv + 2 * HID, HID, QS);

  dim3 tgrid(S_LEN / 64, 2, BATCH * NHEADS);
  transpose_v_kernel<<<tgrid, 256, 0, stream>>>(qkv, vt);

  rope_kernel<<<ROWS, 256, 0, stream>>>(pos, cost, sint, qkv);

  attn_kernel<<<1024, 256, 0, stream>>>(qkv, vt, h /* ctx */);

  dim3 ogrid(HID / 128, ROWS / 128);    // 16 x 32 = 512 blocks
  gemm8_kernel<float, 2><<<ogrid, 512, 0, stream>>>(h, wob, out, HID, HID);
}

// Round 9
// 284.555 us; speedup vs baseline: 1.8291x; 1.0372x over previous
//
#include <hip/hip_runtime.h>
#include <hip/hip_bf16.h>
#include <stdint.h>

#define S_LEN   2048
#define BATCH   2
#define HID     2048
#define NHEADS  16
#define HDIM    128
#define ROWS    (BATCH * S_LEN)          // 4096
#define QS      6144                     // qkv row stride (3*HID)
#define ATT_SCALE 0.08838834764831843f   // 1/sqrt(128)
#define LOG2E     1.4426950408889634f

typedef __attribute__((ext_vector_type(8))) short s16x8;
typedef __attribute__((ext_vector_type(4))) float f32x4;

#define GLL16(gp, lp)                                                          \
  __builtin_amdgcn_global_load_lds(                                            \
      (__attribute__((address_space(1))) void*)(gp),                           \
      (__attribute__((address_space(3))) void*)(lp), 16, 0, 0)

__device__ __forceinline__ float bf2f(unsigned short u) {
  union { unsigned int i; float f; } v; v.i = ((unsigned int)u) << 16; return v.f;
}
__device__ __forceinline__ unsigned short f2bf(float f) {
  union { float f; unsigned int i; } v; v.f = f;
  unsigned int i = v.i;
  return (unsigned short)((i + 0x7FFFu + ((i >> 16) & 1u)) >> 16);
}
__device__ __forceinline__ void store_out(unsigned short* p, float v) { *p = f2bf(v); }
__device__ __forceinline__ void store_out(float* p, float v) { *p = v; }

// ---------------- fused weight cast fp32 -> bf16 (4 weights, 1 launch) ----------------
__global__ __launch_bounds__(256) void cast4_kernel(const float* __restrict__ w0,
                                                    const float* __restrict__ w1,
                                                    const float* __restrict__ w2,
                                                    const float* __restrict__ w3,
                                                    unsigned short* __restrict__ dqkv,
                                                    unsigned short* __restrict__ dwo) {
  const int which = blockIdx.y;
  const float* src = (which == 0) ? w0 : (which == 1) ? w1 : (which == 2) ? w2 : w3;
  unsigned short* dst = (which < 3) ? dqkv + (size_t)which * HID * HID : dwo;
  int i = blockIdx.x * 256 + threadIdx.x;
  float4 v = ((const float4*)src)[i];
  ushort4 o;
  o.x = f2bf(v.x); o.y = f2bf(v.y); o.z = f2bf(v.z); o.w = f2bf(v.w);
  ((ushort4*)dst)[i] = o;
}

// ---------------- RMSNorm (fp32 in, bf16 out) ----------------
__global__ __launch_bounds__(256) void rmsnorm_kernel(const float* __restrict__ x,
                                                      const float* __restrict__ w,
                                                      unsigned short* __restrict__ h) {
  int row = blockIdx.x;
  int t = threadIdx.x;
  const float4* xr4 = (const float4*)(x + (size_t)row * HID);
  float4 a = xr4[t], b = xr4[t + 256];
  float ss = a.x*a.x + a.y*a.y + a.z*a.z + a.w*a.w
           + b.x*b.x + b.y*b.y + b.z*b.z + b.w*b.w;
#pragma unroll
  for (int off = 32; off >= 1; off >>= 1) ss += __shfl_xor(ss, off, 64);
  __shared__ float red[4];
  if ((t & 63) == 0) red[t >> 6] = ss;
  __syncthreads();
  float tot = red[0] + red[1] + red[2] + red[3];
  float rs = rsqrtf(tot * (1.0f / (float)HID) + 1e-6f);
  const float4* w4 = (const float4*)w;
  float4 wa = w4[t], wb = w4[t + 256];
  ushort4 oa, ob;
  oa.x = f2bf(a.x * wa.x * rs); oa.y = f2bf(a.y * wa.y * rs);
  oa.z = f2bf(a.z * wa.z * rs); oa.w = f2bf(a.w * wa.w * rs);
  ob.x = f2bf(b.x * wb.x * rs); ob.y = f2bf(b.y * wb.y * rs);
  ob.z = f2bf(b.z * wb.z * rs); ob.w = f2bf(b.w * wb.w * rs);
  ushort4* hr = (ushort4*)(h + (size_t)row * HID);
  hr[t] = oa; hr[t + 256] = ob;
}

// ---------------- RoPE tables ----------------
__global__ void rope_tab_kernel(float* __restrict__ cost, float* __restrict__ sint) {
  int s = blockIdx.x, j = threadIdx.x;  // 64 threads
  float inv = powf(10000.0f, -((float)j) / 64.0f);
  float ang = (float)s * inv;
  cost[s * 64 + j] = cosf(ang);
  sint[s * 64 + j] = sinf(ang);
}

// ---------------- RoPE apply in-place on q,k inside fused qkv ----------------
// q pre-scaled by ATT_SCALE*log2(e): attention softmax runs in the exp2 domain.
__global__ __launch_bounds__(256) void rope_kernel(const int* __restrict__ pos_ids,
                                                   const float* __restrict__ cost,
                                                   const float* __restrict__ sint,
                                                   unsigned short* __restrict__ qkv) {
  int row = blockIdx.x;            // b*S + s
  int p = pos_ids[row];
  int t = threadIdx.x;
  int head = t >> 4;
  int j0 = (t & 15) * 4;
  size_t base = (size_t)row * QS + head * HDIM;
  float4 c = *(const float4*)(cost + p * 64 + j0);
  float4 s = *(const float4*)(sint + p * 64 + j0);
#pragma unroll
  for (int which = 0; which < 2; which++) {
    unsigned short* ptr = qkv + base + which * HID;  // q then k
    float sc = which ? 1.0f : (ATT_SCALE * LOG2E);
    ushort4 v1 = *(ushort4*)(ptr + j0);
    ushort4 v2 = *(ushort4*)(ptr + 64 + j0);
    ushort4 o1, o2;
    o1.x = f2bf((bf2f(v1.x) * c.x - bf2f(v2.x) * s.x) * sc);
    o1.y = f2bf((bf2f(v1.y) * c.y - bf2f(v2.y) * s.y) * sc);
    o1.z = f2bf((bf2f(v1.z) * c.z - bf2f(v2.z) * s.z) * sc);
    o1.w = f2bf((bf2f(v1.w) * c.w - bf2f(v2.w) * s.w) * sc);
    o2.x = f2bf((bf2f(v2.x) * c.x + bf2f(v1.x) * s.x) * sc);
    o2.y = f2bf((bf2f(v2.y) * c.y + bf2f(v1.y) * s.y) * sc);
    o2.z = f2bf((bf2f(v2.z) * c.z + bf2f(v1.z) * s.z) * sc);
    o2.w = f2bf((bf2f(v2.w) * c.w + bf2f(v1.w) * s.w) * sc);
    *(ushort4*)(ptr + j0) = o1;
    *(ushort4*)(ptr + 64 + j0) = o2;
  }
}

// ---------------- V transpose: qkv v-block [tok][d] -> vt [bh*128+d][S] ----------------
__global__ __launch_bounds__(256) void transpose_v_kernel(const unsigned short* __restrict__ qkv,
                                                          unsigned short* __restrict__ vt) {
  __shared__ unsigned short tile[64][72];
  const int stile = blockIdx.x, dt = blockIdx.y, bh = blockIdx.z;
  const int t = threadIdx.x;
  const int b = bh >> 4, h = bh & 15;
  const int s0 = stile * 64;
  const unsigned short* src = qkv + (size_t)(b * S_LEN + s0) * QS + 2 * HID + h * HDIM + dt * 64;
#pragma unroll
  for (int it = 0; it < 2; it++) {
    int sl = (t >> 3) + 32 * it;
    int dl = (t & 7) * 8;
    *(s16x8*)&tile[sl][dl] = *(const s16x8*)(src + (size_t)sl * QS + dl);
  }
  __syncthreads();
#pragma unroll
  for (int it = 0; it < 2; it++) {
    int dl = (t >> 3) + 32 * it;
    int sl8 = (t & 7) * 8;
    s16x8 o;
#pragma unroll
    for (int jj = 0; jj < 8; jj++) o[jj] = (short)tile[sl8 + jj][dl];
    *(s16x8*)(vt + (size_t)(bh * 128 + dt * 64 + dl) * S_LEN + s0 + sl8) = o;
  }
}

// ---------------- 256x256 kk-half-staggered GEMM (QK projection) ----------------
#define SH(kt, bi, kk2) {                                                      \
    const unsigned short* sa_ = aQ + (size_t)(kt) * 64 + (kk2) * 32;           \
    const unsigned short* sb_ = bQ + (size_t)(kt) * 64 + (kk2) * 32;           \
    char* da_ = qsm + ((bi) * 2 + (kk2)) * 32768 + tid * 16;                   \
    GLL16(sa_, da_);                                                           \
    GLL16(sa_ + (size_t)128 * K, da_ + 8192);                                  \
    GLL16(sb_, da_ + 16384);                                                   \
    GLL16(sb_ + (size_t)128 * K, da_ + 16384 + 8192);                          \
  }

__global__ __launch_bounds__(512, 2) void gemm_qk_kernel(const unsigned short* __restrict__ A,
                                                         const unsigned short* __restrict__ B,
                                                         unsigned short* __restrict__ C,
                                                         int K, int N) {
  __shared__ __align__(16) unsigned short Qsm[2][2][2][256 * 32];  // 128 KB
  const int bm = blockIdx.y, bn = blockIdx.x;
  const int tid = threadIdx.x;
  const int w = tid >> 6, wr = w >> 2, wc = w & 3;
  const int l = tid & 63, g = l >> 4, r = l & 15;
  const int KT = K >> 6;

  const int srow = tid >> 2;
  const int sg = (tid & 3) ^ ((tid >> 2) & 3) ^ ((tid >> 4) & 3);
  const unsigned short* aQ = A + (size_t)(bm * 256 + srow) * K + sg * 8;
  const unsigned short* bQ = B + (size_t)(bn * 256 + srow) * K + sg * 8;
  char* const qsm = (char*)Qsm;

  f32x4 zero = {0.f, 0.f, 0.f, 0.f};
  f32x4 acc[8][4];
#pragma unroll
  for (int mi = 0; mi < 8; mi++)
#pragma unroll
    for (int ni = 0; ni < 4; ni++) acc[mi][ni] = zero;

  const int ro = ((g ^ (r & 3) ^ ((r >> 2) & 3)) << 4);
  const int aOff = (wr * 128 + r) * 64 + ro;           // + mi*1024
  const int bOff = 16384 + (wc * 64 + r) * 64 + ro;    // + ni*1024

  SH(0, 0, 0); SH(0, 0, 1);

  for (int kt = 0; kt < KT; ++kt) {
    const int buf = kt & 1;
    const bool more = (kt + 1 < KT);
    const char* l0 = qsm + (buf * 2 + 0) * 32768;
    const char* l1 = qsm + (buf * 2 + 1) * 32768;

    asm volatile("s_waitcnt vmcnt(4)" ::: "memory");
    __builtin_amdgcn_s_barrier();
    __builtin_amdgcn_sched_barrier(0);
    s16x8 a[4], b[4];
#pragma unroll
    for (int ni = 0; ni < 4; ni++) b[ni] = *(const s16x8*)(l0 + bOff + ni * 1024);
#pragma unroll
    for (int i = 0; i < 4; i++) a[i] = *(const s16x8*)(l0 + aOff + i * 1024);
    if (more) SH(kt + 1, buf ^ 1, 0);
    __builtin_amdgcn_s_setprio(1);
#pragma unroll
    for (int ni = 0; ni < 4; ni++)
#pragma unroll
      for (int i = 0; i < 4; i++)
        acc[i][ni] = __builtin_amdgcn_mfma_f32_16x16x32_bf16(a[i], b[ni], acc[i][ni], 0, 0, 0);
    __builtin_amdgcn_s_setprio(0);

    s16x8 a2[4];
#pragma unroll
    for (int i = 0; i < 4; i++) a2[i] = *(const s16x8*)(l0 + aOff + (4 + i) * 1024);
    __builtin_amdgcn_s_setprio(1);
#pragma unroll
    for (int ni = 0; ni < 4; ni++)
#pragma unroll
      for (int i = 0; i < 4; i++)
        acc[4 + i][ni] = __builtin_amdgcn_mfma_f32_16x16x32_bf16(a2[i], b[ni], acc[4 + i][ni], 0, 0, 0);
    __builtin_amdgcn_s_setprio(0);

    if (more) { asm volatile("s_waitcnt vmcnt(4)" ::: "memory"); }
    else      { asm volatile("s_waitcnt vmcnt(0)" ::: "memory"); }
    __builtin_amdgcn_s_barrier();
    __builtin_amdgcn_sched_barrier(0);
#pragma unroll
    for (int ni = 0; ni < 4; ni++) b[ni] = *(const s16x8*)(l1 + bOff + ni * 1024);
#pragma unroll
    for (int i = 0; i < 4; i++) a[i] = *(const s16x8*)(l1 + aOff + i * 1024);
    if (more) SH(kt + 1, buf ^ 1, 1);
    __builtin_amdgcn_s_setprio(1);
#pragma unroll
    for (int ni = 0; ni < 4; ni++)
#pragma unroll
      for (int i = 0; i < 4; i++)
        acc[i][ni] = __builtin_amdgcn_mfma_f32_16x16x32_bf16(a[i], b[ni], acc[i][ni], 0, 0, 0);
    __builtin_amdgcn_s_setprio(0);

#pragma unroll
    for (int i = 0; i < 4; i++) a2[i] = *(const s16x8*)(l1 + aOff + (4 + i) * 1024);
    __builtin_amdgcn_s_setprio(1);
#pragma unroll
    for (int ni = 0; ni < 4; ni++)
#pragma unroll
      for (int i = 0; i < 4; i++)
        acc[4 + i][ni] = __builtin_amdgcn_mfma_f32_16x16x32_bf16(a2[i], b[ni], acc[4 + i][ni], 0, 0, 0);
    __builtin_amdgcn_s_setprio(0);
  }

#pragma unroll
  for (int mi = 0; mi < 8; mi++)
#pragma unroll
    for (int ni = 0; ni < 4; ni++) {
      const int crow = bm * 256 + wr * 128 + mi * 16 + g * 4;
      const int ccol = bn * 256 + wc * 64 + ni * 16 + r;
#pragma unroll
      for (int j = 0; j < 4; j++)
        store_out(&C[(size_t)(crow + j) * N + ccol], acc[mi][ni][j]);
    }
}
#undef SH

// ---------------- Triple-buffered counted-vmcnt GEMM (V proj + out-proj) ----------------
#define SA(kt, bi) {                                                           \
    const unsigned short* s_ = aS + (size_t)(kt) * 64;                         \
    char* d_ = (char*)Ab[bi] + tid * 16;                                       \
    GLL16(s_, d_);                                                             \
    GLL16(s_ + (size_t)64 * K, d_ + 8192);                                     \
  }
#define SB(kt, bi, hf) {                                                       \
    const unsigned short* s_ = bS + (size_t)(hf) * 128 * K + (size_t)(kt) * 64;\
    char* d_ = (char*)Bb[bi] + (hf) * 16384 + tid * 16;                        \
    GLL16(s_, d_);                                                             \
    GLL16(s_ + (size_t)64 * K, d_ + 8192);                                     \
  }

template <typename OutT, int NI>
__global__ __launch_bounds__(512, 1) void gemm8_kernel(const unsigned short* __restrict__ A,
                                                       const unsigned short* __restrict__ B,
                                                       OutT* __restrict__ C, int K, int N) {
  __shared__ __align__(16) unsigned short Ab[3][128 * 64];       // 48 KB
  __shared__ __align__(16) unsigned short Bb[3][NI * 64 * 64];   // 96 or 48 KB
  const int bm = blockIdx.y, bn = blockIdx.x;                    // plain mapping
  const int tid = threadIdx.x;
  const int w = tid >> 6, wr = w >> 2, wc = w & 3;
  const int l = tid & 63, g = l >> 4, r = l & 15;
  const int KT = K >> 6;

  const int srow = tid >> 3;
  const int sgr = (tid & 7) ^ (srow & 7);
  const unsigned short* aS = A + (size_t)(bm * 128 + srow) * K + sgr * 8;
  const unsigned short* bS = B + (size_t)(bn * (NI * 64) + srow) * K + sgr * 8;

  f32x4 zero = {0.f, 0.f, 0.f, 0.f};
  f32x4 acc[4][NI];
#pragma unroll
  for (int mi = 0; mi < 4; mi++)
#pragma unroll
    for (int ni = 0; ni < NI; ni++) acc[mi][ni] = zero;

  const int swx = (r & 7) << 4;
  const int ks0 = (g << 4) ^ swx;
  const int ks1 = ((4 | g) << 4) ^ swx;
  const int aOff = (wr * 64 + r) * 128;
  const int bOff = (wc * (NI * 16) + r) * 128;

  SA(0, 0); SB(0, 0, 0); if (NI == 4) SB(0, 0, 1);
  SA(1, 1); SB(1, 1, 0); if (NI == 4) SB(1, 1, 1);

  int cur = 0;
  for (int kt = 0; kt < KT; ++kt) {
    const int b2 = (cur >= 1) ? cur - 1 : cur + 2;   // (cur+2)%3
    if (kt == KT - 1)      { asm volatile("s_waitcnt vmcnt(0)" ::: "memory"); }
    else if (NI == 4)      { asm volatile("s_waitcnt vmcnt(6)" ::: "memory"); }
    else                   { asm volatile("s_waitcnt vmcnt(4)" ::: "memory"); }
    __builtin_amdgcn_s_barrier();
    __builtin_amdgcn_sched_barrier(0);
    const char* lA = (const char*)Ab[cur];
    const char* lB = (const char*)Bb[cur];
    const bool more = (kt + 2 < KT);

    s16x8 a[4][2], b[NI][2];
#pragma unroll
    for (int mi = 0; mi < 4; mi++) {
      a[mi][0] = *(const s16x8*)(lA + aOff + mi * 2048 + ks0);
      a[mi][1] = *(const s16x8*)(lA + aOff + mi * 2048 + ks1);
    }
#pragma unroll
    for (int ni = 0; ni < NI / 2; ni++) {
      b[ni][0] = *(const s16x8*)(lB + bOff + ni * 2048 + ks0);
      b[ni][1] = *(const s16x8*)(lB + bOff + ni * 2048 + ks1);
    }
    if (more) { SA(kt + 2, b2); if (NI == 4) SB(kt + 2, b2, 0); }
    __builtin_amdgcn_s_setprio(1);
#pragma unroll
    for (int kk = 0; kk < 2; kk++)
#pragma unroll
      for (int ni = 0; ni < NI / 2; ni++)
#pragma unroll
        for (int mi = 0; mi < 4; mi++)
          acc[mi][ni] = __builtin_amdgcn_mfma_f32_16x16x32_bf16(a[mi][kk], b[ni][kk], acc[mi][ni], 0, 0, 0);
    __builtin_amdgcn_s_setprio(0);
    __builtin_amdgcn_sched_barrier(0);

#pragma unroll
    for (int ni = NI / 2; ni < NI; ni++) {
      b[ni][0] = *(const s16x8*)(lB + bOff + ni * 2048 + ks0);
      b[ni][1] = *(const s16x8*)(lB + bOff + ni * 2048 + ks1);
    }
    if (more) { if (NI == 4) { SB(kt + 2, b2, 1); } else { SB(kt + 2, b2, 0); } }
    __builtin_amdgcn_s_setprio(1);
#pragma unroll
    for (int kk = 0; kk < 2; kk++)
#pragma unroll
      for (int ni = NI / 2; ni < NI; ni++)
#pragma unroll
        for (int mi = 0; mi < 4; mi++)
          acc[mi][ni] = __builtin_amdgcn_mfma_f32_16x16x32_bf16(a[mi][kk], b[ni][kk], acc[mi][ni], 0, 0, 0);
    __builtin_amdgcn_s_setprio(0);
    cur = (cur == 2) ? 0 : cur + 1;
  }

#pragma unroll
  for (int mi = 0; mi < 4; mi++)
#pragma unroll
    for (int ni = 0; ni < NI; ni++) {
      const int crow = bm * 128 + wr * 64 + mi * 16 + g * 4;
      const int ccol = bn * (NI * 64) + wc * (NI * 16) + ni * 16 + r;
#pragma unroll
      for (int j = 0; j < 4; j++)
        store_out(&C[(size_t)(crow + j) * N + ccol], acc[mi][ni][j]);
    }
}

// ---------------- Flash attention, causal ----------------
// 1024 blocks x 256 thr (4 waves); block = 64-row q-tile; LPT + XCD-chunked.
// KV double-buffered (72 KB -> 2 blocks/CU); STAGE(kt+1) issued right after the
// top barrier so loads fly under the whole tile compute; ONE barrier per tile.
// Softmax in exp2 domain (log2e folded into q), defer-max THR=8, cvt_pk P->bf16.
__global__ __launch_bounds__(256, 2) void attn_kernel(const unsigned short* __restrict__ QKV,
                                                      const unsigned short* __restrict__ VT,
                                                      unsigned short* __restrict__ O) {
  __shared__ __align__(16) unsigned short Ksm[2][64 * 128];    // 32KB swizzled
  __shared__ __align__(16) unsigned short VTsm[2][128 * 64];   // 32KB swizzled
  __shared__ __align__(16) unsigned short Psm[4 * 16 * 64];    // 8KB per-wave
  const int bid = blockIdx.x;
  const int grp = bid & 7, idx = bid >> 3;     // idx 0..127
  const int qt = 31 - (idx >> 2);              // heavy-first (LPT)
  const int bh = (grp << 2) | (idx & 3);
  const int b = bh >> 4, hd = bh & 15;
  const int tid = threadIdx.x, w = tid >> 6, l = tid & 63, g = l >> 4, r = l & 15;
  const int qbs = qt * 64 + w * 16;            // wave's q-row base (16 rows)

  const unsigned short* qp = QKV + (size_t)(b * S_LEN + qbs + r) * QS + hd * HDIM;
  s16x8 qf[4];
#pragma unroll
  for (int ks = 0; ks < 4; ks++) qf[ks] = *(const s16x8*)(qp + ks * 32 + g * 8);

  float mreg[4], lreg[4];
  f32x4 zero = {0.f, 0.f, 0.f, 0.f};
  f32x4 oacc[8];
#pragma unroll
  for (int jj = 0; jj < 4; jj++) { mreg[jj] = -1e30f; lreg[jj] = 0.f; }
#pragma unroll
  for (int di = 0; di < 8; di++) oacc[di] = zero;

  const int cK = tid & 15, rowK = tid >> 4;            // 0..15 (+16/i)
  const unsigned short* kp_base = QKV + (size_t)(b * S_LEN + rowK) * QS + HID + hd * HDIM
                                  + ((cK ^ (rowK & 7)) << 3);
  const int cV = tid & 7, dV = tid >> 3;               // 0..31 (+32/i)
  const unsigned short* vp_base = VT + (size_t)(bh * 128 + dV) * S_LEN + ((cV ^ (dV & 7)) << 3);
  char* const ksm0 = (char*)Ksm;
  char* const vtsm0 = (char*)VTsm;
  char* const psm_w = (char*)Psm + w * 2048;

#define STAGE(kt, bufi)                                                        \
  {                                                                            \
    const unsigned short* kp_ = kp_base + (size_t)((kt) * 64) * QS;            \
    const unsigned short* vp_ = vp_base + (kt) * 64;                           \
    char* kd_ = ksm0 + (bufi) * 16384;                                         \
    char* vd_ = vtsm0 + (bufi) * 16384;                                        \
    GLL16(kp_,                      kd_ + tid * 16);                           \
    GLL16(kp_ + (size_t)16 * QS,    kd_ + (tid + 256) * 16);                   \
    GLL16(kp_ + (size_t)32 * QS,    kd_ + (tid + 512) * 16);                   \
    GLL16(kp_ + (size_t)48 * QS,    kd_ + (tid + 768) * 16);                   \
    GLL16(vp_,                      vd_ + tid * 16);                           \
    GLL16(vp_ + (size_t)32 * S_LEN, vd_ + (tid + 256) * 16);                   \
    GLL16(vp_ + (size_t)64 * S_LEN, vd_ + (tid + 512) * 16);                   \
    GLL16(vp_ + (size_t)96 * S_LEN, vd_ + (tid + 768) * 16);                   \
  }

  const int nt = qt + 1;
  STAGE(0, 0);

  for (int kt2 = 0; kt2 < nt; kt2++) {
    const int buf = kt2 & 1;
    // gate: my 8 loads for THIS tile (issued one full tile ago) complete.
    asm volatile("s_waitcnt vmcnt(0)" ::: "memory");
    __builtin_amdgcn_s_barrier();      // all waves past reads of buf^1 and loads done
    __builtin_amdgcn_sched_barrier(0);
    if (kt2 + 1 < nt) STAGE(kt2 + 1, buf ^ 1);   // flies under this tile's compute

    const char* ksm_c = ksm0 + buf * 16384;
    const char* vtsm_c = vtsm0 + buf * 16384;

    // S = Q K^T (scores pre-scaled to log2 domain)
    f32x4 sacc[4];
#pragma unroll
    for (int ni = 0; ni < 4; ni++) sacc[ni] = zero;
#pragma unroll
    for (int ni = 0; ni < 4; ni++) {
      const int krow = ni * 16 + r;
      const int swz = (krow & 7) << 4;
      const char* kb2 = ksm_c + krow * 256;
#pragma unroll
      for (int ks = 0; ks < 4; ks++) {
        s16x8 kf = *(const s16x8*)(kb2 + ((ks * 64 + g * 16) ^ swz));
        sacc[ni] = __builtin_amdgcn_mfma_f32_16x16x32_bf16(qf[ks], kf, sacc[ni], 0, 0, 0);
      }
    }

    // causal mask (uniform branch: only the diagonal tile pays)
    if (kt2 == qt) {
#pragma unroll
      for (int ni = 0; ni < 4; ni++)
#pragma unroll
        for (int jj = 0; jj < 4; jj++)
          if ((kt2 * 64 + ni * 16 + r) > (qbs + g * 4 + jj)) sacc[ni][jj] = -1e30f;
    }

    // online softmax, defer-max (THR=8 in log2 units)
    float mrow[4];
#pragma unroll
    for (int jj = 0; jj < 4; jj++)
      mrow[jj] = fmaxf(fmaxf(sacc[0][jj], sacc[1][jj]), fmaxf(sacc[2][jj], sacc[3][jj]));
#pragma unroll
    for (int jj = 0; jj < 4; jj++) {
#pragma unroll
      for (int off = 8; off >= 1; off >>= 1)
        mrow[jj] = fmaxf(mrow[jj], __shfl_xor(mrow[jj], off, 64));
    }
    bool grow = false;
#pragma unroll
    for (int jj = 0; jj < 4; jj++) grow = grow || (mrow[jj] > mreg[jj] + 8.0f);
    if (__any(grow)) {
#pragma unroll
      for (int jj = 0; jj < 4; jj++) {
        float mn = fmaxf(mreg[jj], mrow[jj]);
        float corr = exp2f(mreg[jj] - mn);
        mreg[jj] = mn;
        lreg[jj] *= corr;
#pragma unroll
        for (int di = 0; di < 8; di++) oacc[di][jj] *= corr;
      }
    }
#pragma unroll
    for (int jj = 0; jj < 4; jj++) {
      float sm = 0.f;
#pragma unroll
      for (int ni = 0; ni < 4; ni++) {
        float p2 = exp2f(sacc[ni][jj] - mreg[jj]);
        sacc[ni][jj] = p2;
        sm += p2;
      }
#pragma unroll
      for (int off = 8; off >= 1; off >>= 1) sm += __shfl_xor(sm, off, 64);
      lreg[jj] += sm;
    }

    // P -> wave-private LDS (swizzled), packed bf16 conversion
#pragma unroll
    for (int ni = 0; ni < 4; ni++) {
      unsigned int pk01, pk23;
      asm("v_cvt_pk_bf16_f32 %0, %1, %2" : "=v"(pk01) : "v"(sacc[ni][0]), "v"(sacc[ni][1]));
      asm("v_cvt_pk_bf16_f32 %0, %1, %2" : "=v"(pk23) : "v"(sacc[ni][2]), "v"(sacc[ni][3]));
      const int col2 = (ni * 16 + r) << 1;
      const int pr0 = g * 4;
      *(unsigned short*)(psm_w + (((pr0 + 0) * 128 + col2) ^ (((pr0 + 0) & 7) << 4))) = (unsigned short)pk01;
      *(unsigned short*)(psm_w + (((pr0 + 1) * 128 + col2) ^ (((pr0 + 1) & 7) << 4))) = (unsigned short)(pk01 >> 16);
      *(unsigned short*)(psm_w + (((pr0 + 2) * 128 + col2) ^ (((pr0 + 2) & 7) << 4))) = (unsigned short)pk23;
      *(unsigned short*)(psm_w + (((pr0 + 3) * 128 + col2) ^ (((pr0 + 3) & 7) << 4))) = (unsigned short)(pk23 >> 16);
    }

    // PV
#pragma unroll
    for (int ksl = 0; ksl < 2; ksl++) {
      s16x8 pa = *(const s16x8*)(psm_w + ((r * 128 + ((ksl * 32 + g * 8) << 1)) ^ ((r & 7) << 4)));
      const int kgran = ksl * 4 + g;
#pragma unroll
      for (int di = 0; di < 8; di++) {
        const int d = di * 16 + r;
        s16x8 vf = *(const s16x8*)(vtsm_c + d * 128 + ((kgran ^ (d & 7)) << 4));
        oacc[di] = __builtin_amdgcn_mfma_f32_16x16x32_bf16(pa, vf, oacc[di], 0, 0, 0);
      }
    }
  }
#undef STAGE

  // epilogue
#pragma unroll
  for (int di = 0; di < 8; di++)
#pragma unroll
    for (int jj = 0; jj < 4; jj++) {
      int orow = qbs + g * 4 + jj;
      O[(size_t)(b * S_LEN + orow) * HID + hd * HDIM + di * 16 + r] =
          f2bf(oacc[di][jj] / lreg[jj]);
    }
}

extern "C" void kernel_launch(void* const* d_in, const int* in_sizes, int n_in,
                              void* d_out, int out_size, void* d_ws, size_t ws_size,
                              hipStream_t stream) {
  const float* x      = (const float*)d_in[0];
  const float* norm_w = (const float*)d_in[1];
  const float* wq     = (const float*)d_in[2];
  const float* wk     = (const float*)d_in[3];
  const float* wv     = (const float*)d_in[4];
  const float* wo     = (const float*)d_in[5];
  const int*   pos    = (const int*)d_in[6];
  float* out = (float*)d_out;

  char* ws = (char*)d_ws;
  const size_t WQKV_B = (size_t)3 * HID * HID * 2;   // 24 MB
  const size_t WO_B   = (size_t)HID * HID * 2;       // 8 MB
  const size_t H_B    = (size_t)ROWS * HID * 2;      // 16 MB
  const size_t QKV_B  = (size_t)ROWS * QS * 2;       // 48 MB

  unsigned short* wqkvb = (unsigned short*)(ws);                     // [0,24)
  unsigned short* vt    = (unsigned short*)(ws);                     // aliases [0,16) after gemms
  unsigned short* wob   = (unsigned short*)(ws + WQKV_B);            // [24,32)
  unsigned short* h     = (unsigned short*)(ws + WQKV_B + WO_B);     // [32,48) also ctx
  unsigned short* qkv   = (unsigned short*)(ws + WQKV_B + WO_B + H_B);           // [48,96)
  float* cost = (float*)(ws + WQKV_B + WO_B + H_B + QKV_B);
  float* sint = cost + (size_t)S_LEN * 64;

  dim3 cgrid(HID * HID / 4 / 256, 4);
  cast4_kernel<<<cgrid, 256, 0, stream>>>(wq, wk, wv, wo, wqkvb, wob);
  rope_tab_kernel<<<S_LEN, 64, 0, stream>>>(cost, sint);
  rmsnorm_kernel<<<ROWS, 256, 0, stream>>>(x, norm_w, h);

  // Q,K projection: 256x256-tile kernel, 16x16 = 256 blocks (1/CU, no tail)
  dim3 qkgrid(2 * HID / 256, ROWS / 256);
  gemm_qk_kernel<<<qkgrid, 512, 0, stream>>>(h, wqkvb, qkv, HID, QS);

  // V projection: gemm8 NI=4, 8x32 = 256 blocks
  dim3 vgrid(HID / 256, ROWS / 128);
  gemm8_kernel<unsigned short, 4><<<vgrid, 512, 0, stream>>>(
      h, wqkvb + (size_t)2 * HID * HID, qkv + 2 * HID, HID, QS);

  dim3 tgrid(S_LEN / 64, 2, BATCH * NHEADS);
  transpose_v_kernel<<<tgrid, 256, 0, stream>>>(qkv, vt);

  rope_kernel<<<ROWS, 256, 0, stream>>>(pos, cost, sint, qkv);

  attn_kernel<<<1024, 256, 0, stream>>>(qkv, vt, h /* ctx */);

  // out-proj: gemm8 NI=4, 8x32 = 256 blocks (was NI=2 @ 512 blocks, ~100us)
  dim3 ogrid(HID / 256, ROWS / 128);
  gemm8_kernel<float, 4><<<ogrid, 512, 0, stream>>>(h, wob, out, HID, HID);
}

// Round 10
// 256.179 us; speedup vs baseline: 2.0317x; 1.1108x over previous
//
#include <hip/hip_runtime.h>
#include <hip/hip_bf16.h>
#include <stdint.h>

#define S_LEN   2048
#define BATCH   2
#define HID     2048
#define NHEADS  16
#define HDIM    128
#define ROWS    (BATCH * S_LEN)          // 4096
#define QKS     4096                     // qk row stride (2*HID; V lives in VT)
#define ATT_SCALE 0.08838834764831843f   // 1/sqrt(128)
#define LOG2E     1.4426950408889634f

typedef __attribute__((ext_vector_type(8))) short s16x8;
typedef __attribute__((ext_vector_type(4))) float f32x4;

#define GLL16(gp, lp)                                                          \
  __builtin_amdgcn_global_load_lds(                                            \
      (__attribute__((address_space(1))) void*)(gp),                           \
      (__attribute__((address_space(3))) void*)(lp), 16, 0, 0)

__device__ __forceinline__ float bf2f(unsigned short u) {
  union { unsigned int i; float f; } v; v.i = ((unsigned int)u) << 16; return v.f;
}
__device__ __forceinline__ unsigned short f2bf(float f) {
  union { float f; unsigned int i; } v; v.f = f;
  unsigned int i = v.i;
  return (unsigned short)((i + 0x7FFFu + ((i >> 16) & 1u)) >> 16);
}
__device__ __forceinline__ void store_out(unsigned short* p, float v) { *p = f2bf(v); }
__device__ __forceinline__ void store_out(float* p, float v) { *p = v; }

// ---------------- fused weight cast fp32 -> bf16 (4 weights, 1 launch) ----------------
__global__ __launch_bounds__(256) void cast4_kernel(const float* __restrict__ w0,
                                                    const float* __restrict__ w1,
                                                    const float* __restrict__ w2,
                                                    const float* __restrict__ w3,
                                                    unsigned short* __restrict__ dqkv,
                                                    unsigned short* __restrict__ dwo) {
  const int which = blockIdx.y;
  const float* src = (which == 0) ? w0 : (which == 1) ? w1 : (which == 2) ? w2 : w3;
  unsigned short* dst = (which < 3) ? dqkv + (size_t)which * HID * HID : dwo;
  int i = blockIdx.x * 256 + threadIdx.x;
  float4 v = ((const float4*)src)[i];
  ushort4 o;
  o.x = f2bf(v.x); o.y = f2bf(v.y); o.z = f2bf(v.z); o.w = f2bf(v.w);
  ((ushort4*)dst)[i] = o;
}

// ---------------- RMSNorm (fp32 in, bf16 out) ----------------
__global__ __launch_bounds__(256) void rmsnorm_kernel(const float* __restrict__ x,
                                                      const float* __restrict__ w,
                                                      unsigned short* __restrict__ h) {
  int row = blockIdx.x;
  int t = threadIdx.x;
  const float4* xr4 = (const float4*)(x + (size_t)row * HID);
  float4 a = xr4[t], b = xr4[t + 256];
  float ss = a.x*a.x + a.y*a.y + a.z*a.z + a.w*a.w
           + b.x*b.x + b.y*b.y + b.z*b.z + b.w*b.w;
#pragma unroll
  for (int off = 32; off >= 1; off >>= 1) ss += __shfl_xor(ss, off, 64);
  __shared__ float red[4];
  if ((t & 63) == 0) red[t >> 6] = ss;
  __syncthreads();
  float tot = red[0] + red[1] + red[2] + red[3];
  float rs = rsqrtf(tot * (1.0f / (float)HID) + 1e-6f);
  const float4* w4 = (const float4*)w;
  float4 wa = w4[t], wb = w4[t + 256];
  ushort4 oa, ob;
  oa.x = f2bf(a.x * wa.x * rs); oa.y = f2bf(a.y * wa.y * rs);
  oa.z = f2bf(a.z * wa.z * rs); oa.w = f2bf(a.w * wa.w * rs);
  ob.x = f2bf(b.x * wb.x * rs); ob.y = f2bf(b.y * wb.y * rs);
  ob.z = f2bf(b.z * wb.z * rs); ob.w = f2bf(b.w * wb.w * rs);
  ushort4* hr = (ushort4*)(h + (size_t)row * HID);
  hr[t] = oa; hr[t + 256] = ob;
}

// ---------------- RoPE tables ----------------
__global__ void rope_tab_kernel(float* __restrict__ cost, float* __restrict__ sint) {
  int s = blockIdx.x, j = threadIdx.x;  // 64 threads
  float inv = powf(10000.0f, -((float)j) / 64.0f);
  float ang = (float)s * inv;
  cost[s * 64 + j] = cosf(ang);
  sint[s * 64 + j] = sinf(ang);
}

// ---------------- RoPE apply in-place on q,k (qk buffer, stride QKS) ----------------
// q pre-scaled by ATT_SCALE*log2(e): attention softmax runs in the exp2 domain.
__global__ __launch_bounds__(256) void rope_kernel(const int* __restrict__ pos_ids,
                                                   const float* __restrict__ cost,
                                                   const float* __restrict__ sint,
                                                   unsigned short* __restrict__ qk) {
  int row = blockIdx.x;            // b*S + s
  int p = pos_ids[row];
  int t = threadIdx.x;
  int head = t >> 4;
  int j0 = (t & 15) * 4;
  size_t base = (size_t)row * QKS + head * HDIM;
  float4 c = *(const float4*)(cost + p * 64 + j0);
  float4 s = *(const float4*)(sint + p * 64 + j0);
#pragma unroll
  for (int which = 0; which < 2; which++) {
    unsigned short* ptr = qk + base + which * HID;  // q then k
    float sc = which ? 1.0f : (ATT_SCALE * LOG2E);
    ushort4 v1 = *(ushort4*)(ptr + j0);
    ushort4 v2 = *(ushort4*)(ptr + 64 + j0);
    ushort4 o1, o2;
    o1.x = f2bf((bf2f(v1.x) * c.x - bf2f(v2.x) * s.x) * sc);
    o1.y = f2bf((bf2f(v1.y) * c.y - bf2f(v2.y) * s.y) * sc);
    o1.z = f2bf((bf2f(v1.z) * c.z - bf2f(v2.z) * s.z) * sc);
    o1.w = f2bf((bf2f(v1.w) * c.w - bf2f(v2.w) * s.w) * sc);
    o2.x = f2bf((bf2f(v2.x) * c.x + bf2f(v1.x) * s.x) * sc);
    o2.y = f2bf((bf2f(v2.y) * c.y + bf2f(v1.y) * s.y) * sc);
    o2.z = f2bf((bf2f(v2.z) * c.z + bf2f(v1.z) * s.z) * sc);
    o2.w = f2bf((bf2f(v2.w) * c.w + bf2f(v1.w) * s.w) * sc);
    *(ushort4*)(ptr + j0) = o1;
    *(ushort4*)(ptr + 64 + j0) = o2;
  }
}

// ---------------- 256x256 kk-half-staggered GEMM (QK projection) ----------------
#define SH(kt, bi, kk2) {                                                      \
    const unsigned short* sa_ = aQ + (size_t)(kt) * 64 + (kk2) * 32;           \
    const unsigned short* sb_ = bQ + (size_t)(kt) * 64 + (kk2) * 32;           \
    char* da_ = qsm + ((bi) * 2 + (kk2)) * 32768 + tid * 16;                   \
    GLL16(sa_, da_);                                                           \
    GLL16(sa_ + (size_t)128 * K, da_ + 8192);                                  \
    GLL16(sb_, da_ + 16384);                                                   \
    GLL16(sb_ + (size_t)128 * K, da_ + 16384 + 8192);                          \
  }

__global__ __launch_bounds__(512, 2) void gemm_qk_kernel(const unsigned short* __restrict__ A,
                                                         const unsigned short* __restrict__ B,
                                                         unsigned short* __restrict__ C,
                                                         int K, int N) {
  __shared__ __align__(16) unsigned short Qsm[2][2][2][256 * 32];  // 128 KB
  const int bm = blockIdx.y, bn = blockIdx.x;
  const int tid = threadIdx.x;
  const int w = tid >> 6, wr = w >> 2, wc = w & 3;
  const int l = tid & 63, g = l >> 4, r = l & 15;
  const int KT = K >> 6;

  const int srow = tid >> 2;
  const int sg = (tid & 3) ^ ((tid >> 2) & 3) ^ ((tid >> 4) & 3);
  const unsigned short* aQ = A + (size_t)(bm * 256 + srow) * K + sg * 8;
  const unsigned short* bQ = B + (size_t)(bn * 256 + srow) * K + sg * 8;
  char* const qsm = (char*)Qsm;

  f32x4 zero = {0.f, 0.f, 0.f, 0.f};
  f32x4 acc[8][4];
#pragma unroll
  for (int mi = 0; mi < 8; mi++)
#pragma unroll
    for (int ni = 0; ni < 4; ni++) acc[mi][ni] = zero;

  const int ro = ((g ^ (r & 3) ^ ((r >> 2) & 3)) << 4);
  const int aOff = (wr * 128 + r) * 64 + ro;           // + mi*1024
  const int bOff = 16384 + (wc * 64 + r) * 64 + ro;    // + ni*1024

  SH(0, 0, 0); SH(0, 0, 1);

  for (int kt = 0; kt < KT; ++kt) {
    const int buf = kt & 1;
    const bool more = (kt + 1 < KT);
    const char* l0 = qsm + (buf * 2 + 0) * 32768;
    const char* l1 = qsm + (buf * 2 + 1) * 32768;

    asm volatile("s_waitcnt vmcnt(4)" ::: "memory");
    __builtin_amdgcn_s_barrier();
    __builtin_amdgcn_sched_barrier(0);
    s16x8 a[4], b[4];
#pragma unroll
    for (int ni = 0; ni < 4; ni++) b[ni] = *(const s16x8*)(l0 + bOff + ni * 1024);
#pragma unroll
    for (int i = 0; i < 4; i++) a[i] = *(const s16x8*)(l0 + aOff + i * 1024);
    if (more) SH(kt + 1, buf ^ 1, 0);
    __builtin_amdgcn_s_setprio(1);
#pragma unroll
    for (int ni = 0; ni < 4; ni++)
#pragma unroll
      for (int i = 0; i < 4; i++)
        acc[i][ni] = __builtin_amdgcn_mfma_f32_16x16x32_bf16(a[i], b[ni], acc[i][ni], 0, 0, 0);
    __builtin_amdgcn_s_setprio(0);

    s16x8 a2[4];
#pragma unroll
    for (int i = 0; i < 4; i++) a2[i] = *(const s16x8*)(l0 + aOff + (4 + i) * 1024);
    __builtin_amdgcn_s_setprio(1);
#pragma unroll
    for (int ni = 0; ni < 4; ni++)
#pragma unroll
      for (int i = 0; i < 4; i++)
        acc[4 + i][ni] = __builtin_amdgcn_mfma_f32_16x16x32_bf16(a2[i], b[ni], acc[4 + i][ni], 0, 0, 0);
    __builtin_amdgcn_s_setprio(0);

    if (more) { asm volatile("s_waitcnt vmcnt(4)" ::: "memory"); }
    else      { asm volatile("s_waitcnt vmcnt(0)" ::: "memory"); }
    __builtin_amdgcn_s_barrier();
    __builtin_amdgcn_sched_barrier(0);
#pragma unroll
    for (int ni = 0; ni < 4; ni++) b[ni] = *(const s16x8*)(l1 + bOff + ni * 1024);
#pragma unroll
    for (int i = 0; i < 4; i++) a[i] = *(const s16x8*)(l1 + aOff + i * 1024);
    if (more) SH(kt + 1, buf ^ 1, 1);
    __builtin_amdgcn_s_setprio(1);
#pragma unroll
    for (int ni = 0; ni < 4; ni++)
#pragma unroll
      for (int i = 0; i < 4; i++)
        acc[i][ni] = __builtin_amdgcn_mfma_f32_16x16x32_bf16(a[i], b[ni], acc[i][ni], 0, 0, 0);
    __builtin_amdgcn_s_setprio(0);

#pragma unroll
    for (int i = 0; i < 4; i++) a2[i] = *(const s16x8*)(l1 + aOff + (4 + i) * 1024);
    __builtin_amdgcn_s_setprio(1);
#pragma unroll
    for (int ni = 0; ni < 4; ni++)
#pragma unroll
      for (int i = 0; i < 4; i++)
        acc[4 + i][ni] = __builtin_amdgcn_mfma_f32_16x16x32_bf16(a2[i], b[ni], acc[4 + i][ni], 0, 0, 0);
    __builtin_amdgcn_s_setprio(0);
  }

#pragma unroll
  for (int mi = 0; mi < 8; mi++)
#pragma unroll
    for (int ni = 0; ni < 4; ni++) {
      const int crow = bm * 256 + wr * 128 + mi * 16 + g * 4;
      const int ccol = bn * 256 + wc * 64 + ni * 16 + r;
#pragma unroll
      for (int j = 0; j < 4; j++)
        store_out(&C[(size_t)(crow + j) * N + ccol], acc[mi][ni][j]);
    }
}
#undef SH

// ---------------- Triple-buffered counted-vmcnt GEMM ----------------
// VT_OUT: write C transposed into VT layout [bh*128+d][S_LEN] (V projection).
#define SA(kt, bi) {                                                           \
    const unsigned short* s_ = aS + (size_t)(kt) * 64;                         \
    char* d_ = (char*)Ab[bi] + tid * 16;                                       \
    GLL16(s_, d_);                                                             \
    GLL16(s_ + (size_t)64 * K, d_ + 8192);                                     \
  }
#define SB(kt, bi, hf) {                                                       \
    const unsigned short* s_ = bS + (size_t)(hf) * 128 * K + (size_t)(kt) * 64;\
    char* d_ = (char*)Bb[bi] + (hf) * 16384 + tid * 16;                        \
    GLL16(s_, d_);                                                             \
    GLL16(s_ + (size_t)64 * K, d_ + 8192);                                     \
  }

template <typename OutT, int NI, bool VT_OUT>
__global__ __launch_bounds__(512, 1) void gemm8_kernel(const unsigned short* __restrict__ A,
                                                       const unsigned short* __restrict__ B,
                                                       OutT* __restrict__ C, int K, int N) {
  __shared__ __align__(16) unsigned short Ab[3][128 * 64];       // 48 KB
  __shared__ __align__(16) unsigned short Bb[3][NI * 64 * 64];   // 96 or 48 KB
  const int bm = blockIdx.y, bn = blockIdx.x;                    // plain mapping
  const int tid = threadIdx.x;
  const int w = tid >> 6, wr = w >> 2, wc = w & 3;
  const int l = tid & 63, g = l >> 4, r = l & 15;
  const int KT = K >> 6;

  const int srow = tid >> 3;
  const int sgr = (tid & 7) ^ (srow & 7);
  const unsigned short* aS = A + (size_t)(bm * 128 + srow) * K + sgr * 8;
  const unsigned short* bS = B + (size_t)(bn * (NI * 64) + srow) * K + sgr * 8;

  f32x4 zero = {0.f, 0.f, 0.f, 0.f};
  f32x4 acc[4][NI];
#pragma unroll
  for (int mi = 0; mi < 4; mi++)
#pragma unroll
    for (int ni = 0; ni < NI; ni++) acc[mi][ni] = zero;

  const int swx = (r & 7) << 4;
  const int ks0 = (g << 4) ^ swx;
  const int ks1 = ((4 | g) << 4) ^ swx;
  const int aOff = (wr * 64 + r) * 128;
  const int bOff = (wc * (NI * 16) + r) * 128;

  SA(0, 0); SB(0, 0, 0); if (NI == 4) SB(0, 0, 1);
  SA(1, 1); SB(1, 1, 0); if (NI == 4) SB(1, 1, 1);

  int cur = 0;
  for (int kt = 0; kt < KT; ++kt) {
    const int b2 = (cur >= 1) ? cur - 1 : cur + 2;   // (cur+2)%3
    if (kt == KT - 1)      { asm volatile("s_waitcnt vmcnt(0)" ::: "memory"); }
    else if (NI == 4)      { asm volatile("s_waitcnt vmcnt(6)" ::: "memory"); }
    else                   { asm volatile("s_waitcnt vmcnt(4)" ::: "memory"); }
    __builtin_amdgcn_s_barrier();
    __builtin_amdgcn_sched_barrier(0);
    const char* lA = (const char*)Ab[cur];
    const char* lB = (const char*)Bb[cur];
    const bool more = (kt + 2 < KT);

    s16x8 a[4][2], b[NI][2];
#pragma unroll
    for (int mi = 0; mi < 4; mi++) {
      a[mi][0] = *(const s16x8*)(lA + aOff + mi * 2048 + ks0);
      a[mi][1] = *(const s16x8*)(lA + aOff + mi * 2048 + ks1);
    }
#pragma unroll
    for (int ni = 0; ni < NI / 2; ni++) {
      b[ni][0] = *(const s16x8*)(lB + bOff + ni * 2048 + ks0);
      b[ni][1] = *(const s16x8*)(lB + bOff + ni * 2048 + ks1);
    }
    if (more) { SA(kt + 2, b2); if (NI == 4) SB(kt + 2, b2, 0); }
    __builtin_amdgcn_s_setprio(1);
#pragma unroll
    for (int kk = 0; kk < 2; kk++)
#pragma unroll
      for (int ni = 0; ni < NI / 2; ni++)
#pragma unroll
        for (int mi = 0; mi < 4; mi++)
          acc[mi][ni] = __builtin_amdgcn_mfma_f32_16x16x32_bf16(a[mi][kk], b[ni][kk], acc[mi][ni], 0, 0, 0);
    __builtin_amdgcn_s_setprio(0);
    __builtin_amdgcn_sched_barrier(0);

#pragma unroll
    for (int ni = NI / 2; ni < NI; ni++) {
      b[ni][0] = *(const s16x8*)(lB + bOff + ni * 2048 + ks0);
      b[ni][1] = *(const s16x8*)(lB + bOff + ni * 2048 + ks1);
    }
    if (more) { if (NI == 4) { SB(kt + 2, b2, 1); } else { SB(kt + 2, b2, 0); } }
    __builtin_amdgcn_s_setprio(1);
#pragma unroll
    for (int kk = 0; kk < 2; kk++)
#pragma unroll
      for (int ni = NI / 2; ni < NI; ni++)
#pragma unroll
        for (int mi = 0; mi < 4; mi++)
          acc[mi][ni] = __builtin_amdgcn_mfma_f32_16x16x32_bf16(a[mi][kk], b[ni][kk], acc[mi][ni], 0, 0, 0);
    __builtin_amdgcn_s_setprio(0);
    cur = (cur == 2) ? 0 : cur + 1;
  }

#pragma unroll
  for (int mi = 0; mi < 4; mi++)
#pragma unroll
    for (int ni = 0; ni < NI; ni++) {
      const int crow = bm * 128 + wr * 64 + mi * 16 + g * 4;
      const int ccol = bn * (NI * 64) + wc * (NI * 16) + ni * 16 + r;
      if constexpr (VT_OUT) {
        // C^T into VT[(b*16+head)*128 + d][s]; 4 consecutive tokens -> ushort4
        const int bidx = crow >> 11;            // token / S_LEN
        const int s0 = crow & (S_LEN - 1);
        const int vrow = (bidx * 16 + (ccol >> 7)) * 128 + (ccol & 127);
        ushort4 o;
        o.x = f2bf(acc[mi][ni][0]); o.y = f2bf(acc[mi][ni][1]);
        o.z = f2bf(acc[mi][ni][2]); o.w = f2bf(acc[mi][ni][3]);
        *(ushort4*)((unsigned short*)C + (size_t)vrow * S_LEN + s0) = o;
      } else {
#pragma unroll
        for (int j = 0; j < 4; j++)
          store_out(&C[(size_t)(crow + j) * N + ccol], acc[mi][ni][j]);
      }
    }
}

// ---------------- Flash attention, causal, swapped-operand softmax ----------------
// 1024 blocks x 256 thr (4 waves); block = 64-row q-tile; LPT + XCD-chunked.
// QK computed as mfma(K,Q) -> lane holds S^T[kv][q=r]: row-reduce = local tree
// + 2 shfl (was 8); P->LDS = 8 ds_write_b32; PV = mfma(V^T, P^T) -> O^T.
// KV double-buffered (72KB -> 2 blocks/CU), single barrier/tile, exp2 domain,
// defer-max THR=8.
__global__ __launch_bounds__(256, 2) void attn_kernel(const unsigned short* __restrict__ QK,
                                                      const unsigned short* __restrict__ VT,
                                                      unsigned short* __restrict__ O) {
  __shared__ __align__(16) unsigned short Ksm[2][64 * 128];    // 32KB swizzled
  __shared__ __align__(16) unsigned short VTsm[2][128 * 64];   // 32KB swizzled
  __shared__ __align__(16) unsigned short Psm[4 * 16 * 64];    // 8KB per-wave [q][kv]
  const int bid = blockIdx.x;
  const int grp = bid & 7, idx = bid >> 3;     // idx 0..127
  const int qt = 31 - (idx >> 2);              // heavy-first (LPT)
  const int bh = (grp << 2) | (idx & 3);
  const int b = bh >> 4, hd = bh & 15;
  const int tid = threadIdx.x, w = tid >> 6, l = tid & 63, g = l >> 4, r = l & 15;
  const int qbs = qt * 64 + w * 16;            // wave's q-row base (16 rows)

  // Q fragment (B operand): lane row = q = qbs + r (pre-scaled by scale*log2e)
  const unsigned short* qp = QK + (size_t)(b * S_LEN + qbs + r) * QKS + hd * HDIM;
  s16x8 qf[4];
#pragma unroll
  for (int ks = 0; ks < 4; ks++) qf[ks] = *(const s16x8*)(qp + ks * 32 + g * 8);

  float mreg = -1e30f, lreg = 0.f;
  f32x4 zero = {0.f, 0.f, 0.f, 0.f};
  f32x4 oacc[8];                               // O^T[d=di*16+g*4+jj][q=r]
#pragma unroll
  for (int di = 0; di < 8; di++) oacc[di] = zero;

  const int cK = tid & 15, rowK = tid >> 4;            // 0..15 (+16/i)
  const unsigned short* kp_base = QK + (size_t)(b * S_LEN + rowK) * QKS + HID + hd * HDIM
                                  + ((cK ^ (rowK & 7)) << 3);
  const int cV = tid & 7, dV = tid >> 3;               // 0..31 (+32/i)
  const unsigned short* vp_base = VT + (size_t)(bh * 128 + dV) * S_LEN + ((cV ^ (dV & 7)) << 3);
  char* const ksm0 = (char*)Ksm;
  char* const vtsm0 = (char*)VTsm;
  char* const psm_w = (char*)Psm + w * 2048;
  const int pswz = (r & 7) << 4;

#define STAGE(kt, bufi)                                                        \
  {                                                                            \
    const unsigned short* kp_ = kp_base + (size_t)((kt) * 64) * QKS;           \
    const unsigned short* vp_ = vp_base + (kt) * 64;                           \
    char* kd_ = ksm0 + (bufi) * 16384;                                         \
    char* vd_ = vtsm0 + (bufi) * 16384;                                        \
    GLL16(kp_,                      kd_ + tid * 16);                           \
    GLL16(kp_ + (size_t)16 * QKS,   kd_ + (tid + 256) * 16);                   \
    GLL16(kp_ + (size_t)32 * QKS,   kd_ + (tid + 512) * 16);                   \
    GLL16(kp_ + (size_t)48 * QKS,   kd_ + (tid + 768) * 16);                   \
    GLL16(vp_,                      vd_ + tid * 16);                           \
    GLL16(vp_ + (size_t)32 * S_LEN, vd_ + (tid + 256) * 16);                   \
    GLL16(vp_ + (size_t)64 * S_LEN, vd_ + (tid + 512) * 16);                   \
    GLL16(vp_ + (size_t)96 * S_LEN, vd_ + (tid + 768) * 16);                   \
  }

  const int nt = qt + 1;
  STAGE(0, 0);

  for (int kt2 = 0; kt2 < nt; kt2++) {
    const int buf = kt2 & 1;
    asm volatile("s_waitcnt vmcnt(0)" ::: "memory");
    __builtin_amdgcn_s_barrier();
    __builtin_amdgcn_sched_barrier(0);
    if (kt2 + 1 < nt) STAGE(kt2 + 1, buf ^ 1);   // flies under this tile's compute

    const char* ksm_c = ksm0 + buf * 16384;
    const char* vtsm_c = vtsm0 + buf * 16384;

    // S^T = K Q^T: sacc[ni][jj] = S[kv=kt2*64+ni*16+g*4+jj][q=qbs+r]
    f32x4 sacc[4];
#pragma unroll
    for (int ni = 0; ni < 4; ni++) sacc[ni] = zero;
#pragma unroll
    for (int ni = 0; ni < 4; ni++) {
      const int krow = ni * 16 + r;
      const int swz = (krow & 7) << 4;
      const char* kb2 = ksm_c + krow * 256;
#pragma unroll
      for (int ks = 0; ks < 4; ks++) {
        s16x8 kf = *(const s16x8*)(kb2 + ((ks * 64 + g * 16) ^ swz));
        sacc[ni] = __builtin_amdgcn_mfma_f32_16x16x32_bf16(kf, qf[ks], sacc[ni], 0, 0, 0);
      }
    }

    // causal mask (diagonal tile only)
    if (kt2 == qt) {
#pragma unroll
      for (int ni = 0; ni < 4; ni++)
#pragma unroll
        for (int jj = 0; jj < 4; jj++)
          if ((kt2 * 64 + ni * 16 + g * 4 + jj) > (qbs + r)) sacc[ni][jj] = -1e30f;
    }

    // row max for q=r: local 16-tree + 2 shfl (over g lanes)
    float m0 = fmaxf(fmaxf(sacc[0][0], sacc[0][1]), fmaxf(sacc[0][2], sacc[0][3]));
    float m1 = fmaxf(fmaxf(sacc[1][0], sacc[1][1]), fmaxf(sacc[1][2], sacc[1][3]));
    float m2 = fmaxf(fmaxf(sacc[2][0], sacc[2][1]), fmaxf(sacc[2][2], sacc[2][3]));
    float m3 = fmaxf(fmaxf(sacc[3][0], sacc[3][1]), fmaxf(sacc[3][2], sacc[3][3]));
    float mx = fmaxf(fmaxf(m0, m1), fmaxf(m2, m3));
    mx = fmaxf(mx, __shfl_xor(mx, 16, 64));
    mx = fmaxf(mx, __shfl_xor(mx, 32, 64));

    // defer-max (THR=8 in log2 units)
    if (__any(mx > mreg + 8.0f)) {
      float mn = fmaxf(mreg, mx);
      float corr = exp2f(mreg - mn);
      mreg = mn;
      lreg *= corr;
#pragma unroll
      for (int di = 0; di < 8; di++) oacc[di] = oacc[di] * corr;
    }

    // exp + row sum
#pragma unroll
    for (int ni = 0; ni < 4; ni++)
#pragma unroll
      for (int jj = 0; jj < 4; jj++) sacc[ni][jj] = exp2f(sacc[ni][jj] - mreg);
    float s0 = (sacc[0][0] + sacc[0][1]) + (sacc[0][2] + sacc[0][3]);
    float s1 = (sacc[1][0] + sacc[1][1]) + (sacc[1][2] + sacc[1][3]);
    float s2 = (sacc[2][0] + sacc[2][1]) + (sacc[2][2] + sacc[2][3]);
    float s3 = (sacc[3][0] + sacc[3][1]) + (sacc[3][2] + sacc[3][3]);
    float sm = (s0 + s1) + (s2 + s3);
    sm += __shfl_xor(sm, 16, 64);
    sm += __shfl_xor(sm, 32, 64);
    lreg += sm;

    // P -> wave-private LDS [q=r][kv], swizzled; kv-pairs packed -> b32 writes
#pragma unroll
    for (int ni = 0; ni < 4; ni++) {
      unsigned int pk01, pk23;
      asm("v_cvt_pk_bf16_f32 %0, %1, %2" : "=v"(pk01) : "v"(sacc[ni][0]), "v"(sacc[ni][1]));
      asm("v_cvt_pk_bf16_f32 %0, %1, %2" : "=v"(pk23) : "v"(sacc[ni][2]), "v"(sacc[ni][3]));
      const int byte0 = (r * 128 + ni * 32 + g * 8) ^ pswz;
      *(unsigned int*)(psm_w + byte0) = pk01;
      *(unsigned int*)(psm_w + byte0 + 4) = pk23;
    }

    // PV: O^T += V^T * P^T; A = V^T frag (row d), B = P^T frag (row q=r)
#pragma unroll
    for (int ksl = 0; ksl < 2; ksl++) {
      s16x8 pb = *(const s16x8*)(psm_w + ((r * 128 + ksl * 64 + g * 16) ^ pswz));
      const int kgran = ksl * 4 + g;
#pragma unroll
      for (int di = 0; di < 8; di++) {
        const int d = di * 16 + r;
        s16x8 vf = *(const s16x8*)(vtsm_c + d * 128 + ((kgran ^ (d & 7)) << 4));
        oacc[di] = __builtin_amdgcn_mfma_f32_16x16x32_bf16(vf, pb, oacc[di], 0, 0, 0);
      }
    }
  }
#undef STAGE

  // epilogue: O[q=qbs+r][d = di*16+g*4+jj], 8B stores
  const float inv = 1.0f / lreg;
  unsigned short* orow = O + (size_t)(b * S_LEN + qbs + r) * HID + hd * HDIM;
#pragma unroll
  for (int di = 0; di < 8; di++) {
    ushort4 o;
    o.x = f2bf(oacc[di][0] * inv); o.y = f2bf(oacc[di][1] * inv);
    o.z = f2bf(oacc[di][2] * inv); o.w = f2bf(oacc[di][3] * inv);
    *(ushort4*)(orow + di * 16 + g * 4) = o;
  }
}

extern "C" void kernel_launch(void* const* d_in, const int* in_sizes, int n_in,
                              void* d_out, int out_size, void* d_ws, size_t ws_size,
                              hipStream_t stream) {
  const float* x      = (const float*)d_in[0];
  const float* norm_w = (const float*)d_in[1];
  const float* wq     = (const float*)d_in[2];
  const float* wk     = (const float*)d_in[3];
  const float* wv     = (const float*)d_in[4];
  const float* wo     = (const float*)d_in[5];
  const int*   pos    = (const int*)d_in[6];
  float* out = (float*)d_out;

  char* ws = (char*)d_ws;
  const size_t WQKV_B = (size_t)3 * HID * HID * 2;   // 24 MB
  const size_t WO_B   = (size_t)HID * HID * 2;       // 8 MB
  const size_t H_B    = (size_t)ROWS * HID * 2;      // 16 MB
  const size_t QK_B   = (size_t)ROWS * QKS * 2;      // 32 MB

  unsigned short* wqkvb = (unsigned short*)(ws);                     // [0,24)
  unsigned short* vt    = (unsigned short*)(ws);                     // aliases [0,16) after gemm_qk
  unsigned short* wob   = (unsigned short*)(ws + WQKV_B);            // [24,32)
  unsigned short* h     = (unsigned short*)(ws + WQKV_B + WO_B);     // [32,48) also ctx
  unsigned short* qk    = (unsigned short*)(ws + WQKV_B + WO_B + H_B);   // [48,80)
  float* cost = (float*)(ws + WQKV_B + WO_B + H_B + QK_B);
  float* sint = cost + (size_t)S_LEN * 64;

  dim3 cgrid(HID * HID / 4 / 256, 4);
  cast4_kernel<<<cgrid, 256, 0, stream>>>(wq, wk, wv, wo, wqkvb, wob);
  rope_tab_kernel<<<S_LEN, 64, 0, stream>>>(cost, sint);
  rmsnorm_kernel<<<ROWS, 256, 0, stream>>>(x, norm_w, h);

  // Q,K projection: 256x256-tile kernel, 16x16 = 256 blocks (1/CU, no tail)
  dim3 qkgrid(2 * HID / 256, ROWS / 256);
  gemm_qk_kernel<<<qkgrid, 512, 0, stream>>>(h, wqkvb, qk, HID, QKS);

  // V projection writes V^T directly (wq/wk region is dead after gemm_qk)
  dim3 vgrid(HID / 256, ROWS / 128);
  gemm8_kernel<unsigned short, 4, true><<<vgrid, 512, 0, stream>>>(
      h, wqkvb + (size_t)2 * HID * HID, vt, HID, S_LEN);

  rope_kernel<<<ROWS, 256, 0, stream>>>(pos, cost, sint, qk);

  attn_kernel<<<1024, 256, 0, stream>>>(qk, vt, h /* ctx */);

  // out-proj: gemm8 NI=4, 8x32 = 256 blocks
  dim3 ogrid(HID / 256, ROWS / 128);
  gemm8_kernel<float, 4, false><<<ogrid, 512, 0, stream>>>(h, wob, out, HID, HID);
}